// Round 3
// baseline (7997.130 us; speedup 1.0000x reference)
//
#include <hip/hip_runtime.h>

// ---------------- problem constants ----------------
constexpr int Bc   = 2;
constexpr int Tc   = 4096;
constexpr int Dc   = 2048;
constexpr int Hc   = 16;
constexpr int Kc   = 128;
constexpr int Pc   = Hc * Kc;     // 2048
constexpr int Cc   = 64;          // chunk size
constexpr int NCc  = Tc / Cc;     // 64 chunks
constexpr int Mc   = Bc * Tc;     // 8192 rows
constexpr int LATc = 128;

// ---------------- helpers ----------------
__device__ __forceinline__ float bf2f(unsigned short u) {
  unsigned int x = ((unsigned int)u) << 16;
  return __builtin_bit_cast(float, x);
}
__device__ __forceinline__ unsigned short f2bf(float f) {
  unsigned int x = __builtin_bit_cast(unsigned int, f);
  x += 0x7fffu + ((x >> 16) & 1u);
  return (unsigned short)(x >> 16);
}
__device__ __forceinline__ float4 ld4(const float* p) {
  return *reinterpret_cast<const float4*>(p);
}
__device__ __forceinline__ float4 ld4(const unsigned short* p) {
  ushort4 u = *reinterpret_cast<const ushort4*>(p);
  return make_float4(bf2f(u.x), bf2f(u.y), bf2f(u.z), bf2f(u.w));
}
__device__ __forceinline__ void st1(float* p, float v) { *p = v; }
__device__ __forceinline__ void st1(unsigned short* p, float v) { *p = f2bf(v); }

// ---------------- generic NT GEMM: Out[M,N] = A[M,Kd] * Bm[N,Kd]^T ----------------
// tile 128x64, 256 threads, 8x4 micro, K-step 32. M must be multiple of 128.
template <typename AT, typename BT, typename OT>
__global__ __launch_bounds__(256) void gemm_nt(const AT* __restrict__ A,
                                               const BT* __restrict__ Bm,
                                               OT* __restrict__ Out,
                                               int Ndim, int Kd) {
  __shared__ float As[32][132];  // transposed: As[k][m]
  __shared__ float Bs[32][68];   // transposed: Bs[k][n]
  const int m0 = blockIdx.x * 128;
  const int n0 = blockIdx.y * 64;
  const int tid = threadIdx.x;
  const int tx = tid & 15, ty = tid >> 4;
  float acc[8][4];
#pragma unroll
  for (int i = 0; i < 8; ++i)
#pragma unroll
    for (int j = 0; j < 4; ++j) acc[i][j] = 0.f;

  for (int k0 = 0; k0 < Kd; k0 += 32) {
#pragma unroll
    for (int p = 0; p < 4; ++p) {
      int e = tid + p * 256;     // 0..1023 -> 128 rows x 8 float4
      int r = e >> 3;
      int c = (e & 7) << 2;
      float4 v = ld4(A + (size_t)(m0 + r) * Kd + k0 + c);
      As[c + 0][r] = v.x; As[c + 1][r] = v.y; As[c + 2][r] = v.z; As[c + 3][r] = v.w;
    }
#pragma unroll
    for (int p = 0; p < 2; ++p) {
      int e = tid + p * 256;     // 0..511 -> 64 rows x 8 float4
      int r = e >> 3;
      int c = (e & 7) << 2;
      float4 v = make_float4(0.f, 0.f, 0.f, 0.f);
      if (n0 + r < Ndim) v = ld4(Bm + (size_t)(n0 + r) * Kd + k0 + c);
      Bs[c + 0][r] = v.x; Bs[c + 1][r] = v.y; Bs[c + 2][r] = v.z; Bs[c + 3][r] = v.w;
    }
    __syncthreads();
#pragma unroll
    for (int kk = 0; kk < 32; ++kk) {
      const float4* ar = reinterpret_cast<const float4*>(&As[kk][0]);
      const float4* br = reinterpret_cast<const float4*>(&Bs[kk][0]);
      float4 b4 = br[tx];
      float4 a0 = ar[ty * 2], a1 = ar[ty * 2 + 1];
      float av[8] = {a0.x, a0.y, a0.z, a0.w, a1.x, a1.y, a1.z, a1.w};
      float bv4[4] = {b4.x, b4.y, b4.z, b4.w};
#pragma unroll
      for (int i = 0; i < 8; ++i)
#pragma unroll
        for (int j = 0; j < 4; ++j) acc[i][j] = fmaf(av[i], bv4[j], acc[i][j]);
    }
    __syncthreads();
  }
#pragma unroll
  for (int i = 0; i < 8; ++i) {
    int m = m0 + ty * 8 + i;
#pragma unroll
    for (int j = 0; j < 4; ++j) {
      int n = n0 + tx * 4 + j;
      if (n < Ndim) st1(Out + (size_t)m * Ndim + n, acc[i][j]);
    }
  }
}

// ---------------- chunk prep: conv+silu, l2norm, gates, beta; writes qt,u,bw,bv,wlast ----
// grid: B*H*NC blocks (blk = (b*H+h)*NC + n), 128 threads (one per k-channel)
__global__ __launch_bounds__(128) void chunk_prep(
    const unsigned short* __restrict__ q_lin, const unsigned short* __restrict__ k_lin,
    const unsigned short* __restrict__ v_lin, const unsigned short* __restrict__ g_raw,
    const float* __restrict__ beta_lin, const float* __restrict__ conv_q,
    const float* __restrict__ conv_k, const float* __restrict__ conv_v,
    const float* __restrict__ A_log, const float* __restrict__ dt_bias,
    unsigned short* __restrict__ qt, unsigned short* __restrict__ u_,
    unsigned short* __restrict__ bv, unsigned short* __restrict__ bw,
    float* __restrict__ wlast) {
  const int blk = blockIdx.x;
  const int n = blk & 63;
  const int h = (blk >> 6) & 15;
  const int b = blk >> 10;
  const int kk = threadIdx.x;
  const int p = h * Kc + kk;
  float cq[4], ck[4], cv[4];
#pragma unroll
  for (int j = 0; j < 4; ++j) {
    cq[j] = conv_q[p * 4 + j];
    ck[j] = conv_k[p * 4 + j];
    cv[j] = conv_v[p * 4 + j];
  }
  const float aneg = -expf(A_log[h]);
  const float db = dt_bias[p];
  __shared__ float red[4];
  float cum = 0.f;
  for (int c = 0; c < Cc; ++c) {
    const int t = n * Cc + c;
    float qv = 0.f, kv = 0.f, vv = 0.f;
#pragma unroll
    for (int j = 0; j < 4; ++j) {
      int ts = t - 3 + j;
      if (ts >= 0) {
        size_t off = ((size_t)(b * Tc + ts)) * Pc + p;
        qv += cq[j] * bf2f(q_lin[off]);
        kv += ck[j] * bf2f(k_lin[off]);
        vv += cv[j] * bf2f(v_lin[off]);
      }
    }
    qv = qv / (1.f + expf(-qv));  // silu
    kv = kv / (1.f + expf(-kv));
    vv = vv / (1.f + expf(-vv));
    // block reduce sum of squares for q and k (128 threads = 2 waves)
    float a = qv * qv, bb = kv * kv;
#pragma unroll
    for (int off = 32; off > 0; off >>= 1) {
      a += __shfl_down(a, off, 64);
      bb += __shfl_down(bb, off, 64);
    }
    __syncthreads();  // protect red[] from previous iteration's readers
    if ((kk & 63) == 0) { red[(kk >> 6) * 2] = a; red[(kk >> 6) * 2 + 1] = bb; }
    __syncthreads();
    float sq = red[0] + red[2];
    float sk = red[1] + red[3];
    float qn = qv * rsqrtf(sq + 1e-12f) * 0.08838834764831845f;  // K^-0.5
    float kn = kv * rsqrtf(sk + 1e-12f);
    float g = bf2f(g_raw[((size_t)(b * Tc + t)) * Pc + p]) + db;
    float sp = (g > 20.f) ? g : log1pf(expf(g));
    cum += aneg * sp;
    float cc = fmaxf(cum, -15.f);
    float Wg = expf(cc);
    float Wi = expf(-cc);
    float beta = 1.f / (1.f + expf(-beta_lin[((size_t)(b * Tc + t)) * Hc + h]));
    size_t idx = ((size_t)blk * Cc + c) * Kc + kk;
    qt[idx] = f2bf(qn * Wg);
    u_[idx] = f2bf(kn * Wi);
    bw[idx] = f2bf(beta * kn * Wg);
    bv[idx] = f2bf(beta * vv);
    if (c == Cc - 1) wlast[(size_t)blk * Kc + kk] = Wg;
  }
}

// ---------------- chunk solve: L, intra, two forward substitutions (in-place ev/ew) ----
// grid: B*H*NC blocks, 256 threads
__global__ __launch_bounds__(256) void chunk_solve(
    const unsigned short* __restrict__ qt, const unsigned short* __restrict__ u_,
    unsigned short* __restrict__ evb,  // in: bv, out: ev
    unsigned short* __restrict__ ewb,  // in: bw, out: ew
    unsigned short* __restrict__ intra_out) {
  const int blk = blockIdx.x;
  const size_t base = (size_t)blk * (Cc * Kc);
  const int tid = threadIdx.x;
  const int j = tid & 63, g = tid >> 6;
  // overlay: uS (bf16 64x130, padded vs bank conflicts) then Lsm (f32 64x64)
  __shared__ __align__(16) char ovl_raw[64 * 130 * 2];
  unsigned short(*uS)[130] = reinterpret_cast<unsigned short(*)[130]>(ovl_raw);
  float(*Lsm)[64] = reinterpret_cast<float(*)[64]>(ovl_raw);
  __shared__ float wS[64][128];

#pragma unroll 8
  for (int pp = 0; pp < 32; ++pp) {
    int e = tid + pp * 256;
    uS[e >> 7][e & 127] = u_[base + e];
  }
#pragma unroll 8
  for (int pp = 0; pp < 32; ++pp) {
    int e = tid + pp * 256;
    wS[e >> 7][e & 127] = bf2f(ewb[base + e]);  // bw
  }
  __syncthreads();
  float Lacc[16];
#pragma unroll
  for (int ii = 0; ii < 16; ++ii) Lacc[ii] = 0.f;
  for (int k = 0; k < 128; ++k) {
    float uv = bf2f(uS[j][k]);
#pragma unroll
    for (int ii = 0; ii < 16; ++ii) Lacc[ii] += wS[g * 16 + ii][k] * uv;
  }
  __syncthreads();
#pragma unroll 8
  for (int pp = 0; pp < 32; ++pp) {
    int e = tid + pp * 256;
    wS[e >> 7][e & 127] = bf2f(qt[base + e]);
  }
  __syncthreads();
  float Iacc[16];
#pragma unroll
  for (int ii = 0; ii < 16; ++ii) Iacc[ii] = 0.f;
  for (int k = 0; k < 128; ++k) {
    float uv = bf2f(uS[j][k]);
#pragma unroll
    for (int ii = 0; ii < 16; ++ii) Iacc[ii] += wS[g * 16 + ii][k] * uv;
  }
  size_t ibase = (size_t)blk * (Cc * Cc);
#pragma unroll
  for (int ii = 0; ii < 16; ++ii) {
    int i = g * 16 + ii;
    intra_out[ibase + i * 64 + j] = f2bf((j <= i) ? Iacc[ii] : 0.f);
  }
  __syncthreads();  // all uS reads done; overlay with L
#pragma unroll
  for (int ii = 0; ii < 16; ++ii) Lsm[g * 16 + ii][j] = Lacc[ii];
  __syncthreads();
  // forward substitution for bv->ev then bw->ew (unit lower, strict-lower = Lsm)
  for (int s = 0; s < 2; ++s) {
    unsigned short* rb = (s == 0) ? evb : ewb;
#pragma unroll 8
    for (int pp = 0; pp < 32; ++pp) {
      int e = tid + pp * 256;
      wS[e >> 7][e & 127] = bf2f(rb[base + e]);
    }
    __syncthreads();
    const int col = tid & 127;
    for (int i = 1; i < 64; ++i) {
      if (tid < 128) {
        float sacc = 0.f;
        for (int jj = 0; jj < i; ++jj) sacc += Lsm[i][jj] * wS[jj][col];
        wS[i][col] -= sacc;
      }
      __syncthreads();
    }
#pragma unroll 8
    for (int pp = 0; pp < 32; ++pp) {
      int e = tid + pp * 256;
      rb[base + e] = f2bf(wS[e >> 7][e & 127]);
    }
    __syncthreads();
  }
}

// ---------------- sequential inter-chunk scan, split over 8 v-slices of 16 ----------------
// grid: 256 blocks (blk = b*128 + h*8 + vs), 256 threads
__global__ __launch_bounds__(256) void scan_kernel(
    const unsigned short* __restrict__ qt, const unsigned short* __restrict__ u_,
    const unsigned short* __restrict__ evb, const unsigned short* __restrict__ ewb,
    const unsigned short* __restrict__ intra, const float* __restrict__ wlast,
    unsigned short* __restrict__ attn_o, float* __restrict__ snapraw) {
  const int blk = blockIdx.x;
  const int vs = blk & 7;
  const int h = (blk >> 3) & 15;
  const int b = blk >> 7;
  const int v0 = vs * 16;
  const int tid = threadIdx.x;
  const int v = tid & 15;
  const int cg = tid >> 4;  // 0..15
  __shared__ float S[128][16];    // state slice
  __shared__ float Wbuf[64][132]; // staged ew / qt / u (padded)
  __shared__ float Ia[64][68];    // staged intra (padded)
  __shared__ float Dl[64][16];    // delta
#pragma unroll
  for (int r = 0; r < 8; ++r) S[cg + r * 16][v] = 0.f;
  const int bh = b * Hc + h;
  __syncthreads();
  for (int n = 0; n < NCc; ++n) {
    const size_t cb = ((size_t)bh * NCc + n) * (Cc * Kc);
    const size_t ib = ((size_t)bh * NCc + n) * (Cc * Cc);
    // stage ew + intra
#pragma unroll 8
    for (int pp = 0; pp < 32; ++pp) {
      int e = tid + pp * 256;
      Wbuf[e >> 7][e & 127] = bf2f(ewb[cb + e]);
    }
#pragma unroll 8
    for (int pp = 0; pp < 16; ++pp) {
      int e = tid + pp * 256;
      Ia[e >> 6][e & 63] = bf2f(intra[ib + e]);
    }
    __syncthreads();
    // delta = ev - ew @ S
    float dv[4];
#pragma unroll
    for (int qq = 0; qq < 4; ++qq) {
      int c = cg + qq * 16;
      float acc = bf2f(evb[cb + c * Kc + v0 + v]);
      for (int k = 0; k < 128; ++k) acc -= Wbuf[c][k] * S[k][v];
      dv[qq] = acc;
    }
#pragma unroll
    for (int qq = 0; qq < 4; ++qq) Dl[cg + qq * 16][v] = dv[qq];
    __syncthreads();  // delta done; Wbuf free
    // stage qt
#pragma unroll 8
    for (int pp = 0; pp < 32; ++pp) {
      int e = tid + pp * 256;
      Wbuf[e >> 7][e & 127] = bf2f(qt[cb + e]);
    }
    __syncthreads();
    // o = qt @ S + intra @ delta
#pragma unroll
    for (int qq = 0; qq < 4; ++qq) {
      int c = cg + qq * 16;
      float acc = 0.f;
      for (int k = 0; k < 128; ++k) acc += Wbuf[c][k] * S[k][v];
      for (int jj = 0; jj < 64; ++jj) acc += Ia[c][jj] * Dl[jj][v];
      int t = n * Cc + c;
      attn_o[((size_t)(b * Tc + t) * Hc + h) * Kc + v0 + v] = f2bf(acc);
    }
    __syncthreads();  // Wbuf free
    // stage u
#pragma unroll 8
    for (int pp = 0; pp < 32; ++pp) {
      int e = tid + pp * 256;
      Wbuf[e >> 7][e & 127] = bf2f(u_[cb + e]);
    }
    __syncthreads();
    // S = wl[k] * (S + u^T @ delta)
#pragma unroll
    for (int r = 0; r < 8; ++r) {
      int k = cg + r * 16;
      float acc = S[k][v];
      for (int c2 = 0; c2 < 64; ++c2) acc += Wbuf[c2][k] * Dl[c2][v];
      acc *= wlast[((size_t)bh * NCc + n) * Kc + k];
      S[k][v] = acc;
    }
    __syncthreads();
    if ((n & 3) == 3) {
      int ns = n >> 2;
      size_t sb = ((((size_t)ns * Bc + b) * Hc + h) * Kc) * Kc;
#pragma unroll
      for (int r = 0; r < 8; ++r) {
        int k = cg + r * 16;
        snapraw[sb + (size_t)k * Kc + v0 + v] = S[k][v];
      }
    }
  }
}

// ---------------- snapshot helpers ----------------
__global__ void sdw_mul(const float* __restrict__ snap_down, const float* __restrict__ w,
                        float* __restrict__ sdw) {
  int i = blockIdx.x * 256 + threadIdx.x;  // LAT*K*K = 2097152 total
  sdw[i] = snap_down[i] * w[i & 16383];
}

__global__ __launch_bounds__(256) void snap_scale_kernel(const float* __restrict__ snapraw,
                                                         float* __restrict__ scale) {
  int r = blockIdx.x;  // 512 rows
  const float* row = snapraw + (size_t)r * 16384;
  float s = 0.f;
  for (int ii = threadIdx.x; ii < 16384; ii += 256) {
    float x = row[ii];
    s += x * x;
  }
#pragma unroll
  for (int off = 32; off > 0; off >>= 1) s += __shfl_down(s, off, 64);
  __shared__ float red[4];
  if ((threadIdx.x & 63) == 0) red[threadIdx.x >> 6] = s;
  __syncthreads();
  if (threadIdx.x == 0) {
    float tot = red[0] + red[1] + red[2] + red[3];
    scale[r] = rsqrtf(tot * (1.f / 16384.f) + 1e-6f);
  }
}

__global__ void snap_scatter(const float* __restrict__ snap_out,
                             const float* __restrict__ scale, float* __restrict__ outp) {
  int idx = blockIdx.x * 256 + threadIdx.x;  // B*NS*H*LAT = 65536, layout (b,ns,h,l)
  int l = idx & 127;
  int hh = (idx >> 7) & 15;
  int ns = (idx >> 11) & 15;
  int bb = idx >> 15;
  int r = (ns * Bc + bb) * Hc + hh;  // snapraw row order (ns,b,h)
  outp[idx] = snap_out[r * 128 + l] * scale[r];
}

// ---------------- final rmsnorm * sigmoid(gate), in-place on attn buffer --------------
__global__ __launch_bounds__(128) void out_norm_gate(unsigned short* __restrict__ attn_io,
                                                     const unsigned short* __restrict__ gate_raw,
                                                     const float* __restrict__ bgb,
                                                     const float* __restrict__ o_norm_w) {
  const int blk = blockIdx.x;  // (b*T + t)*H + h
  const int kk = threadIdx.x;
  const int h = blk & 15;
  const size_t row = (size_t)(blk >> 4);  // b*T + t
  const int p = h * Kc + kk;
  const size_t base = (size_t)blk * Kc;
  float x = bf2f(attn_io[base + kk]);
  float ss = x * x;
#pragma unroll
  for (int off = 32; off > 0; off >>= 1) ss += __shfl_down(ss, off, 64);
  __shared__ float red[2];
  if ((kk & 63) == 0) red[kk >> 6] = ss;
  __syncthreads();
  float tot = red[0] + red[1];
  float normed = x * rsqrtf(tot * (1.f / 128.f) + 1e-6f) * o_norm_w[kk];
  float g = bf2f(gate_raw[row * Pc + p]) + bgb[p];
  float o = normed / (1.f + expf(-g));
  attn_io[base + kk] = f2bf(o);
}

// ---------------- launch ----------------
extern "C" void kernel_launch(void* const* d_in, const int* in_sizes, int n_in,
                              void* d_out, int out_size, void* d_ws, size_t ws_size,
                              hipStream_t stream) {
  (void)in_sizes; (void)n_in;
  const float* x        = (const float*)d_in[0];
  const float* Wq       = (const float*)d_in[1];
  const float* Wk       = (const float*)d_in[2];
  const float* Wv       = (const float*)d_in[3];
  const float* conv_q   = (const float*)d_in[4];
  const float* conv_k   = (const float*)d_in[5];
  const float* conv_v   = (const float*)d_in[6];
  const float* A_log    = (const float*)d_in[7];
  const float* dt_bias  = (const float*)d_in[8];
  const float* Wfa      = (const float*)d_in[9];
  const float* Wfb      = (const float*)d_in[10];
  const float* Wb       = (const float*)d_in[11];
  const float* Wga      = (const float*)d_in[12];
  const float* Wgb      = (const float*)d_in[13];
  const float* bgb      = (const float*)d_in[14];
  const float* o_norm_w = (const float*)d_in[15];
  const float* Wo       = (const float*)d_in[16];
  const float* snap_nw  = (const float*)d_in[17];
  const float* snap_down= (const float*)d_in[18];

  // ---- workspace layout (peak ~211.3 MB) ----
  const size_t MP2 = (size_t)Mc * Pc * 2;             // 33,554,432 B (bf16 M x P)
  const size_t NEED = 6 * MP2                          // q,k,v,g_raw,evb,ewb
                    + 2 * (size_t)Mc * Kc * 4          // fa, ga
                    + (size_t)Mc * Hc * 4              // betab
                    + (size_t)Bc * Hc * NCc * Kc * 4;  // wlast
  if (ws_size < NEED + 4096) {
    // graceful fail: leaves zeros -> absmax = max|ref|, diagnosable (not a fault)
    hipMemsetAsync(d_out, 0, (size_t)out_size * 4, stream);
    return;
  }
  char* w = (char*)d_ws;
  auto alloc = [&](size_t bytes) {
    char* r = w;
    w += (bytes + 255) & ~(size_t)255;
    return r;
  };
  unsigned short* q_lin    = (unsigned short*)alloc(MP2);  // later: intra
  unsigned short* k_lin    = (unsigned short*)alloc(MP2);  // later: attn
  unsigned short* v_lin    = (unsigned short*)alloc(MP2);  // later: snapraw (f32, exact fit)
  unsigned short* g_raw    = (unsigned short*)alloc(MP2);  // later: gate_raw
  unsigned short* evb      = (unsigned short*)alloc(MP2);  // bv -> ev; later: sdw
  unsigned short* ewb      = (unsigned short*)alloc(MP2);  // bw -> ew; later: snap_out/scale
  float* fa    = (float*)alloc((size_t)Mc * Kc * 4);
  float* ga    = (float*)alloc((size_t)Mc * Kc * 4);
  float* betab = (float*)alloc((size_t)Mc * Hc * 4);
  float* wlast = (float*)alloc((size_t)Bc * Hc * NCc * Kc * 4);

  // qt + u live in d_out's y-region (exactly 64 MB, dead before y is written)
  unsigned short* qt = (unsigned short*)d_out;
  unsigned short* u_ = (unsigned short*)((char*)d_out + MP2);

  // aliases of dead ws buffers (byte-exact, no overlap):
  //   sdw      -> evb region, bytes [0, 8.39 MB)  (LAT*16384 f32)
  //   snap_out -> ewb region, bytes [0, 262 KB)   (512*128 f32)
  //   snapscale-> ewb region, bytes [262 KB, +2KB) (512 f32)
  unsigned short* intra    = q_lin;                    // 16.8 MB needed, 33.5 avail
  unsigned short* attn     = k_lin;
  float*          snapraw  = (float*)v_lin;            // 512 x 16384 f32 = 33.5 MB exact
  unsigned short* gate_raw = g_raw;
  float* sdw       = (float*)evb;                      // 8.4 MB, evb dead after scan
  float* snap_out  = (float*)ewb;                      // 512 x 128 f32, ewb dead after scan
  float* snapscale = (float*)ewb + (size_t)512 * 128;  // 512 f32, right after snap_out

  float* y = (float*)d_out;
  float* snaps_out = (float*)d_out + (size_t)Bc * Tc * Dc;

  // 1) input GEMMs
  gemm_nt<float, float, unsigned short><<<dim3(64, 32), 256, 0, stream>>>(x, Wq, q_lin, Pc, Dc);
  gemm_nt<float, float, unsigned short><<<dim3(64, 32), 256, 0, stream>>>(x, Wk, k_lin, Pc, Dc);
  gemm_nt<float, float, unsigned short><<<dim3(64, 32), 256, 0, stream>>>(x, Wv, v_lin, Pc, Dc);
  gemm_nt<float, float, float><<<dim3(64, 2), 256, 0, stream>>>(x, Wfa, fa, Kc, Dc);
  gemm_nt<float, float, float><<<dim3(64, 2), 256, 0, stream>>>(x, Wga, ga, Kc, Dc);
  gemm_nt<float, float, float><<<dim3(64, 1), 256, 0, stream>>>(x, Wb, betab, Hc, Dc);
  gemm_nt<float, float, unsigned short><<<dim3(64, 32), 256, 0, stream>>>(fa, Wfb, g_raw, Pc, Kc);

  // 2) per-chunk prep + UT transform (qt,u -> d_out scratch; bv->evb, bw->ewb in ws)
  chunk_prep<<<Bc * Hc * NCc, 128, 0, stream>>>(q_lin, k_lin, v_lin, g_raw, betab, conv_q,
                                                conv_k, conv_v, A_log, dt_bias, qt, u_, evb,
                                                ewb, wlast);
  chunk_solve<<<Bc * Hc * NCc, 256, 0, stream>>>(qt, u_, evb, ewb, intra);  // intra -> q_lin region

  // 3) gate projection (g_raw region now dead -> gate_raw)
  gemm_nt<float, float, unsigned short><<<dim3(64, 32), 256, 0, stream>>>(ga, Wgb, gate_raw, Pc, Kc);

  // 4) sequential scan (v-sliced); attn -> k_lin region, snapraw -> v_lin region
  scan_kernel<<<256, 256, 0, stream>>>(qt, u_, evb, ewb, intra, wlast, attn, snapraw);

  // 5) snapshots (evb/ewb regions now dead -> sdw / snap_out / snapscale)
  sdw_mul<<<8192, 256, 0, stream>>>(snap_down, snap_nw, sdw);
  snap_scale_kernel<<<512, 256, 0, stream>>>(snapraw, snapscale);
  gemm_nt<float, float, float><<<dim3(4, 2), 256, 0, stream>>>(snapraw, sdw, snap_out, LATc, 16384);
  snap_scatter<<<256, 256, 0, stream>>>(snap_out, snapscale, snaps_out);

  // 6) output norm*gate + final projection (qt/u in d_out dead now; y overwrites them)
  out_norm_gate<<<Mc * Hc, 128, 0, stream>>>(attn, gate_raw, bgb, o_norm_w);
  gemm_nt<unsigned short, float, float><<<dim3(64, 32), 256, 0, stream>>>(attn, Wo, y, Dc, Pc);
}

// Round 4
// 4236.272 us; speedup vs baseline: 1.8878x; 1.8878x over previous
//
#include <hip/hip_runtime.h>

// ---------------- problem constants ----------------
constexpr int Bc   = 2;
constexpr int Tc   = 4096;
constexpr int Dc   = 2048;
constexpr int Hc   = 16;
constexpr int Kc   = 128;
constexpr int Pc   = Hc * Kc;     // 2048
constexpr int Cc   = 64;          // chunk size
constexpr int NCc  = Tc / Cc;     // 64 chunks
constexpr int Mc   = Bc * Tc;     // 8192 rows
constexpr int LATc = 128;

// ---------------- helpers ----------------
__device__ __forceinline__ float bf2f(unsigned short u) {
  unsigned int x = ((unsigned int)u) << 16;
  return __builtin_bit_cast(float, x);
}
__device__ __forceinline__ unsigned short f2bf(float f) {
  unsigned int x = __builtin_bit_cast(unsigned int, f);
  x += 0x7fffu + ((x >> 16) & 1u);
  return (unsigned short)(x >> 16);
}
__device__ __forceinline__ float4 ld4(const float* p) {
  return *reinterpret_cast<const float4*>(p);
}
__device__ __forceinline__ float4 ld4(const unsigned short* p) {
  ushort4 u = *reinterpret_cast<const ushort4*>(p);
  return make_float4(bf2f(u.x), bf2f(u.y), bf2f(u.z), bf2f(u.w));
}
__device__ __forceinline__ void st1(float* p, float v) { *p = v; }
__device__ __forceinline__ void st1(unsigned short* p, float v) { *p = f2bf(v); }

// ---------------- f32 -> bf16 cast (n multiple of 4; grid covers n/4 threads) ----
__global__ void cast_f32_bf16(const float* __restrict__ in, unsigned short* __restrict__ out,
                              int n) {
  int i = (blockIdx.x * 256 + threadIdx.x) * 4;
  if (i < n) {
    float4 v = ld4(in + i);
    ushort4 o;
    o.x = f2bf(v.x); o.y = f2bf(v.y); o.z = f2bf(v.z); o.w = f2bf(v.w);
    *reinterpret_cast<ushort4*>(out + i) = o;
  }
}

// ---------------- bf16 MFMA NT GEMM: Out[M,N] = A[M,Kd] * Bm[N,Kd]^T ----------------
// 128x128 tile, 256 threads (4 waves, 2x2), each wave 64x64 via 4x4 frags of 16x16x32.
// Requires: M%128==0, N%128==0, Kd%32==0. global_load_lds width-16 staging (m97 recipe).
typedef __attribute__((ext_vector_type(8))) short bf16x8;
typedef __attribute__((ext_vector_type(4))) float f32x4;

__device__ __forceinline__ void gload_lds16(const unsigned short* g, unsigned short* l) {
  __builtin_amdgcn_global_load_lds(
      (const __attribute__((address_space(1))) void*)g,
      (__attribute__((address_space(3))) void*)l, 16, 0, 0);
}

template <typename OT>
__global__ __launch_bounds__(256) void gemm_nt_mfma(const unsigned short* __restrict__ A,
                                                    const unsigned short* __restrict__ Bm,
                                                    OT* __restrict__ Out,
                                                    int Ndim, int Kd) {
  __shared__ __align__(16) unsigned short As[128 * 32];
  __shared__ __align__(16) unsigned short Bs[128 * 32];
  const int m0 = blockIdx.x * 128;
  const int n0 = blockIdx.y * 128;
  const int tid = threadIdx.x;
  const int wave = tid >> 6;
  const int lane = tid & 63;
  const int wr = wave >> 1, wc = wave & 1;
  const int l15 = lane & 15, l4 = lane >> 4;
  f32x4 acc[4][4] = {};

  for (int k0 = 0; k0 < Kd; k0 += 32) {
    // stage 128x32 bf16 tiles of A and B^T: per wave 2 issues x 64 lanes x 16B
#pragma unroll
    for (int i = 0; i < 2; ++i) {
      int e = (wave * 2 + i) * 512 + lane * 8;  // element in [0,4096)
      int r = e >> 5, c = e & 31;
      gload_lds16(&A[(size_t)(m0 + r) * Kd + k0 + c], &As[(wave * 2 + i) * 512]);
      gload_lds16(&Bm[(size_t)(n0 + r) * Kd + k0 + c], &Bs[(wave * 2 + i) * 512]);
    }
    __syncthreads();  // drains vmcnt (compiler emits waitcnt before barrier)
    bf16x8 af[4], bfr[4];
#pragma unroll
    for (int m = 0; m < 4; ++m)
      af[m] = *reinterpret_cast<const bf16x8*>(&As[(wr * 64 + m * 16 + l15) * 32 + l4 * 8]);
#pragma unroll
    for (int n = 0; n < 4; ++n)
      bfr[n] = *reinterpret_cast<const bf16x8*>(&Bs[(wc * 64 + n * 16 + l15) * 32 + l4 * 8]);
#pragma unroll
    for (int m = 0; m < 4; ++m)
#pragma unroll
      for (int n = 0; n < 4; ++n)
        acc[m][n] = __builtin_amdgcn_mfma_f32_16x16x32_bf16(af[m], bfr[n], acc[m][n], 0, 0, 0);
    __syncthreads();
  }
  // C/D layout: col = lane&15, row = (lane>>4)*4 + reg  (verified m89/m91)
#pragma unroll
  for (int m = 0; m < 4; ++m)
#pragma unroll
    for (int n = 0; n < 4; ++n)
#pragma unroll
      for (int r = 0; r < 4; ++r) {
        int row = m0 + wr * 64 + m * 16 + l4 * 4 + r;
        int col = n0 + wc * 64 + n * 16 + l15;
        st1(&Out[(size_t)row * Ndim + col], acc[m][n][r]);
      }
}

// ---------------- generic fp32 NT GEMM (kept for N=16 beta and K=16384 snap) --------
template <typename AT, typename BT, typename OT>
__global__ __launch_bounds__(256) void gemm_nt(const AT* __restrict__ A,
                                               const BT* __restrict__ Bm,
                                               OT* __restrict__ Out,
                                               int Ndim, int Kd) {
  __shared__ float As[32][132];  // transposed: As[k][m]
  __shared__ float Bs[32][68];   // transposed: Bs[k][n]
  const int m0 = blockIdx.x * 128;
  const int n0 = blockIdx.y * 64;
  const int tid = threadIdx.x;
  const int tx = tid & 15, ty = tid >> 4;
  float acc[8][4];
#pragma unroll
  for (int i = 0; i < 8; ++i)
#pragma unroll
    for (int j = 0; j < 4; ++j) acc[i][j] = 0.f;

  for (int k0 = 0; k0 < Kd; k0 += 32) {
#pragma unroll
    for (int p = 0; p < 4; ++p) {
      int e = tid + p * 256;     // 0..1023 -> 128 rows x 8 float4
      int r = e >> 3;
      int c = (e & 7) << 2;
      float4 v = ld4(A + (size_t)(m0 + r) * Kd + k0 + c);
      As[c + 0][r] = v.x; As[c + 1][r] = v.y; As[c + 2][r] = v.z; As[c + 3][r] = v.w;
    }
#pragma unroll
    for (int p = 0; p < 2; ++p) {
      int e = tid + p * 256;     // 0..511 -> 64 rows x 8 float4
      int r = e >> 3;
      int c = (e & 7) << 2;
      float4 v = make_float4(0.f, 0.f, 0.f, 0.f);
      if (n0 + r < Ndim) v = ld4(Bm + (size_t)(n0 + r) * Kd + k0 + c);
      Bs[c + 0][r] = v.x; Bs[c + 1][r] = v.y; Bs[c + 2][r] = v.z; Bs[c + 3][r] = v.w;
    }
    __syncthreads();
#pragma unroll
    for (int kk = 0; kk < 32; ++kk) {
      const float4* ar = reinterpret_cast<const float4*>(&As[kk][0]);
      const float4* br = reinterpret_cast<const float4*>(&Bs[kk][0]);
      float4 b4 = br[tx];
      float4 a0 = ar[ty * 2], a1 = ar[ty * 2 + 1];
      float av[8] = {a0.x, a0.y, a0.z, a0.w, a1.x, a1.y, a1.z, a1.w};
      float bv4[4] = {b4.x, b4.y, b4.z, b4.w};
#pragma unroll
      for (int i = 0; i < 8; ++i)
#pragma unroll
        for (int j = 0; j < 4; ++j) acc[i][j] = fmaf(av[i], bv4[j], acc[i][j]);
    }
    __syncthreads();
  }
#pragma unroll
  for (int i = 0; i < 8; ++i) {
    int m = m0 + ty * 8 + i;
#pragma unroll
    for (int j = 0; j < 4; ++j) {
      int n = n0 + tx * 4 + j;
      if (n < Ndim) st1(Out + (size_t)m * Ndim + n, acc[i][j]);
    }
  }
}

// ---------------- chunk prep: conv+silu, l2norm, gates, beta; writes qt,u,bw,bv,wlast ----
// grid: B*H*NC blocks (blk = (b*H+h)*NC + n), 128 threads (one per k-channel)
__global__ __launch_bounds__(128) void chunk_prep(
    const unsigned short* __restrict__ q_lin, const unsigned short* __restrict__ k_lin,
    const unsigned short* __restrict__ v_lin, const unsigned short* __restrict__ g_raw,
    const float* __restrict__ beta_lin, const float* __restrict__ conv_q,
    const float* __restrict__ conv_k, const float* __restrict__ conv_v,
    const float* __restrict__ A_log, const float* __restrict__ dt_bias,
    unsigned short* __restrict__ qt, unsigned short* __restrict__ u_,
    unsigned short* __restrict__ bv, unsigned short* __restrict__ bw,
    float* __restrict__ wlast) {
  const int blk = blockIdx.x;
  const int n = blk & 63;
  const int h = (blk >> 6) & 15;
  const int b = blk >> 10;
  const int kk = threadIdx.x;
  const int p = h * Kc + kk;
  float cq[4], ck[4], cv[4];
#pragma unroll
  for (int j = 0; j < 4; ++j) {
    cq[j] = conv_q[p * 4 + j];
    ck[j] = conv_k[p * 4 + j];
    cv[j] = conv_v[p * 4 + j];
  }
  const float aneg = -expf(A_log[h]);
  const float db = dt_bias[p];
  __shared__ float red[4];
  float cum = 0.f;
  for (int c = 0; c < Cc; ++c) {
    const int t = n * Cc + c;
    float qv = 0.f, kv = 0.f, vv = 0.f;
#pragma unroll
    for (int j = 0; j < 4; ++j) {
      int ts = t - 3 + j;
      if (ts >= 0) {
        size_t off = ((size_t)(b * Tc + ts)) * Pc + p;
        qv += cq[j] * bf2f(q_lin[off]);
        kv += ck[j] * bf2f(k_lin[off]);
        vv += cv[j] * bf2f(v_lin[off]);
      }
    }
    qv = qv / (1.f + expf(-qv));  // silu
    kv = kv / (1.f + expf(-kv));
    vv = vv / (1.f + expf(-vv));
    // block reduce sum of squares for q and k (128 threads = 2 waves)
    float a = qv * qv, bb = kv * kv;
#pragma unroll
    for (int off = 32; off > 0; off >>= 1) {
      a += __shfl_down(a, off, 64);
      bb += __shfl_down(bb, off, 64);
    }
    __syncthreads();  // protect red[] from previous iteration's readers
    if ((kk & 63) == 0) { red[(kk >> 6) * 2] = a; red[(kk >> 6) * 2 + 1] = bb; }
    __syncthreads();
    float sq = red[0] + red[2];
    float sk = red[1] + red[3];
    float qn = qv * rsqrtf(sq + 1e-12f) * 0.08838834764831845f;  // K^-0.5
    float kn = kv * rsqrtf(sk + 1e-12f);
    float g = bf2f(g_raw[((size_t)(b * Tc + t)) * Pc + p]) + db;
    float sp = (g > 20.f) ? g : log1pf(expf(g));
    cum += aneg * sp;
    float cc = fmaxf(cum, -15.f);
    float Wg = expf(cc);
    float Wi = expf(-cc);
    float beta = 1.f / (1.f + expf(-beta_lin[((size_t)(b * Tc + t)) * Hc + h]));
    size_t idx = ((size_t)blk * Cc + c) * Kc + kk;
    qt[idx] = f2bf(qn * Wg);
    u_[idx] = f2bf(kn * Wi);
    bw[idx] = f2bf(beta * kn * Wg);
    bv[idx] = f2bf(beta * vv);
    if (c == Cc - 1) wlast[(size_t)blk * Kc + kk] = Wg;
  }
}

// ---------------- chunk solve: L, intra, two forward substitutions (in-place ev/ew) ----
// grid: B*H*NC blocks, 256 threads
__global__ __launch_bounds__(256) void chunk_solve(
    const unsigned short* __restrict__ qt, const unsigned short* __restrict__ u_,
    unsigned short* __restrict__ evb,  // in: bv, out: ev
    unsigned short* __restrict__ ewb,  // in: bw, out: ew
    unsigned short* __restrict__ intra_out) {
  const int blk = blockIdx.x;
  const size_t base = (size_t)blk * (Cc * Kc);
  const int tid = threadIdx.x;
  const int j = tid & 63, g = tid >> 6;
  // overlay: uS (bf16 64x130, padded vs bank conflicts) then Lsm (f32 64x64)
  __shared__ __align__(16) char ovl_raw[64 * 130 * 2];
  unsigned short(*uS)[130] = reinterpret_cast<unsigned short(*)[130]>(ovl_raw);
  float(*Lsm)[64] = reinterpret_cast<float(*)[64]>(ovl_raw);
  __shared__ float wS[64][128];

#pragma unroll 8
  for (int pp = 0; pp < 32; ++pp) {
    int e = tid + pp * 256;
    uS[e >> 7][e & 127] = u_[base + e];
  }
#pragma unroll 8
  for (int pp = 0; pp < 32; ++pp) {
    int e = tid + pp * 256;
    wS[e >> 7][e & 127] = bf2f(ewb[base + e]);  // bw
  }
  __syncthreads();
  float Lacc[16];
#pragma unroll
  for (int ii = 0; ii < 16; ++ii) Lacc[ii] = 0.f;
  for (int k = 0; k < 128; ++k) {
    float uv = bf2f(uS[j][k]);
#pragma unroll
    for (int ii = 0; ii < 16; ++ii) Lacc[ii] += wS[g * 16 + ii][k] * uv;
  }
  __syncthreads();
#pragma unroll 8
  for (int pp = 0; pp < 32; ++pp) {
    int e = tid + pp * 256;
    wS[e >> 7][e & 127] = bf2f(qt[base + e]);
  }
  __syncthreads();
  float Iacc[16];
#pragma unroll
  for (int ii = 0; ii < 16; ++ii) Iacc[ii] = 0.f;
  for (int k = 0; k < 128; ++k) {
    float uv = bf2f(uS[j][k]);
#pragma unroll
    for (int ii = 0; ii < 16; ++ii) Iacc[ii] += wS[g * 16 + ii][k] * uv;
  }
  size_t ibase = (size_t)blk * (Cc * Cc);
#pragma unroll
  for (int ii = 0; ii < 16; ++ii) {
    int i = g * 16 + ii;
    intra_out[ibase + i * 64 + j] = f2bf((j <= i) ? Iacc[ii] : 0.f);
  }
  __syncthreads();  // all uS reads done; overlay with L
#pragma unroll
  for (int ii = 0; ii < 16; ++ii) Lsm[g * 16 + ii][j] = Lacc[ii];
  __syncthreads();
  // forward substitution for bv->ev then bw->ew (unit lower, strict-lower = Lsm)
  for (int s = 0; s < 2; ++s) {
    unsigned short* rb = (s == 0) ? evb : ewb;
#pragma unroll 8
    for (int pp = 0; pp < 32; ++pp) {
      int e = tid + pp * 256;
      wS[e >> 7][e & 127] = bf2f(rb[base + e]);
    }
    __syncthreads();
    const int col = tid & 127;
    for (int i = 1; i < 64; ++i) {
      if (tid < 128) {
        float sacc = 0.f;
        for (int jj = 0; jj < i; ++jj) sacc += Lsm[i][jj] * wS[jj][col];
        wS[i][col] -= sacc;
      }
      __syncthreads();
    }
#pragma unroll 8
    for (int pp = 0; pp < 32; ++pp) {
      int e = tid + pp * 256;
      rb[base + e] = f2bf(wS[e >> 7][e & 127]);
    }
    __syncthreads();
  }
}

// ---------------- sequential inter-chunk scan, split over 8 v-slices of 16 ----------------
// grid: 256 blocks (blk = b*128 + h*8 + vs), 256 threads
__global__ __launch_bounds__(256) void scan_kernel(
    const unsigned short* __restrict__ qt, const unsigned short* __restrict__ u_,
    const unsigned short* __restrict__ evb, const unsigned short* __restrict__ ewb,
    const unsigned short* __restrict__ intra, const float* __restrict__ wlast,
    unsigned short* __restrict__ attn_o, float* __restrict__ snapraw) {
  const int blk = blockIdx.x;
  const int vs = blk & 7;
  const int h = (blk >> 3) & 15;
  const int b = blk >> 7;
  const int v0 = vs * 16;
  const int tid = threadIdx.x;
  const int v = tid & 15;
  const int cg = tid >> 4;  // 0..15
  __shared__ float S[128][16];    // state slice
  __shared__ float Wbuf[64][132]; // staged ew / qt / u (padded)
  __shared__ float Ia[64][68];    // staged intra (padded)
  __shared__ float Dl[64][16];    // delta
#pragma unroll
  for (int r = 0; r < 8; ++r) S[cg + r * 16][v] = 0.f;
  const int bh = b * Hc + h;
  __syncthreads();
  for (int n = 0; n < NCc; ++n) {
    const size_t cb = ((size_t)bh * NCc + n) * (Cc * Kc);
    const size_t ib = ((size_t)bh * NCc + n) * (Cc * Cc);
    // stage ew + intra
#pragma unroll 8
    for (int pp = 0; pp < 32; ++pp) {
      int e = tid + pp * 256;
      Wbuf[e >> 7][e & 127] = bf2f(ewb[cb + e]);
    }
#pragma unroll 8
    for (int pp = 0; pp < 16; ++pp) {
      int e = tid + pp * 256;
      Ia[e >> 6][e & 63] = bf2f(intra[ib + e]);
    }
    __syncthreads();
    // delta = ev - ew @ S
    float dv[4];
#pragma unroll
    for (int qq = 0; qq < 4; ++qq) {
      int c = cg + qq * 16;
      float acc = bf2f(evb[cb + c * Kc + v0 + v]);
      for (int k = 0; k < 128; ++k) acc -= Wbuf[c][k] * S[k][v];
      dv[qq] = acc;
    }
#pragma unroll
    for (int qq = 0; qq < 4; ++qq) Dl[cg + qq * 16][v] = dv[qq];
    __syncthreads();  // delta done; Wbuf free
    // stage qt
#pragma unroll 8
    for (int pp = 0; pp < 32; ++pp) {
      int e = tid + pp * 256;
      Wbuf[e >> 7][e & 127] = bf2f(qt[cb + e]);
    }
    __syncthreads();
    // o = qt @ S + intra @ delta
#pragma unroll
    for (int qq = 0; qq < 4; ++qq) {
      int c = cg + qq * 16;
      float acc = 0.f;
      for (int k = 0; k < 128; ++k) acc += Wbuf[c][k] * S[k][v];
      for (int jj = 0; jj < 64; ++jj) acc += Ia[c][jj] * Dl[jj][v];
      int t = n * Cc + c;
      attn_o[((size_t)(b * Tc + t) * Hc + h) * Kc + v0 + v] = f2bf(acc);
    }
    __syncthreads();  // Wbuf free
    // stage u
#pragma unroll 8
    for (int pp = 0; pp < 32; ++pp) {
      int e = tid + pp * 256;
      Wbuf[e >> 7][e & 127] = bf2f(u_[cb + e]);
    }
    __syncthreads();
    // S = wl[k] * (S + u^T @ delta)
#pragma unroll
    for (int r = 0; r < 8; ++r) {
      int k = cg + r * 16;
      float acc = S[k][v];
      for (int c2 = 0; c2 < 64; ++c2) acc += Wbuf[c2][k] * Dl[c2][v];
      acc *= wlast[((size_t)bh * NCc + n) * Kc + k];
      S[k][v] = acc;
    }
    __syncthreads();
    if ((n & 3) == 3) {
      int ns = n >> 2;
      size_t sb = ((((size_t)ns * Bc + b) * Hc + h) * Kc) * Kc;
#pragma unroll
      for (int r = 0; r < 8; ++r) {
        int k = cg + r * 16;
        snapraw[sb + (size_t)k * Kc + v0 + v] = S[k][v];
      }
    }
  }
}

// ---------------- snapshot helpers ----------------
__global__ void sdw_mul(const float* __restrict__ snap_down, const float* __restrict__ w,
                        float* __restrict__ sdw) {
  int i = blockIdx.x * 256 + threadIdx.x;  // LAT*K*K = 2097152 total
  sdw[i] = snap_down[i] * w[i & 16383];
}

__global__ __launch_bounds__(256) void snap_scale_kernel(const float* __restrict__ snapraw,
                                                         float* __restrict__ scale) {
  int r = blockIdx.x;  // 512 rows
  const float* row = snapraw + (size_t)r * 16384;
  float s = 0.f;
  for (int ii = threadIdx.x; ii < 16384; ii += 256) {
    float x = row[ii];
    s += x * x;
  }
#pragma unroll
  for (int off = 32; off > 0; off >>= 1) s += __shfl_down(s, off, 64);
  __shared__ float red[4];
  if ((threadIdx.x & 63) == 0) red[threadIdx.x >> 6] = s;
  __syncthreads();
  if (threadIdx.x == 0) {
    float tot = red[0] + red[1] + red[2] + red[3];
    scale[r] = rsqrtf(tot * (1.f / 16384.f) + 1e-6f);
  }
}

__global__ void snap_scatter(const float* __restrict__ snap_out,
                             const float* __restrict__ scale, float* __restrict__ outp) {
  int idx = blockIdx.x * 256 + threadIdx.x;  // B*NS*H*LAT = 65536, layout (b,ns,h,l)
  int l = idx & 127;
  int hh = (idx >> 7) & 15;
  int ns = (idx >> 11) & 15;
  int bb = idx >> 15;
  int r = (ns * Bc + bb) * Hc + hh;  // snapraw row order (ns,b,h)
  outp[idx] = snap_out[r * 128 + l] * scale[r];
}

// ---------------- final rmsnorm * sigmoid(gate), in-place on attn buffer --------------
__global__ __launch_bounds__(128) void out_norm_gate(unsigned short* __restrict__ attn_io,
                                                     const unsigned short* __restrict__ gate_raw,
                                                     const float* __restrict__ bgb,
                                                     const float* __restrict__ o_norm_w) {
  const int blk = blockIdx.x;  // (b*T + t)*H + h
  const int kk = threadIdx.x;
  const int h = blk & 15;
  const size_t row = (size_t)(blk >> 4);  // b*T + t
  const int p = h * Kc + kk;
  const size_t base = (size_t)blk * Kc;
  float x = bf2f(attn_io[base + kk]);
  float ss = x * x;
#pragma unroll
  for (int off = 32; off > 0; off >>= 1) ss += __shfl_down(ss, off, 64);
  __shared__ float red[2];
  if ((kk & 63) == 0) red[kk >> 6] = ss;
  __syncthreads();
  float tot = red[0] + red[1];
  float normed = x * rsqrtf(tot * (1.f / 128.f) + 1e-6f) * o_norm_w[kk];
  float g = bf2f(gate_raw[row * Pc + p]) + bgb[p];
  float o = normed / (1.f + expf(-g));
  attn_io[base + kk] = f2bf(o);
}

// ---------------- launch ----------------
extern "C" void kernel_launch(void* const* d_in, const int* in_sizes, int n_in,
                              void* d_out, int out_size, void* d_ws, size_t ws_size,
                              hipStream_t stream) {
  (void)in_sizes; (void)n_in;
  const float* x        = (const float*)d_in[0];
  const float* Wq       = (const float*)d_in[1];
  const float* Wk       = (const float*)d_in[2];
  const float* Wv       = (const float*)d_in[3];
  const float* conv_q   = (const float*)d_in[4];
  const float* conv_k   = (const float*)d_in[5];
  const float* conv_v   = (const float*)d_in[6];
  const float* A_log    = (const float*)d_in[7];
  const float* dt_bias  = (const float*)d_in[8];
  const float* Wfa      = (const float*)d_in[9];
  const float* Wfb      = (const float*)d_in[10];
  const float* Wb       = (const float*)d_in[11];
  const float* Wga      = (const float*)d_in[12];
  const float* Wgb      = (const float*)d_in[13];
  const float* bgb      = (const float*)d_in[14];
  const float* o_norm_w = (const float*)d_in[15];
  const float* Wo       = (const float*)d_in[16];
  const float* snap_nw  = (const float*)d_in[17];
  const float* snap_down= (const float*)d_in[18];

  // ---- workspace layout (peak ~211.3 MB, unchanged from round 3) ----
  const size_t MP2 = (size_t)Mc * Pc * 2;             // 33,554,432 B (bf16 M x P)
  const size_t NEED = 6 * MP2                          // q,k,v,g_raw,evb,ewb
                    + 2 * (size_t)Mc * Kc * 4          // fa, ga
                    + (size_t)Mc * Hc * 4              // betab
                    + (size_t)Bc * Hc * NCc * Kc * 4;  // wlast
  if (ws_size < NEED + 4096) {
    hipMemsetAsync(d_out, 0, (size_t)out_size * 4, stream);
    return;
  }
  char* w = (char*)d_ws;
  auto alloc = [&](size_t bytes) {
    char* r = w;
    w += (bytes + 255) & ~(size_t)255;
    return r;
  };
  unsigned short* q_lin = (unsigned short*)alloc(MP2);  // later: intra + Wob + Wgbb
  unsigned short* k_lin = (unsigned short*)alloc(MP2);  // later: attn
  unsigned short* v_lin = (unsigned short*)alloc(MP2);  // later: snapraw (f32, exact fit)
  unsigned short* g_raw = (unsigned short*)alloc(MP2);  // later: gate_raw
  unsigned short* evb   = (unsigned short*)alloc(MP2);  // pre-prep: xb; then bv->ev; then sdw
  unsigned short* ewb   = (unsigned short*)alloc(MP2);  // pre-prep: weight casts; bw->ew; snaps
  float* fa    = (float*)alloc((size_t)Mc * Kc * 4);    // used as bf16 (half the space)
  float* ga    = (float*)alloc((size_t)Mc * Kc * 4);    // used as bf16
  float* betab = (float*)alloc((size_t)Mc * Hc * 4);
  float* wlast = (float*)alloc((size_t)Bc * Hc * NCc * Kc * 4);

  // qt + u live in d_out's y-region (exactly 67.1 MB, dead before y is written)
  unsigned short* qt = (unsigned short*)d_out;
  unsigned short* u_ = (unsigned short*)((char*)d_out + MP2);

  // -- bf16 casts in dead phases of existing regions --
  unsigned short* xb    = evb;                       // 16.78M elem, dead before chunk_prep
  unsigned short* Wqb   = ewb;                       // 4.19M elem each
  unsigned short* Wkb   = ewb + 4194304;
  unsigned short* Wvb   = ewb + 8388608;
  unsigned short* Wfab  = ewb + 12582912;            // 262,144 elem
  unsigned short* Wgab  = ewb + 12845056;
  unsigned short* Wfbb  = ewb + 13107200;            // ends 13,369,344 < 16,777,216 ok
  unsigned short* fab   = (unsigned short*)fa;       // bf16 view
  unsigned short* gab   = (unsigned short*)ga;

  // post-chunk_prep aliases
  unsigned short* intra = q_lin;                     // [0 .. 8,388,608) elem
  unsigned short* Wob   = q_lin + 8388608;           // 4.19M elem, ends 12,582,912
  unsigned short* Wgbb  = q_lin + 12582912;          // 262,144 elem, ends 12,845,056
  unsigned short* attn  = k_lin;
  float* snapraw        = (float*)v_lin;             // 512 x 16384 f32, exact fit
  unsigned short* gate_raw = g_raw;
  float* sdw       = (float*)evb;                    // 8.4 MB, evb dead after scan
  float* snap_out  = (float*)ewb;                    // 512x128 f32
  float* snapscale = (float*)ewb + (size_t)512 * 128;

  float* y = (float*)d_out;
  float* snaps_out = (float*)d_out + (size_t)Bc * Tc * Dc;

  // 0) casts (x + weights needed before chunk_prep)
  cast_f32_bf16<<<16384, 256, 0, stream>>>(x, xb, Mc * Dc);
  cast_f32_bf16<<<4096, 256, 0, stream>>>(Wq, Wqb, Pc * Dc);
  cast_f32_bf16<<<4096, 256, 0, stream>>>(Wk, Wkb, Pc * Dc);
  cast_f32_bf16<<<4096, 256, 0, stream>>>(Wv, Wvb, Pc * Dc);
  cast_f32_bf16<<<256, 256, 0, stream>>>(Wfa, Wfab, Kc * Dc);
  cast_f32_bf16<<<256, 256, 0, stream>>>(Wga, Wgab, Kc * Dc);
  cast_f32_bf16<<<256, 256, 0, stream>>>(Wfb, Wfbb, Pc * Kc);

  // 1) input GEMMs (bf16 MFMA)
  gemm_nt_mfma<unsigned short><<<dim3(64, 16), 256, 0, stream>>>(xb, Wqb, q_lin, Pc, Dc);
  gemm_nt_mfma<unsigned short><<<dim3(64, 16), 256, 0, stream>>>(xb, Wkb, k_lin, Pc, Dc);
  gemm_nt_mfma<unsigned short><<<dim3(64, 16), 256, 0, stream>>>(xb, Wvb, v_lin, Pc, Dc);
  gemm_nt_mfma<unsigned short><<<dim3(64, 1), 256, 0, stream>>>(xb, Wfab, fab, Kc, Dc);
  gemm_nt_mfma<unsigned short><<<dim3(64, 1), 256, 0, stream>>>(xb, Wgab, gab, Kc, Dc);
  gemm_nt<float, float, float><<<dim3(64, 1), 256, 0, stream>>>(x, Wb, betab, Hc, Dc);
  gemm_nt_mfma<unsigned short><<<dim3(64, 16), 256, 0, stream>>>(fab, Wfbb, g_raw, Pc, Kc);

  // 2) per-chunk prep (qt,u -> d_out scratch; bv->evb, bw->ewb; consumes xb/weight regions)
  chunk_prep<<<Bc * Hc * NCc, 128, 0, stream>>>(q_lin, k_lin, v_lin, g_raw, betab, conv_q,
                                                conv_k, conv_v, A_log, dt_bias, qt, u_, evb,
                                                ewb, wlast);

  // 3) late casts into q_lin's dead tail (q_lin fully consumed by chunk_prep)
  cast_f32_bf16<<<4096, 256, 0, stream>>>(Wo, Wob, Dc * Pc);
  cast_f32_bf16<<<256, 256, 0, stream>>>(Wgb, Wgbb, Pc * Kc);

  chunk_solve<<<Bc * Hc * NCc, 256, 0, stream>>>(qt, u_, evb, ewb, intra);

  // 4) gate projection (g_raw region now dead -> gate_raw)
  gemm_nt_mfma<unsigned short><<<dim3(64, 16), 256, 0, stream>>>(gab, Wgbb, gate_raw, Pc, Kc);

  // 5) sequential scan (v-sliced); attn -> k_lin region, snapraw -> v_lin region
  scan_kernel<<<256, 256, 0, stream>>>(qt, u_, evb, ewb, intra, wlast, attn, snapraw);

  // 6) snapshots (evb/ewb regions now dead -> sdw / snap_out / snapscale)
  sdw_mul<<<8192, 256, 0, stream>>>(snap_down, snap_nw, sdw);
  snap_scale_kernel<<<512, 256, 0, stream>>>(snapraw, snapscale);
  gemm_nt<float, float, float><<<dim3(4, 2), 256, 0, stream>>>(snapraw, sdw, snap_out, LATc, 16384);
  snap_scatter<<<256, 256, 0, stream>>>(snap_out, snapscale, snaps_out);

  // 7) output norm*gate + final projection (qt/u in d_out dead now; y overwrites them)
  out_norm_gate<<<Mc * Hc, 128, 0, stream>>>(attn, gate_raw, bgb, o_norm_w);
  gemm_nt_mfma<float><<<dim3(64, 16), 256, 0, stream>>>(attn, Wob, y, Dc, Pc);
}

// Round 5
// 1657.202 us; speedup vs baseline: 4.8257x; 2.5563x over previous
//
#include <hip/hip_runtime.h>

// ---------------- problem constants ----------------
constexpr int Bc   = 2;
constexpr int Tc   = 4096;
constexpr int Dc   = 2048;
constexpr int Hc   = 16;
constexpr int Kc   = 128;
constexpr int Pc   = Hc * Kc;     // 2048
constexpr int Cc   = 64;          // chunk size
constexpr int NCc  = Tc / Cc;     // 64 chunks
constexpr int Mc   = Bc * Tc;     // 8192 rows
constexpr int LATc = 128;

// ---------------- helpers ----------------
__device__ __forceinline__ float bf2f(unsigned short u) {
  unsigned int x = ((unsigned int)u) << 16;
  return __builtin_bit_cast(float, x);
}
__device__ __forceinline__ unsigned short f2bf(float f) {
  unsigned int x = __builtin_bit_cast(unsigned int, f);
  x += 0x7fffu + ((x >> 16) & 1u);
  return (unsigned short)(x >> 16);
}
__device__ __forceinline__ float4 ld4(const float* p) {
  return *reinterpret_cast<const float4*>(p);
}
__device__ __forceinline__ float4 ld4(const unsigned short* p) {
  ushort4 u = *reinterpret_cast<const ushort4*>(p);
  return make_float4(bf2f(u.x), bf2f(u.y), bf2f(u.z), bf2f(u.w));
}
__device__ __forceinline__ void st1(float* p, float v) { *p = v; }
__device__ __forceinline__ void st1(unsigned short* p, float v) { *p = f2bf(v); }

typedef __attribute__((ext_vector_type(8))) short bf16x8;
typedef __attribute__((ext_vector_type(4))) float f32x4;

// ---------------- f32 -> bf16 cast ----------------
__global__ void cast_f32_bf16(const float* __restrict__ in, unsigned short* __restrict__ out,
                              int n) {
  int i = (blockIdx.x * 256 + threadIdx.x) * 4;
  if (i < n) {
    float4 v = ld4(in + i);
    ushort4 o;
    o.x = f2bf(v.x); o.y = f2bf(v.y); o.z = f2bf(v.z); o.w = f2bf(v.w);
    *reinterpret_cast<ushort4*>(out + i) = o;
  }
}

// ---------------- bf16 MFMA NT GEMM (128x128 tile, m97 structure) ----------------
__device__ __forceinline__ void gload_lds16(const unsigned short* g, unsigned short* l) {
  __builtin_amdgcn_global_load_lds(
      (const __attribute__((address_space(1))) void*)g,
      (__attribute__((address_space(3))) void*)l, 16, 0, 0);
}

template <typename OT>
__global__ __launch_bounds__(256) void gemm_nt_mfma(const unsigned short* __restrict__ A,
                                                    const unsigned short* __restrict__ Bm,
                                                    OT* __restrict__ Out,
                                                    int Ndim, int Kd) {
  __shared__ __align__(16) unsigned short As[128 * 32];
  __shared__ __align__(16) unsigned short Bs[128 * 32];
  const int m0 = blockIdx.x * 128;
  const int n0 = blockIdx.y * 128;
  const int tid = threadIdx.x;
  const int wave = tid >> 6;
  const int lane = tid & 63;
  const int wr = wave >> 1, wc = wave & 1;
  const int l15 = lane & 15, l4 = lane >> 4;
  f32x4 acc[4][4] = {};

  for (int k0 = 0; k0 < Kd; k0 += 32) {
#pragma unroll
    for (int i = 0; i < 2; ++i) {
      int e = (wave * 2 + i) * 512 + lane * 8;
      int r = e >> 5, c = e & 31;
      gload_lds16(&A[(size_t)(m0 + r) * Kd + k0 + c], &As[(wave * 2 + i) * 512]);
      gload_lds16(&Bm[(size_t)(n0 + r) * Kd + k0 + c], &Bs[(wave * 2 + i) * 512]);
    }
    __syncthreads();
    bf16x8 af[4], bfr[4];
#pragma unroll
    for (int m = 0; m < 4; ++m)
      af[m] = *reinterpret_cast<const bf16x8*>(&As[(wr * 64 + m * 16 + l15) * 32 + l4 * 8]);
#pragma unroll
    for (int n = 0; n < 4; ++n)
      bfr[n] = *reinterpret_cast<const bf16x8*>(&Bs[(wc * 64 + n * 16 + l15) * 32 + l4 * 8]);
#pragma unroll
    for (int m = 0; m < 4; ++m)
#pragma unroll
      for (int n = 0; n < 4; ++n)
        acc[m][n] = __builtin_amdgcn_mfma_f32_16x16x32_bf16(af[m], bfr[n], acc[m][n], 0, 0, 0);
    __syncthreads();
  }
#pragma unroll
  for (int m = 0; m < 4; ++m)
#pragma unroll
    for (int n = 0; n < 4; ++n)
#pragma unroll
      for (int r = 0; r < 4; ++r) {
        int row = m0 + wr * 64 + m * 16 + l4 * 4 + r;
        int col = n0 + wc * 64 + n * 16 + l15;
        st1(&Out[(size_t)row * Ndim + col], acc[m][n][r]);
      }
}

// ---- splitK variant: grid(z) k-slices write disjoint f32 partials (deterministic) ----
__global__ __launch_bounds__(256) void gemm_nt_mfma_sk(const unsigned short* __restrict__ A,
                                                       const unsigned short* __restrict__ Bm,
                                                       float* __restrict__ Part,
                                                       int Ndim, int Kd, int kslice, int Mtot) {
  __shared__ __align__(16) unsigned short As[128 * 32];
  __shared__ __align__(16) unsigned short Bs[128 * 32];
  const int m0 = blockIdx.x * 128;
  const int n0 = blockIdx.y * 128;
  const int kz = blockIdx.z * kslice;
  const int tid = threadIdx.x;
  const int wave = tid >> 6;
  const int lane = tid & 63;
  const int wr = wave >> 1, wc = wave & 1;
  const int l15 = lane & 15, l4 = lane >> 4;
  f32x4 acc[4][4] = {};

  for (int k0 = kz; k0 < kz + kslice; k0 += 32) {
#pragma unroll
    for (int i = 0; i < 2; ++i) {
      int e = (wave * 2 + i) * 512 + lane * 8;
      int r = e >> 5, c = e & 31;
      gload_lds16(&A[(size_t)(m0 + r) * Kd + k0 + c], &As[(wave * 2 + i) * 512]);
      gload_lds16(&Bm[(size_t)(n0 + r) * Kd + k0 + c], &Bs[(wave * 2 + i) * 512]);
    }
    __syncthreads();
    bf16x8 af[4], bfr[4];
#pragma unroll
    for (int m = 0; m < 4; ++m)
      af[m] = *reinterpret_cast<const bf16x8*>(&As[(wr * 64 + m * 16 + l15) * 32 + l4 * 8]);
#pragma unroll
    for (int n = 0; n < 4; ++n)
      bfr[n] = *reinterpret_cast<const bf16x8*>(&Bs[(wc * 64 + n * 16 + l15) * 32 + l4 * 8]);
#pragma unroll
    for (int m = 0; m < 4; ++m)
#pragma unroll
      for (int n = 0; n < 4; ++n)
        acc[m][n] = __builtin_amdgcn_mfma_f32_16x16x32_bf16(af[m], bfr[n], acc[m][n], 0, 0, 0);
    __syncthreads();
  }
  float* out = Part + (size_t)blockIdx.z * Mtot * Ndim;
#pragma unroll
  for (int m = 0; m < 4; ++m)
#pragma unroll
    for (int n = 0; n < 4; ++n)
#pragma unroll
      for (int r = 0; r < 4; ++r) {
        int row = m0 + wr * 64 + m * 16 + l4 * 4 + r;
        int col = n0 + wc * 64 + n * 16 + l15;
        out[(size_t)row * Ndim + col] = acc[m][n][r];
      }
}

// ---------------- generic fp32 NT GEMM (kept only for N=16 beta) --------
template <typename AT, typename BT, typename OT>
__global__ __launch_bounds__(256) void gemm_nt(const AT* __restrict__ A,
                                               const BT* __restrict__ Bm,
                                               OT* __restrict__ Out,
                                               int Ndim, int Kd) {
  __shared__ float As[32][132];
  __shared__ float Bs[32][68];
  const int m0 = blockIdx.x * 128;
  const int n0 = blockIdx.y * 64;
  const int tid = threadIdx.x;
  const int tx = tid & 15, ty = tid >> 4;
  float acc[8][4];
#pragma unroll
  for (int i = 0; i < 8; ++i)
#pragma unroll
    for (int j = 0; j < 4; ++j) acc[i][j] = 0.f;

  for (int k0 = 0; k0 < Kd; k0 += 32) {
#pragma unroll
    for (int p = 0; p < 4; ++p) {
      int e = tid + p * 256;
      int r = e >> 3;
      int c = (e & 7) << 2;
      float4 v = ld4(A + (size_t)(m0 + r) * Kd + k0 + c);
      As[c + 0][r] = v.x; As[c + 1][r] = v.y; As[c + 2][r] = v.z; As[c + 3][r] = v.w;
    }
#pragma unroll
    for (int p = 0; p < 2; ++p) {
      int e = tid + p * 256;
      int r = e >> 3;
      int c = (e & 7) << 2;
      float4 v = make_float4(0.f, 0.f, 0.f, 0.f);
      if (n0 + r < Ndim) v = ld4(Bm + (size_t)(n0 + r) * Kd + k0 + c);
      Bs[c + 0][r] = v.x; Bs[c + 1][r] = v.y; Bs[c + 2][r] = v.z; Bs[c + 3][r] = v.w;
    }
    __syncthreads();
#pragma unroll
    for (int kk = 0; kk < 32; ++kk) {
      const float4* ar = reinterpret_cast<const float4*>(&As[kk][0]);
      const float4* br = reinterpret_cast<const float4*>(&Bs[kk][0]);
      float4 b4 = br[tx];
      float4 a0 = ar[ty * 2], a1 = ar[ty * 2 + 1];
      float av[8] = {a0.x, a0.y, a0.z, a0.w, a1.x, a1.y, a1.z, a1.w};
      float bv4[4] = {b4.x, b4.y, b4.z, b4.w};
#pragma unroll
      for (int i = 0; i < 8; ++i)
#pragma unroll
        for (int j = 0; j < 4; ++j) acc[i][j] = fmaf(av[i], bv4[j], acc[i][j]);
    }
    __syncthreads();
  }
#pragma unroll
  for (int i = 0; i < 8; ++i) {
    int m = m0 + ty * 8 + i;
#pragma unroll
    for (int j = 0; j < 4; ++j) {
      int n = n0 + tx * 4 + j;
      if (n < Ndim) st1(Out + (size_t)m * Ndim + n, acc[i][j]);
    }
  }
}

// ---------------- chunk prep (unchanged) ----------------
__global__ __launch_bounds__(128) void chunk_prep(
    const unsigned short* __restrict__ q_lin, const unsigned short* __restrict__ k_lin,
    const unsigned short* __restrict__ v_lin, const unsigned short* __restrict__ g_raw,
    const float* __restrict__ beta_lin, const float* __restrict__ conv_q,
    const float* __restrict__ conv_k, const float* __restrict__ conv_v,
    const float* __restrict__ A_log, const float* __restrict__ dt_bias,
    unsigned short* __restrict__ qt, unsigned short* __restrict__ u_,
    unsigned short* __restrict__ bv, unsigned short* __restrict__ bw,
    float* __restrict__ wlast) {
  const int blk = blockIdx.x;
  const int n = blk & 63;
  const int h = (blk >> 6) & 15;
  const int b = blk >> 10;
  const int kk = threadIdx.x;
  const int p = h * Kc + kk;
  float cq[4], ck[4], cv[4];
#pragma unroll
  for (int j = 0; j < 4; ++j) {
    cq[j] = conv_q[p * 4 + j];
    ck[j] = conv_k[p * 4 + j];
    cv[j] = conv_v[p * 4 + j];
  }
  const float aneg = -expf(A_log[h]);
  const float db = dt_bias[p];
  __shared__ float red[4];
  float cum = 0.f;
  for (int c = 0; c < Cc; ++c) {
    const int t = n * Cc + c;
    float qv = 0.f, kv = 0.f, vv = 0.f;
#pragma unroll
    for (int j = 0; j < 4; ++j) {
      int ts = t - 3 + j;
      if (ts >= 0) {
        size_t off = ((size_t)(b * Tc + ts)) * Pc + p;
        qv += cq[j] * bf2f(q_lin[off]);
        kv += ck[j] * bf2f(k_lin[off]);
        vv += cv[j] * bf2f(v_lin[off]);
      }
    }
    qv = qv / (1.f + expf(-qv));
    kv = kv / (1.f + expf(-kv));
    vv = vv / (1.f + expf(-vv));
    float a = qv * qv, bb = kv * kv;
#pragma unroll
    for (int off = 32; off > 0; off >>= 1) {
      a += __shfl_down(a, off, 64);
      bb += __shfl_down(bb, off, 64);
    }
    __syncthreads();
    if ((kk & 63) == 0) { red[(kk >> 6) * 2] = a; red[(kk >> 6) * 2 + 1] = bb; }
    __syncthreads();
    float sq = red[0] + red[2];
    float sk = red[1] + red[3];
    float qn = qv * rsqrtf(sq + 1e-12f) * 0.08838834764831845f;
    float kn = kv * rsqrtf(sk + 1e-12f);
    float g = bf2f(g_raw[((size_t)(b * Tc + t)) * Pc + p]) + db;
    float sp = (g > 20.f) ? g : log1pf(expf(g));
    cum += aneg * sp;
    float cc = fmaxf(cum, -15.f);
    float Wg = expf(cc);
    float Wi = expf(-cc);
    float beta = 1.f / (1.f + expf(-beta_lin[((size_t)(b * Tc + t)) * Hc + h]));
    size_t idx = ((size_t)blk * Cc + c) * Kc + kk;
    qt[idx] = f2bf(qn * Wg);
    u_[idx] = f2bf(kn * Wi);
    bw[idx] = f2bf(beta * kn * Wg);
    bv[idx] = f2bf(beta * vv);
    if (c == Cc - 1) wlast[(size_t)blk * Kc + kk] = Wg;
  }
}

// ---------------- chunk solve (unchanged) ----------------
__global__ __launch_bounds__(256) void chunk_solve(
    const unsigned short* __restrict__ qt, const unsigned short* __restrict__ u_,
    unsigned short* __restrict__ evb, unsigned short* __restrict__ ewb,
    unsigned short* __restrict__ intra_out) {
  const int blk = blockIdx.x;
  const size_t base = (size_t)blk * (Cc * Kc);
  const int tid = threadIdx.x;
  const int j = tid & 63, g = tid >> 6;
  __shared__ __align__(16) char ovl_raw[64 * 130 * 2];
  unsigned short(*uS)[130] = reinterpret_cast<unsigned short(*)[130]>(ovl_raw);
  float(*Lsm)[64] = reinterpret_cast<float(*)[64]>(ovl_raw);
  __shared__ float wS[64][128];

#pragma unroll 8
  for (int pp = 0; pp < 32; ++pp) {
    int e = tid + pp * 256;
    uS[e >> 7][e & 127] = u_[base + e];
  }
#pragma unroll 8
  for (int pp = 0; pp < 32; ++pp) {
    int e = tid + pp * 256;
    wS[e >> 7][e & 127] = bf2f(ewb[base + e]);
  }
  __syncthreads();
  float Lacc[16];
#pragma unroll
  for (int ii = 0; ii < 16; ++ii) Lacc[ii] = 0.f;
  for (int k = 0; k < 128; ++k) {
    float uv = bf2f(uS[j][k]);
#pragma unroll
    for (int ii = 0; ii < 16; ++ii) Lacc[ii] += wS[g * 16 + ii][k] * uv;
  }
  __syncthreads();
#pragma unroll 8
  for (int pp = 0; pp < 32; ++pp) {
    int e = tid + pp * 256;
    wS[e >> 7][e & 127] = bf2f(qt[base + e]);
  }
  __syncthreads();
  float Iacc[16];
#pragma unroll
  for (int ii = 0; ii < 16; ++ii) Iacc[ii] = 0.f;
  for (int k = 0; k < 128; ++k) {
    float uv = bf2f(uS[j][k]);
#pragma unroll
    for (int ii = 0; ii < 16; ++ii) Iacc[ii] += wS[g * 16 + ii][k] * uv;
  }
  size_t ibase = (size_t)blk * (Cc * Cc);
#pragma unroll
  for (int ii = 0; ii < 16; ++ii) {
    int i = g * 16 + ii;
    intra_out[ibase + i * 64 + j] = f2bf((j <= i) ? Iacc[ii] : 0.f);
  }
  __syncthreads();
#pragma unroll
  for (int ii = 0; ii < 16; ++ii) Lsm[g * 16 + ii][j] = Lacc[ii];
  __syncthreads();
  for (int s = 0; s < 2; ++s) {
    unsigned short* rb = (s == 0) ? evb : ewb;
#pragma unroll 8
    for (int pp = 0; pp < 32; ++pp) {
      int e = tid + pp * 256;
      wS[e >> 7][e & 127] = bf2f(rb[base + e]);
    }
    __syncthreads();
    const int col = tid & 127;
    for (int i = 1; i < 64; ++i) {
      if (tid < 128) {
        float sacc = 0.f;
        for (int jj = 0; jj < i; ++jj) sacc += Lsm[i][jj] * wS[jj][col];
        wS[i][col] -= sacc;
      }
      __syncthreads();
    }
#pragma unroll 8
    for (int pp = 0; pp < 32; ++pp) {
      int e = tid + pp * 256;
      rb[base + e] = f2bf(wS[e >> 7][e & 127]);
    }
    __syncthreads();
  }
}

// ---------------- MFMA scan: 1 block per (b,h), 8 waves, S in MFMA accumulators ------
// LDS swizzles: rows of stride 256B (ewS/qtS/sBT) and 128B (uTS/iaS/dBT), byte^=((row&7)<<4)
__device__ __forceinline__ int swzA(int row, int kbyte) { return row * 256 + (kbyte ^ ((row & 7) << 4)); }
__device__ __forceinline__ int swzB(int row, int kbyte) { return row * 128 + (kbyte ^ ((row & 7) << 4)); }
__device__ __forceinline__ bf16x8 ldsv8(const unsigned short* base, int byteoff) {
  return *reinterpret_cast<const bf16x8*>(reinterpret_cast<const char*>(base) + byteoff);
}
__device__ __forceinline__ void stsv16B(unsigned short* base, int byteoff, int4 v) {
  *reinterpret_cast<int4*>(reinterpret_cast<char*>(base) + byteoff) = v;
}
__device__ __forceinline__ void stsv8B(unsigned short* base, int byteoff, uint2 v) {
  *reinterpret_cast<uint2*>(reinterpret_cast<char*>(base) + byteoff) = v;
}

__global__ __launch_bounds__(512) void scan_mfma(
    const unsigned short* __restrict__ qt, const unsigned short* __restrict__ u_,
    const unsigned short* __restrict__ evb, const unsigned short* __restrict__ ewb,
    const unsigned short* __restrict__ intra, const float* __restrict__ wlast,
    unsigned short* __restrict__ attn_o, unsigned short* __restrict__ snapb) {
  const int bh = blockIdx.x, b = bh >> 4, h = bh & 15;
  const int tid = threadIdx.x, wave = tid >> 6, lane = tid & 63;
  const int l15 = lane & 15, l4 = lane >> 4;
  __shared__ __align__(16) unsigned short ewS[8192];   // [64 c][128 k]  swzA
  __shared__ __align__(16) unsigned short qtS[8192];   // [64 c][128 k]  swzA
  __shared__ __align__(16) unsigned short uTS[8192];   // [128 k][64 c]  swzB
  __shared__ __align__(16) unsigned short iaS[4096];   // [64 c][64 j]   swzB
  __shared__ __align__(16) unsigned short sBT[16384];  // [128 v][128 k] swzA (S^T bf16)
  __shared__ __align__(16) unsigned short dBT[8192];   // [128 v][64 c]  swzB (delta^T bf16)

  f32x4 S[8] = {};
  // zero sBT (S0 = 0): 512 threads x 64B
  {
    int4 z = {0, 0, 0, 0};
#pragma unroll
    for (int i = 0; i < 4; ++i) stsv16B(sBT, tid * 64 + i * 16, z);
  }

  // staging mapping: 512 threads cover 64x128 (2x16B each) / 64x64 (1x16B)
  const int sr = tid >> 3;           // row 0..63
  const int sk0 = (tid & 7) * 16;    // col base for 128-wide
  const int sc0 = (tid & 7) * 8;     // col base for 64-wide
  int4 rEw0, rEw1, rQt0, rQt1, rU0, rU1, rIa;

#define STAGE_LOAD(CB, IB)                                                        \
  rEw0 = *(const int4*)(ewb + (CB) + sr * 128 + sk0);                             \
  rEw1 = *(const int4*)(ewb + (CB) + sr * 128 + sk0 + 8);                         \
  rQt0 = *(const int4*)(qt + (CB) + sr * 128 + sk0);                              \
  rQt1 = *(const int4*)(qt + (CB) + sr * 128 + sk0 + 8);                          \
  rU0 = *(const int4*)(u_ + (CB) + sr * 128 + sk0);                               \
  rU1 = *(const int4*)(u_ + (CB) + sr * 128 + sk0 + 8);                           \
  rIa = *(const int4*)(intra + (IB) + sr * 64 + sc0);

#define STAGE_WRITE()                                                             \
  stsv16B(ewS, swzA(sr, sk0 * 2), rEw0);                                          \
  stsv16B(ewS, swzA(sr, sk0 * 2 + 16), rEw1);                                     \
  stsv16B(qtS, swzA(sr, sk0 * 2), rQt0);                                          \
  stsv16B(qtS, swzA(sr, sk0 * 2 + 16), rQt1);                                     \
  stsv16B(iaS, swzB(sr, sc0 * 2), rIa);                                           \
  {                                                                               \
    const unsigned short* up0 = reinterpret_cast<const unsigned short*>(&rU0);    \
    const unsigned short* up1 = reinterpret_cast<const unsigned short*>(&rU1);    \
    _Pragma("unroll")                                                             \
    for (int jj = 0; jj < 8; ++jj) {                                              \
      *reinterpret_cast<unsigned short*>((char*)uTS + swzB(sk0 + jj, sr * 2)) = up0[jj];      \
      *reinterpret_cast<unsigned short*>((char*)uTS + swzB(sk0 + 8 + jj, sr * 2)) = up1[jj];  \
    }                                                                             \
  }

  // prologue: stage chunk 0
  {
    const size_t cb0 = (size_t)bh * 64 * 8192;
    const size_t ib0 = (size_t)bh * 64 * 4096;
    STAGE_LOAD(cb0, ib0);
    STAGE_WRITE();
  }
  __syncthreads();

  const int m = wave & 3, ntb = (wave >> 2) * 4;
  const int arow = 16 * m + l15;     // A-row for ew/qt/ia
  const int krow = 16 * wave + l15;  // A-row for uT (S row-tile ownership)

  for (int n = 0; n < NCc; ++n) {
    const size_t cb = ((size_t)bh * 64 + n) * 8192;
    const size_t ib = ((size_t)bh * 64 + n) * 4096;
    // ---- Phase A: prefetch n+1 (T14 issue-early) + delta = ev - ew@S -> dBT ----
    if (n < 63) { STAGE_LOAD(cb + 8192, ib + 4096); }
    bf16x8 aEw[4];
#pragma unroll
    for (int ks = 0; ks < 4; ++ks) aEw[ks] = ldsv8(ewS, swzA(arow, 16 * l4 + 64 * ks));
#pragma unroll
    for (int nt = 0; nt < 4; ++nt) {
      int v = 16 * (ntb + nt) + l15;
      f32x4 p = {};
#pragma unroll
      for (int ks = 0; ks < 4; ++ks)
        p = __builtin_amdgcn_mfma_f32_16x16x32_bf16(aEw[ks], ldsv8(sBT, swzA(v, 16 * l4 + 64 * ks)), p, 0, 0, 0);
      float d[4];
#pragma unroll
      for (int r = 0; r < 4; ++r) {
        int c = 16 * m + 4 * l4 + r;
        d[r] = bf2f(evb[cb + (size_t)c * 128 + v]) - p[r];
      }
      uint2 pk;
      pk.x = (unsigned)f2bf(d[0]) | ((unsigned)f2bf(d[1]) << 16);
      pk.y = (unsigned)f2bf(d[2]) | ((unsigned)f2bf(d[3]) << 16);
      stsv8B(dBT, swzB(v, (16 * m + 4 * l4) * 2), pk);
    }
    __syncthreads();
    // ---- Phase B1: o = qt@S + ia@delta -> global; S = wl*(S + uT@delta) ----
    bf16x8 aQt[4], aIa[2], aU[2];
#pragma unroll
    for (int ks = 0; ks < 4; ++ks) aQt[ks] = ldsv8(qtS, swzA(arow, 16 * l4 + 64 * ks));
#pragma unroll
    for (int ks = 0; ks < 2; ++ks) aIa[ks] = ldsv8(iaS, swzB(arow, 16 * l4 + 64 * ks));
#pragma unroll
    for (int ks = 0; ks < 2; ++ks) aU[ks] = ldsv8(uTS, swzB(krow, 16 * l4 + 64 * ks));
#pragma unroll
    for (int nt = 0; nt < 4; ++nt) {
      int v = 16 * (ntb + nt) + l15;
      f32x4 o = {};
#pragma unroll
      for (int ks = 0; ks < 4; ++ks)
        o = __builtin_amdgcn_mfma_f32_16x16x32_bf16(aQt[ks], ldsv8(sBT, swzA(v, 16 * l4 + 64 * ks)), o, 0, 0, 0);
#pragma unroll
      for (int ks = 0; ks < 2; ++ks)
        o = __builtin_amdgcn_mfma_f32_16x16x32_bf16(aIa[ks], ldsv8(dBT, swzB(v, 16 * l4 + 64 * ks)), o, 0, 0, 0);
#pragma unroll
      for (int r = 0; r < 4; ++r) {
        int c = 16 * m + 4 * l4 + r;
        int t = n * 64 + c;
        attn_o[((size_t)(b * Tc + t) * Hc + h) * Kc + v] = f2bf(o[r]);
      }
    }
    float wlv[4];
#pragma unroll
    for (int r = 0; r < 4; ++r)
      wlv[r] = wlast[((size_t)bh * 64 + n) * 128 + 16 * wave + 4 * l4 + r];
#pragma unroll
    for (int nt8 = 0; nt8 < 8; ++nt8) {
      int v = 16 * nt8 + l15;
      f32x4 U = {};
#pragma unroll
      for (int ks = 0; ks < 2; ++ks)
        U = __builtin_amdgcn_mfma_f32_16x16x32_bf16(aU[ks], ldsv8(dBT, swzB(v, 16 * l4 + 64 * ks)), U, 0, 0, 0);
#pragma unroll
      for (int r = 0; r < 4; ++r) S[nt8][r] = wlv[r] * (S[nt8][r] + U[r]);
    }
    __syncthreads();
    // ---- Phase B2: S -> sBT (bf16), staging writes for n+1, snapshot ----
#pragma unroll
    for (int nt8 = 0; nt8 < 8; ++nt8) {
      int v = 16 * nt8 + l15;
      uint2 pk;
      pk.x = (unsigned)f2bf(S[nt8][0]) | ((unsigned)f2bf(S[nt8][1]) << 16);
      pk.y = (unsigned)f2bf(S[nt8][2]) | ((unsigned)f2bf(S[nt8][3]) << 16);
      stsv8B(sBT, swzA(v, (16 * wave + 4 * l4) * 2), pk);
    }
    if (n < 63) { STAGE_WRITE(); }
    if ((n & 3) == 3) {
      int ns = n >> 2;
      size_t sb = (size_t)((ns * Bc + b) * Hc + h) * 16384;
#pragma unroll
      for (int nt8 = 0; nt8 < 8; ++nt8)
#pragma unroll
        for (int r = 0; r < 4; ++r) {
          int k = 16 * wave + 4 * l4 + r;
          snapb[sb + (size_t)k * 128 + 16 * nt8 + l15] = f2bf(S[nt8][r]);
        }
    }
    __syncthreads();
  }
#undef STAGE_LOAD
#undef STAGE_WRITE
}

// ---------------- snapshot helpers ----------------
__global__ void sdw_mul_bf16(const float* __restrict__ snap_down, const float* __restrict__ w,
                             unsigned short* __restrict__ sdwb) {
  int i = (blockIdx.x * 256 + threadIdx.x) * 4;  // LAT*K*K = 2097152
  float4 v = ld4(snap_down + i);
  int k = i & 16383;
  float4 ww = ld4(w + k);
  ushort4 o;
  o.x = f2bf(v.x * ww.x); o.y = f2bf(v.y * ww.y); o.z = f2bf(v.z * ww.z); o.w = f2bf(v.w * ww.w);
  *reinterpret_cast<ushort4*>(sdwb + i) = o;
}

__global__ __launch_bounds__(256) void snap_scale_kernel(const unsigned short* __restrict__ snapb,
                                                         float* __restrict__ scale) {
  int r = blockIdx.x;  // 512 rows
  const unsigned short* row = snapb + (size_t)r * 16384;
  float s = 0.f;
  for (int ii = threadIdx.x * 4; ii < 16384; ii += 1024) {
    float4 x = ld4(row + ii);
    s += x.x * x.x + x.y * x.y + x.z * x.z + x.w * x.w;
  }
#pragma unroll
  for (int off = 32; off > 0; off >>= 1) s += __shfl_down(s, off, 64);
  __shared__ float red[4];
  if ((threadIdx.x & 63) == 0) red[threadIdx.x >> 6] = s;
  __syncthreads();
  if (threadIdx.x == 0) {
    float tot = red[0] + red[1] + red[2] + red[3];
    scale[r] = rsqrtf(tot * (1.f / 16384.f) + 1e-6f);
  }
}

// fused: reduce splitK partials * scale -> snaps output (b,ns,h,l)
__global__ void snap_reduce_scatter(const float* __restrict__ part,
                                    const float* __restrict__ scale,
                                    float* __restrict__ outp) {
  int idx = blockIdx.x * 256 + threadIdx.x;  // 65536
  int l = idx & 127;
  int hh = (idx >> 7) & 15;
  int ns = (idx >> 11) & 15;
  int bb = idx >> 15;
  int r = (ns * Bc + bb) * Hc + hh;
  float s = 0.f;
#pragma unroll
  for (int z = 0; z < 16; ++z) s += part[(size_t)z * 65536 + r * 128 + l];
  outp[idx] = s * scale[r];
}

// ---------------- final rmsnorm * sigmoid(gate) ----------------
__global__ __launch_bounds__(128) void out_norm_gate(unsigned short* __restrict__ attn_io,
                                                     const unsigned short* __restrict__ gate_raw,
                                                     const float* __restrict__ bgb,
                                                     const float* __restrict__ o_norm_w) {
  const int blk = blockIdx.x;
  const int kk = threadIdx.x;
  const int h = blk & 15;
  const size_t row = (size_t)(blk >> 4);
  const int p = h * Kc + kk;
  const size_t base = (size_t)blk * Kc;
  float x = bf2f(attn_io[base + kk]);
  float ss = x * x;
#pragma unroll
  for (int off = 32; off > 0; off >>= 1) ss += __shfl_down(ss, off, 64);
  __shared__ float red[2];
  if ((kk & 63) == 0) red[kk >> 6] = ss;
  __syncthreads();
  float tot = red[0] + red[1];
  float normed = x * rsqrtf(tot * (1.f / 128.f) + 1e-6f) * o_norm_w[kk];
  float g = bf2f(gate_raw[row * Pc + p]) + bgb[p];
  float o = normed / (1.f + expf(-g));
  attn_io[base + kk] = f2bf(o);
}

// ---------------- launch ----------------
extern "C" void kernel_launch(void* const* d_in, const int* in_sizes, int n_in,
                              void* d_out, int out_size, void* d_ws, size_t ws_size,
                              hipStream_t stream) {
  (void)in_sizes; (void)n_in;
  const float* x        = (const float*)d_in[0];
  const float* Wq       = (const float*)d_in[1];
  const float* Wk       = (const float*)d_in[2];
  const float* Wv       = (const float*)d_in[3];
  const float* conv_q   = (const float*)d_in[4];
  const float* conv_k   = (const float*)d_in[5];
  const float* conv_v   = (const float*)d_in[6];
  const float* A_log    = (const float*)d_in[7];
  const float* dt_bias  = (const float*)d_in[8];
  const float* Wfa      = (const float*)d_in[9];
  const float* Wfb      = (const float*)d_in[10];
  const float* Wb       = (const float*)d_in[11];
  const float* Wga      = (const float*)d_in[12];
  const float* Wgb      = (const float*)d_in[13];
  const float* bgb      = (const float*)d_in[14];
  const float* o_norm_w = (const float*)d_in[15];
  const float* Wo       = (const float*)d_in[16];
  const float* snap_nw  = (const float*)d_in[17];
  const float* snap_down= (const float*)d_in[18];

  const size_t MP2 = (size_t)Mc * Pc * 2;             // 33,554,432 B
  const size_t NEED = 6 * MP2
                    + 2 * (size_t)Mc * Kc * 4
                    + (size_t)Mc * Hc * 4
                    + (size_t)Bc * Hc * NCc * Kc * 4;
  if (ws_size < NEED + 4096) {
    hipMemsetAsync(d_out, 0, (size_t)out_size * 4, stream);
    return;
  }
  char* w = (char*)d_ws;
  auto alloc = [&](size_t bytes) {
    char* r = w;
    w += (bytes + 255) & ~(size_t)255;
    return r;
  };
  unsigned short* q_lin = (unsigned short*)alloc(MP2);  // later: intra + Wob + Wgbb
  unsigned short* k_lin = (unsigned short*)alloc(MP2);  // later: attn
  unsigned short* v_lin = (unsigned short*)alloc(MP2);  // later: snapb + sdwb
  unsigned short* g_raw = (unsigned short*)alloc(MP2);  // later: gate_raw
  unsigned short* evb   = (unsigned short*)alloc(MP2);  // pre-prep: xb; then bv->ev
  unsigned short* ewb   = (unsigned short*)alloc(MP2);  // pre-prep: W casts; bw->ew; partials
  float* fa    = (float*)alloc((size_t)Mc * Kc * 4);    // bf16 view used
  float* ga    = (float*)alloc((size_t)Mc * Kc * 4);
  float* betab = (float*)alloc((size_t)Mc * Hc * 4);
  float* wlast = (float*)alloc((size_t)Bc * Hc * NCc * Kc * 4);

  unsigned short* qt = (unsigned short*)d_out;
  unsigned short* u_ = (unsigned short*)((char*)d_out + MP2);

  unsigned short* xb    = evb;
  unsigned short* Wqb   = ewb;
  unsigned short* Wkb   = ewb + 4194304;
  unsigned short* Wvb   = ewb + 8388608;
  unsigned short* Wfab  = ewb + 12582912;
  unsigned short* Wgab  = ewb + 12845056;
  unsigned short* Wfbb  = ewb + 13107200;
  unsigned short* fab   = (unsigned short*)fa;
  unsigned short* gab   = (unsigned short*)ga;

  unsigned short* intra = q_lin;
  unsigned short* Wob   = q_lin + 8388608;
  unsigned short* Wgbb  = q_lin + 12582912;
  unsigned short* attn  = k_lin;
  unsigned short* gate_raw = g_raw;
  // snapshot path (all in dead regions after scan inputs are fixed)
  unsigned short* snapb = v_lin;                              // 512 x 16384 bf16 (16.7MB)
  unsigned short* sdwb  = v_lin + (size_t)512 * 16384;        // 128 x 16384 bf16 (4.2MB)
  float* partial   = (float*)ewb;                             // 16 x 512 x 128 f32 (4MB)
  float* snapscale = (float*)(ewb + 4194304 / 2 * 0 + 2200000 * 2); // 512 f32 @ 4.4MB offset
  
  float* y = (float*)d_out;
  float* snaps_out = (float*)d_out + (size_t)Bc * Tc * Dc;

  // 0) casts
  cast_f32_bf16<<<16384, 256, 0, stream>>>(x, xb, Mc * Dc);
  cast_f32_bf16<<<4096, 256, 0, stream>>>(Wq, Wqb, Pc * Dc);
  cast_f32_bf16<<<4096, 256, 0, stream>>>(Wk, Wkb, Pc * Dc);
  cast_f32_bf16<<<4096, 256, 0, stream>>>(Wv, Wvb, Pc * Dc);
  cast_f32_bf16<<<256, 256, 0, stream>>>(Wfa, Wfab, Kc * Dc);
  cast_f32_bf16<<<256, 256, 0, stream>>>(Wga, Wgab, Kc * Dc);
  cast_f32_bf16<<<256, 256, 0, stream>>>(Wfb, Wfbb, Pc * Kc);

  // 1) input GEMMs (bf16 MFMA)
  gemm_nt_mfma<unsigned short><<<dim3(64, 16), 256, 0, stream>>>(xb, Wqb, q_lin, Pc, Dc);
  gemm_nt_mfma<unsigned short><<<dim3(64, 16), 256, 0, stream>>>(xb, Wkb, k_lin, Pc, Dc);
  gemm_nt_mfma<unsigned short><<<dim3(64, 16), 256, 0, stream>>>(xb, Wvb, v_lin, Pc, Dc);
  gemm_nt_mfma<unsigned short><<<dim3(64, 1), 256, 0, stream>>>(xb, Wfab, fab, Kc, Dc);
  gemm_nt_mfma<unsigned short><<<dim3(64, 1), 256, 0, stream>>>(xb, Wgab, gab, Kc, Dc);
  gemm_nt<float, float, float><<<dim3(64, 1), 256, 0, stream>>>(x, Wb, betab, Hc, Dc);
  gemm_nt_mfma<unsigned short><<<dim3(64, 16), 256, 0, stream>>>(fab, Wfbb, g_raw, Pc, Kc);

  // 2) chunk prep
  chunk_prep<<<Bc * Hc * NCc, 128, 0, stream>>>(q_lin, k_lin, v_lin, g_raw, betab, conv_q,
                                                conv_k, conv_v, A_log, dt_bias, qt, u_, evb,
                                                ewb, wlast);

  // 3) late casts into q_lin's dead tail
  cast_f32_bf16<<<4096, 256, 0, stream>>>(Wo, Wob, Dc * Pc);
  cast_f32_bf16<<<256, 256, 0, stream>>>(Wgb, Wgbb, Pc * Kc);

  chunk_solve<<<Bc * Hc * NCc, 256, 0, stream>>>(qt, u_, evb, ewb, intra);

  // 4) gate projection
  gemm_nt_mfma<unsigned short><<<dim3(64, 16), 256, 0, stream>>>(gab, Wgbb, gate_raw, Pc, Kc);

  // 5) MFMA scan: 32 blocks x 512 threads
  scan_mfma<<<Bc * Hc, 512, 0, stream>>>(qt, u_, evb, ewb, intra, wlast, attn, snapb);

  // 6) snapshots: bf16 splitK MFMA GEMM + fused reduce/scale/scatter
  sdw_mul_bf16<<<2048, 256, 0, stream>>>(snap_down, snap_nw, sdwb);
  snap_scale_kernel<<<512, 256, 0, stream>>>(snapb, snapscale);
  gemm_nt_mfma_sk<<<dim3(4, 1, 16), 256, 0, stream>>>(snapb, sdwb, partial, 128, 16384, 1024, 512);
  snap_reduce_scatter<<<256, 256, 0, stream>>>(partial, snapscale, snaps_out);

  // 7) output norm*gate + final projection
  out_norm_gate<<<Mc * Hc, 128, 0, stream>>>(attn, gate_raw, bgb, o_norm_w);
  gemm_nt_mfma<float><<<dim3(64, 16), 256, 0, stream>>>(attn, Wob, y, Dc, Pc);
}

// Round 6
// 1389.314 us; speedup vs baseline: 5.7562x; 1.1928x over previous
//
#include <hip/hip_runtime.h>

// ---------------- problem constants ----------------
constexpr int Bc   = 2;
constexpr int Tc   = 4096;
constexpr int Dc   = 2048;
constexpr int Hc   = 16;
constexpr int Kc   = 128;
constexpr int Pc   = Hc * Kc;     // 2048
constexpr int Cc   = 64;          // chunk size
constexpr int NCc  = Tc / Cc;     // 64 chunks
constexpr int Mc   = Bc * Tc;     // 8192 rows
constexpr int LATc = 128;

// ---------------- helpers ----------------
__device__ __forceinline__ float bf2f(unsigned short u) {
  unsigned int x = ((unsigned int)u) << 16;
  return __builtin_bit_cast(float, x);
}
__device__ __forceinline__ unsigned short f2bf(float f) {
  unsigned int x = __builtin_bit_cast(unsigned int, f);
  x += 0x7fffu + ((x >> 16) & 1u);
  return (unsigned short)(x >> 16);
}
__device__ __forceinline__ float4 ld4(const float* p) {
  return *reinterpret_cast<const float4*>(p);
}
__device__ __forceinline__ float4 ld4(const unsigned short* p) {
  ushort4 u = *reinterpret_cast<const ushort4*>(p);
  return make_float4(bf2f(u.x), bf2f(u.y), bf2f(u.z), bf2f(u.w));
}
__device__ __forceinline__ void st1(float* p, float v) { *p = v; }
__device__ __forceinline__ void st1(unsigned short* p, float v) { *p = f2bf(v); }

typedef __attribute__((ext_vector_type(8))) short bf16x8;
typedef __attribute__((ext_vector_type(4))) float f32x4;

// LDS swizzles: rows of stride 256B (swzA) and 128B (swzB); byte ^= ((row&7)<<4)
__device__ __forceinline__ int swzA(int row, int kbyte) { return row * 256 + (kbyte ^ ((row & 7) << 4)); }
__device__ __forceinline__ int swzB(int row, int kbyte) { return row * 128 + (kbyte ^ ((row & 7) << 4)); }
__device__ __forceinline__ bf16x8 ldsv8(const unsigned short* base, int byteoff) {
  return *reinterpret_cast<const bf16x8*>(reinterpret_cast<const char*>(base) + byteoff);
}
__device__ __forceinline__ void stsv16B(unsigned short* base, int byteoff, int4 v) {
  *reinterpret_cast<int4*>(reinterpret_cast<char*>(base) + byteoff) = v;
}
__device__ __forceinline__ void stsv8B(unsigned short* base, int byteoff, uint2 v) {
  *reinterpret_cast<uint2*>(reinterpret_cast<char*>(base) + byteoff) = v;
}
__device__ __forceinline__ void sts16(unsigned short* base, int byteoff, unsigned short v) {
  *reinterpret_cast<unsigned short*>(reinterpret_cast<char*>(base) + byteoff) = v;
}

// ---------------- f32 -> bf16 cast ----------------
__global__ void cast_f32_bf16(const float* __restrict__ in, unsigned short* __restrict__ out,
                              int n) {
  int i = (blockIdx.x * 256 + threadIdx.x) * 4;
  if (i < n) {
    float4 v = ld4(in + i);
    ushort4 o;
    o.x = f2bf(v.x); o.y = f2bf(v.y); o.z = f2bf(v.z); o.w = f2bf(v.w);
    *reinterpret_cast<ushort4*>(out + i) = o;
  }
}

// ---------------- bf16 MFMA NT GEMM (128x128 tile, m97 structure) ----------------
__device__ __forceinline__ void gload_lds16(const unsigned short* g, unsigned short* l) {
  __builtin_amdgcn_global_load_lds(
      (const __attribute__((address_space(1))) void*)g,
      (__attribute__((address_space(3))) void*)l, 16, 0, 0);
}

template <typename OT>
__global__ __launch_bounds__(256) void gemm_nt_mfma(const unsigned short* __restrict__ A,
                                                    const unsigned short* __restrict__ Bm,
                                                    OT* __restrict__ Out,
                                                    int Ndim, int Kd) {
  __shared__ __align__(16) unsigned short As[128 * 32];
  __shared__ __align__(16) unsigned short Bs[128 * 32];
  const int m0 = blockIdx.x * 128;
  const int n0 = blockIdx.y * 128;
  const int tid = threadIdx.x;
  const int wave = tid >> 6;
  const int lane = tid & 63;
  const int wr = wave >> 1, wc = wave & 1;
  const int l15 = lane & 15, l4 = lane >> 4;
  f32x4 acc[4][4] = {};

  for (int k0 = 0; k0 < Kd; k0 += 32) {
#pragma unroll
    for (int i = 0; i < 2; ++i) {
      int e = (wave * 2 + i) * 512 + lane * 8;
      int r = e >> 5, c = e & 31;
      gload_lds16(&A[(size_t)(m0 + r) * Kd + k0 + c], &As[(wave * 2 + i) * 512]);
      gload_lds16(&Bm[(size_t)(n0 + r) * Kd + k0 + c], &Bs[(wave * 2 + i) * 512]);
    }
    __syncthreads();
    bf16x8 af[4], bfr[4];
#pragma unroll
    for (int m = 0; m < 4; ++m)
      af[m] = *reinterpret_cast<const bf16x8*>(&As[(wr * 64 + m * 16 + l15) * 32 + l4 * 8]);
#pragma unroll
    for (int n = 0; n < 4; ++n)
      bfr[n] = *reinterpret_cast<const bf16x8*>(&Bs[(wc * 64 + n * 16 + l15) * 32 + l4 * 8]);
#pragma unroll
    for (int m = 0; m < 4; ++m)
#pragma unroll
      for (int n = 0; n < 4; ++n)
        acc[m][n] = __builtin_amdgcn_mfma_f32_16x16x32_bf16(af[m], bfr[n], acc[m][n], 0, 0, 0);
    __syncthreads();
  }
#pragma unroll
  for (int m = 0; m < 4; ++m)
#pragma unroll
    for (int n = 0; n < 4; ++n)
#pragma unroll
      for (int r = 0; r < 4; ++r) {
        int row = m0 + wr * 64 + m * 16 + l4 * 4 + r;
        int col = n0 + wc * 64 + n * 16 + l15;
        st1(&Out[(size_t)row * Ndim + col], acc[m][n][r]);
      }
}

// ---- splitK variant ----
__global__ __launch_bounds__(256) void gemm_nt_mfma_sk(const unsigned short* __restrict__ A,
                                                       const unsigned short* __restrict__ Bm,
                                                       float* __restrict__ Part,
                                                       int Ndim, int Kd, int kslice, int Mtot) {
  __shared__ __align__(16) unsigned short As[128 * 32];
  __shared__ __align__(16) unsigned short Bs[128 * 32];
  const int m0 = blockIdx.x * 128;
  const int n0 = blockIdx.y * 128;
  const int kz = blockIdx.z * kslice;
  const int tid = threadIdx.x;
  const int wave = tid >> 6;
  const int lane = tid & 63;
  const int wr = wave >> 1, wc = wave & 1;
  const int l15 = lane & 15, l4 = lane >> 4;
  f32x4 acc[4][4] = {};

  for (int k0 = kz; k0 < kz + kslice; k0 += 32) {
#pragma unroll
    for (int i = 0; i < 2; ++i) {
      int e = (wave * 2 + i) * 512 + lane * 8;
      int r = e >> 5, c = e & 31;
      gload_lds16(&A[(size_t)(m0 + r) * Kd + k0 + c], &As[(wave * 2 + i) * 512]);
      gload_lds16(&Bm[(size_t)(n0 + r) * Kd + k0 + c], &Bs[(wave * 2 + i) * 512]);
    }
    __syncthreads();
    bf16x8 af[4], bfr[4];
#pragma unroll
    for (int m = 0; m < 4; ++m)
      af[m] = *reinterpret_cast<const bf16x8*>(&As[(wr * 64 + m * 16 + l15) * 32 + l4 * 8]);
#pragma unroll
    for (int n = 0; n < 4; ++n)
      bfr[n] = *reinterpret_cast<const bf16x8*>(&Bs[(wc * 64 + n * 16 + l15) * 32 + l4 * 8]);
#pragma unroll
    for (int m = 0; m < 4; ++m)
#pragma unroll
      for (int n = 0; n < 4; ++n)
        acc[m][n] = __builtin_amdgcn_mfma_f32_16x16x32_bf16(af[m], bfr[n], acc[m][n], 0, 0, 0);
    __syncthreads();
  }
  float* out = Part + (size_t)blockIdx.z * Mtot * Ndim;
#pragma unroll
  for (int m = 0; m < 4; ++m)
#pragma unroll
    for (int n = 0; n < 4; ++n)
#pragma unroll
      for (int r = 0; r < 4; ++r) {
        int row = m0 + wr * 64 + m * 16 + l4 * 4 + r;
        int col = n0 + wc * 64 + n * 16 + l15;
        out[(size_t)row * Ndim + col] = acc[m][n][r];
      }
}

// ---------------- generic fp32 NT GEMM (kept only for N=16 beta) --------
template <typename AT, typename BT, typename OT>
__global__ __launch_bounds__(256) void gemm_nt(const AT* __restrict__ A,
                                               const BT* __restrict__ Bm,
                                               OT* __restrict__ Out,
                                               int Ndim, int Kd) {
  __shared__ float As[32][132];
  __shared__ float Bs[32][68];
  const int m0 = blockIdx.x * 128;
  const int n0 = blockIdx.y * 64;
  const int tid = threadIdx.x;
  const int tx = tid & 15, ty = tid >> 4;
  float acc[8][4];
#pragma unroll
  for (int i = 0; i < 8; ++i)
#pragma unroll
    for (int j = 0; j < 4; ++j) acc[i][j] = 0.f;

  for (int k0 = 0; k0 < Kd; k0 += 32) {
#pragma unroll
    for (int p = 0; p < 4; ++p) {
      int e = tid + p * 256;
      int r = e >> 3;
      int c = (e & 7) << 2;
      float4 v = ld4(A + (size_t)(m0 + r) * Kd + k0 + c);
      As[c + 0][r] = v.x; As[c + 1][r] = v.y; As[c + 2][r] = v.z; As[c + 3][r] = v.w;
    }
#pragma unroll
    for (int p = 0; p < 2; ++p) {
      int e = tid + p * 256;
      int r = e >> 3;
      int c = (e & 7) << 2;
      float4 v = make_float4(0.f, 0.f, 0.f, 0.f);
      if (n0 + r < Ndim) v = ld4(Bm + (size_t)(n0 + r) * Kd + k0 + c);
      Bs[c + 0][r] = v.x; Bs[c + 1][r] = v.y; Bs[c + 2][r] = v.z; Bs[c + 3][r] = v.w;
    }
    __syncthreads();
#pragma unroll
    for (int kk = 0; kk < 32; ++kk) {
      const float4* ar = reinterpret_cast<const float4*>(&As[kk][0]);
      const float4* br = reinterpret_cast<const float4*>(&Bs[kk][0]);
      float4 b4 = br[tx];
      float4 a0 = ar[ty * 2], a1 = ar[ty * 2 + 1];
      float av[8] = {a0.x, a0.y, a0.z, a0.w, a1.x, a1.y, a1.z, a1.w};
      float bv4[4] = {b4.x, b4.y, b4.z, b4.w};
#pragma unroll
      for (int i = 0; i < 8; ++i)
#pragma unroll
        for (int j = 0; j < 4; ++j) acc[i][j] = fmaf(av[i], bv4[j], acc[i][j]);
    }
    __syncthreads();
  }
#pragma unroll
  for (int i = 0; i < 8; ++i) {
    int m = m0 + ty * 8 + i;
#pragma unroll
    for (int j = 0; j < 4; ++j) {
      int n = n0 + tx * 4 + j;
      if (n < Ndim) st1(Out + (size_t)m * Ndim + n, acc[i][j]);
    }
  }
}

// ---------------- chunk prep (rolling conv window) ----------------
__global__ __launch_bounds__(128) void chunk_prep(
    const unsigned short* __restrict__ q_lin, const unsigned short* __restrict__ k_lin,
    const unsigned short* __restrict__ v_lin, const unsigned short* __restrict__ g_raw,
    const float* __restrict__ beta_lin, const float* __restrict__ conv_q,
    const float* __restrict__ conv_k, const float* __restrict__ conv_v,
    const float* __restrict__ A_log, const float* __restrict__ dt_bias,
    unsigned short* __restrict__ qt, unsigned short* __restrict__ u_,
    unsigned short* __restrict__ bv, unsigned short* __restrict__ bw,
    float* __restrict__ wlast) {
  const int blk = blockIdx.x;
  const int n = blk & 63;
  const int h = (blk >> 6) & 15;
  const int b = blk >> 10;
  const int kk = threadIdx.x;
  const int p = h * Kc + kk;
  float cq[4], ck[4], cv[4];
#pragma unroll
  for (int j = 0; j < 4; ++j) {
    cq[j] = conv_q[p * 4 + j];
    ck[j] = conv_k[p * 4 + j];
    cv[j] = conv_v[p * 4 + j];
  }
  const float aneg = -expf(A_log[h]);
  const float db = dt_bias[p];
  __shared__ float red[4];
  float cum = 0.f;
  const int t0 = n * Cc;
  // rolling window: raw lin values at t-3, t-2, t-1
  float xq0 = 0.f, xq1 = 0.f, xq2 = 0.f;
  float xk0 = 0.f, xk1 = 0.f, xk2 = 0.f;
  float xv0 = 0.f, xv1 = 0.f, xv2 = 0.f;
  {
    if (t0 - 3 >= 0) {
      size_t o = ((size_t)(b * Tc + t0 - 3)) * Pc + p;
      xq0 = bf2f(q_lin[o]); xk0 = bf2f(k_lin[o]); xv0 = bf2f(v_lin[o]);
    }
    if (t0 - 2 >= 0) {
      size_t o = ((size_t)(b * Tc + t0 - 2)) * Pc + p;
      xq1 = bf2f(q_lin[o]); xk1 = bf2f(k_lin[o]); xv1 = bf2f(v_lin[o]);
    }
    if (t0 - 1 >= 0) {
      size_t o = ((size_t)(b * Tc + t0 - 1)) * Pc + p;
      xq2 = bf2f(q_lin[o]); xk2 = bf2f(k_lin[o]); xv2 = bf2f(v_lin[o]);
    }
  }
  for (int c = 0; c < Cc; ++c) {
    const int t = t0 + c;
    size_t off = ((size_t)(b * Tc + t)) * Pc + p;
    float nq = bf2f(q_lin[off]), nk = bf2f(k_lin[off]), nv = bf2f(v_lin[off]);
    float qv = cq[0] * xq0 + cq[1] * xq1 + cq[2] * xq2 + cq[3] * nq;
    float kv = ck[0] * xk0 + ck[1] * xk1 + ck[2] * xk2 + ck[3] * nk;
    float vv = cv[0] * xv0 + cv[1] * xv1 + cv[2] * xv2 + cv[3] * nv;
    xq0 = xq1; xq1 = xq2; xq2 = nq;
    xk0 = xk1; xk1 = xk2; xk2 = nk;
    xv0 = xv1; xv1 = xv2; xv2 = nv;
    qv = qv / (1.f + expf(-qv));
    kv = kv / (1.f + expf(-kv));
    vv = vv / (1.f + expf(-vv));
    float a = qv * qv, bb = kv * kv;
#pragma unroll
    for (int off2 = 32; off2 > 0; off2 >>= 1) {
      a += __shfl_down(a, off2, 64);
      bb += __shfl_down(bb, off2, 64);
    }
    __syncthreads();
    if ((kk & 63) == 0) { red[(kk >> 6) * 2] = a; red[(kk >> 6) * 2 + 1] = bb; }
    __syncthreads();
    float sq = red[0] + red[2];
    float sk = red[1] + red[3];
    float qn = qv * rsqrtf(sq + 1e-12f) * 0.08838834764831845f;
    float kn = kv * rsqrtf(sk + 1e-12f);
    float g = bf2f(g_raw[off]) + db;
    float sp = (g > 20.f) ? g : log1pf(expf(g));
    cum += aneg * sp;
    float cc = fmaxf(cum, -15.f);
    float Wg = expf(cc);
    float Wi = expf(-cc);
    float beta = 1.f / (1.f + expf(-beta_lin[((size_t)(b * Tc + t)) * Hc + h]));
    size_t idx = ((size_t)blk * Cc + c) * Kc + kk;
    qt[idx] = f2bf(qn * Wg);
    u_[idx] = f2bf(kn * Wi);
    bw[idx] = f2bf(beta * kn * Wg);
    bv[idx] = f2bf(beta * vv);
    if (c == Cc - 1) wlast[(size_t)blk * Kc + kk] = Wg;
  }
}

// ---------------- MFMA chunk solve: L/intra GEMMs + doubling inverse + ev/ew GEMMs ----
// T = (I+L)^{-1} = sum_{j<64} (-L)^j, exact via doubling (N nilpotent, N^64=0).
// All matmuls NT-form: maintain row-major + transposed bf16 copies in LDS.
__global__ __launch_bounds__(256) void chunk_solve_mfma(
    const unsigned short* __restrict__ qt, const unsigned short* __restrict__ u_,
    unsigned short* __restrict__ evb,  // in: bv, out: ev
    unsigned short* __restrict__ ewb,  // in: bw, out: ew
    unsigned short* __restrict__ intra_out) {
  const int blk = blockIdx.x;
  const size_t base = (size_t)blk * (Cc * Kc);
  const size_t ibase = (size_t)blk * (Cc * Cc);
  const int tid = threadIdx.x, wave = tid >> 6, lane = tid & 63;
  const int l15 = lane & 15, l4 = lane >> 4;

  __shared__ __align__(16) char lds[65536];
  unsigned short* uS   = (unsigned short*)(lds);            // [64][128] swzA
  unsigned short* qtS  = (unsigned short*)(lds + 16384);    // [64][128] swzA
  unsigned short* bwS  = (unsigned short*)(lds + 32768);    // [64][128] swzA
  unsigned short* NLrm = (unsigned short*)(lds + 49152);    // [64][64] swzB
  unsigned short* NLT  = (unsigned short*)(lds + 57344);    // [64][64] swzB
  unsigned short* Trm  = (unsigned short*)(lds);            // over uS
  unsigned short* TT   = (unsigned short*)(lds + 8192);
  unsigned short* Prm  = (unsigned short*)(lds + 16384);    // over qtS
  unsigned short* PT   = (unsigned short*)(lds + 24576);
  unsigned short* bvT  = (unsigned short*)(lds + 32768);    // [128][64] swzB, over bwS
  unsigned short* bwT  = (unsigned short*)(lds + 49152);    // [128][64] swzB, over NL

  // ---- phase 1: stage u, bw, qt ----
#pragma unroll
  for (int i = 0; i < 4; ++i) {
    int cid = tid + i * 256;             // 0..1023
    int r = cid >> 4, c8 = (cid & 15) * 8, cb2 = (cid & 15) * 16;
    int4 vu = *(const int4*)(u_ + base + (size_t)r * 128 + c8);
    int4 vb = *(const int4*)(ewb + base + (size_t)r * 128 + c8);
    int4 vq = *(const int4*)(qt + base + (size_t)r * 128 + c8);
    stsv16B(uS, swzA(r, cb2), vu);
    stsv16B(bwS, swzA(r, cb2), vb);
    stsv16B(qtS, swzA(r, cb2), vq);
  }
  __syncthreads();

  // ---- L = bw@u^T, I = qt@u^T  (wave owns rows 16w..16w+15) ----
  const int arow = 16 * wave + l15;
  bf16x8 aBw[4], aQt[4];
#pragma unroll
  for (int ks = 0; ks < 4; ++ks) {
    aBw[ks] = ldsv8(bwS, swzA(arow, 16 * l4 + 64 * ks));
    aQt[ks] = ldsv8(qtS, swzA(arow, 16 * l4 + 64 * ks));
  }
  f32x4 Lc[4], Ic[4];
#pragma unroll
  for (int nt = 0; nt < 4; ++nt) {
    f32x4 a = {}, bq = {};
#pragma unroll
    for (int ks = 0; ks < 4; ++ks) {
      bf16x8 bu = ldsv8(uS, swzA(16 * nt + l15, 16 * l4 + 64 * ks));
      a = __builtin_amdgcn_mfma_f32_16x16x32_bf16(aBw[ks], bu, a, 0, 0, 0);
      bq = __builtin_amdgcn_mfma_f32_16x16x32_bf16(aQt[ks], bu, bq, 0, 0, 0);
    }
    Lc[nt] = a; Ic[nt] = bq;
  }
  // intra out (tril incl diag)
#pragma unroll
  for (int nt = 0; nt < 4; ++nt)
#pragma unroll
    for (int r = 0; r < 4; ++r) {
      int row = 16 * wave + 4 * l4 + r, col = 16 * nt + l15;
      intra_out[ibase + (size_t)row * 64 + col] = f2bf((col <= row) ? Ic[nt][r] : 0.f);
    }
  __syncthreads();  // all phase-1 LDS reads done

  // ---- write NL, T0 = I + NL (Tf master in f32 regs) ----
  f32x4 Tf[4];
#pragma unroll
  for (int nt = 0; nt < 4; ++nt)
#pragma unroll
    for (int r = 0; r < 4; ++r) {
      int row = 16 * wave + 4 * l4 + r, col = 16 * nt + l15;
      float nl = (col < row) ? -Lc[nt][r] : 0.f;
      unsigned short nb = f2bf(nl);
      sts16(NLrm, swzB(row, col * 2), nb);
      sts16(NLT, swzB(col, row * 2), nb);
      float t0 = nl + ((row == col) ? 1.f : 0.f);
      Tf[nt][r] = t0;
      unsigned short tb = f2bf(t0);
      sts16(Trm, swzB(row, col * 2), tb);
      sts16(TT, swzB(col, row * 2), tb);
    }
  __syncthreads();

  // ---- P1 = NL@NL ; issue bv/bw global loads (T14) ----
  bf16x8 aN[2];
#pragma unroll
  for (int ks = 0; ks < 2; ++ks) aN[ks] = ldsv8(NLrm, swzB(arow, 16 * l4 + 64 * ks));
  f32x4 Pf[4];
#pragma unroll
  for (int nt = 0; nt < 4; ++nt) {
    f32x4 acc = {};
#pragma unroll
    for (int ks = 0; ks < 2; ++ks)
      acc = __builtin_amdgcn_mfma_f32_16x16x32_bf16(aN[ks], ldsv8(NLT, swzB(16 * nt + l15, 16 * l4 + 64 * ks)), acc, 0, 0, 0);
    Pf[nt] = acc;
  }
  int4 rv[4], rw[4];
#pragma unroll
  for (int i = 0; i < 4; ++i) {
    int cid = tid + i * 256;
    int r = cid >> 4, c8 = (cid & 15) * 8;
    rv[i] = *(const int4*)(evb + base + (size_t)r * 128 + c8);
    rw[i] = *(const int4*)(ewb + base + (size_t)r * 128 + c8);
  }
  // write P (qtS region is dead)
#pragma unroll
  for (int nt = 0; nt < 4; ++nt)
#pragma unroll
    for (int r = 0; r < 4; ++r) {
      int row = 16 * wave + 4 * l4 + r, col = 16 * nt + l15;
      unsigned short pb = f2bf(Pf[nt][r]);
      sts16(Prm, swzB(row, col * 2), pb);
      sts16(PT, swzB(col, row * 2), pb);
    }
  __syncthreads();

  // ---- doubling: it=0..4: T = T + P@T ; if it<4: P = P@P ----
  for (int it = 0; it < 5; ++it) {
    bf16x8 aP[2];
#pragma unroll
    for (int ks = 0; ks < 2; ++ks) aP[ks] = ldsv8(Prm, swzB(arow, 16 * l4 + 64 * ks));
    f32x4 Tn[4], Pn[4];
#pragma unroll
    for (int nt = 0; nt < 4; ++nt) {
      f32x4 acc = Tf[nt];
#pragma unroll
      for (int ks = 0; ks < 2; ++ks)
        acc = __builtin_amdgcn_mfma_f32_16x16x32_bf16(aP[ks], ldsv8(TT, swzB(16 * nt + l15, 16 * l4 + 64 * ks)), acc, 0, 0, 0);
      Tn[nt] = acc;
    }
    if (it < 4) {
#pragma unroll
      for (int nt = 0; nt < 4; ++nt) {
        f32x4 acc = {};
#pragma unroll
        for (int ks = 0; ks < 2; ++ks)
          acc = __builtin_amdgcn_mfma_f32_16x16x32_bf16(aP[ks], ldsv8(PT, swzB(16 * nt + l15, 16 * l4 + 64 * ks)), acc, 0, 0, 0);
        Pn[nt] = acc;
      }
    }
    __syncthreads();  // all reads of Trm/TT/Prm/PT done
#pragma unroll
    for (int nt = 0; nt < 4; ++nt)
#pragma unroll
      for (int r = 0; r < 4; ++r) {
        int row = 16 * wave + 4 * l4 + r, col = 16 * nt + l15;
        unsigned short tb = f2bf(Tn[nt][r]);
        sts16(Trm, swzB(row, col * 2), tb);
        sts16(TT, swzB(col, row * 2), tb);
        if (it < 4) {
          unsigned short pb = f2bf(Pn[nt][r]);
          sts16(Prm, swzB(row, col * 2), pb);
          sts16(PT, swzB(col, row * 2), pb);
        }
      }
#pragma unroll
    for (int nt = 0; nt < 4; ++nt) Tf[nt] = Tn[nt];
    __syncthreads();
  }

  // ---- stage bv^T, bw^T (transposed) from pre-loaded regs ----
#pragma unroll
  for (int i = 0; i < 4; ++i) {
    int cid = tid + i * 256;
    int r = cid >> 4;
    const unsigned short* pv = reinterpret_cast<const unsigned short*>(&rv[i]);
    const unsigned short* pw = reinterpret_cast<const unsigned short*>(&rw[i]);
#pragma unroll
    for (int j = 0; j < 8; ++j) {
      int v = (cid & 15) * 8 + j;
      sts16(bvT, swzB(v, r * 2), pv[j]);
      sts16(bwT, swzB(v, r * 2), pw[j]);
    }
  }
  __syncthreads();

  // ---- ev = T@bv, ew = T@bw ----
  bf16x8 aT[2];
#pragma unroll
  for (int ks = 0; ks < 2; ++ks) aT[ks] = ldsv8(Trm, swzB(arow, 16 * l4 + 64 * ks));
#pragma unroll
  for (int nt = 0; nt < 8; ++nt) {
    f32x4 e = {}, w2 = {};
#pragma unroll
    for (int ks = 0; ks < 2; ++ks) {
      e = __builtin_amdgcn_mfma_f32_16x16x32_bf16(aT[ks], ldsv8(bvT, swzB(16 * nt + l15, 16 * l4 + 64 * ks)), e, 0, 0, 0);
      w2 = __builtin_amdgcn_mfma_f32_16x16x32_bf16(aT[ks], ldsv8(bwT, swzB(16 * nt + l15, 16 * l4 + 64 * ks)), w2, 0, 0, 0);
    }
#pragma unroll
    for (int r = 0; r < 4; ++r) {
      int row = 16 * wave + 4 * l4 + r, col = 16 * nt + l15;
      evb[base + (size_t)row * 128 + col] = f2bf(e[r]);
      ewb[base + (size_t)row * 128 + col] = f2bf(w2[r]);
    }
  }
}

// ---------------- MFMA scan: 1 block per (b,h), 8 waves, S in MFMA accumulators ------
__global__ __launch_bounds__(512) void scan_mfma(
    const unsigned short* __restrict__ qt, const unsigned short* __restrict__ u_,
    const unsigned short* __restrict__ evb, const unsigned short* __restrict__ ewb,
    const unsigned short* __restrict__ intra, const float* __restrict__ wlast,
    unsigned short* __restrict__ attn_o, unsigned short* __restrict__ snapb) {
  const int bh = blockIdx.x, b = bh >> 4, h = bh & 15;
  const int tid = threadIdx.x, wave = tid >> 6, lane = tid & 63;
  const int l15 = lane & 15, l4 = lane >> 4;
  __shared__ __align__(16) unsigned short ewS[8192];   // [64 c][128 k]  swzA
  __shared__ __align__(16) unsigned short qtS[8192];   // [64 c][128 k]  swzA
  __shared__ __align__(16) unsigned short uTS[8192];   // [128 k][64 c]  swzB
  __shared__ __align__(16) unsigned short iaS[4096];   // [64 c][64 j]   swzB
  __shared__ __align__(16) unsigned short sBT[16384];  // [128 v][128 k] swzA (S^T bf16)
  __shared__ __align__(16) unsigned short dBT[8192];   // [128 v][64 c]  swzB (delta^T bf16)

  f32x4 S[8] = {};
  {
    int4 z = {0, 0, 0, 0};
#pragma unroll
    for (int i = 0; i < 4; ++i) stsv16B(sBT, tid * 64 + i * 16, z);
  }

  const int sr = tid >> 3;
  const int sk0 = (tid & 7) * 16;
  const int sc0 = (tid & 7) * 8;
  int4 rEw0, rEw1, rQt0, rQt1, rU0, rU1, rIa;

#define STAGE_LOAD(CB, IB)                                                        \
  rEw0 = *(const int4*)(ewb + (CB) + sr * 128 + sk0);                             \
  rEw1 = *(const int4*)(ewb + (CB) + sr * 128 + sk0 + 8);                         \
  rQt0 = *(const int4*)(qt + (CB) + sr * 128 + sk0);                              \
  rQt1 = *(const int4*)(qt + (CB) + sr * 128 + sk0 + 8);                          \
  rU0 = *(const int4*)(u_ + (CB) + sr * 128 + sk0);                               \
  rU1 = *(const int4*)(u_ + (CB) + sr * 128 + sk0 + 8);                           \
  rIa = *(const int4*)(intra + (IB) + sr * 64 + sc0);

#define STAGE_WRITE()                                                             \
  stsv16B(ewS, swzA(sr, sk0 * 2), rEw0);                                          \
  stsv16B(ewS, swzA(sr, sk0 * 2 + 16), rEw1);                                     \
  stsv16B(qtS, swzA(sr, sk0 * 2), rQt0);                                          \
  stsv16B(qtS, swzA(sr, sk0 * 2 + 16), rQt1);                                     \
  stsv16B(iaS, swzB(sr, sc0 * 2), rIa);                                           \
  {                                                                               \
    const unsigned short* up0 = reinterpret_cast<const unsigned short*>(&rU0);    \
    const unsigned short* up1 = reinterpret_cast<const unsigned short*>(&rU1);    \
    _Pragma("unroll")                                                             \
    for (int jj = 0; jj < 8; ++jj) {                                              \
      *reinterpret_cast<unsigned short*>((char*)uTS + swzB(sk0 + jj, sr * 2)) = up0[jj];      \
      *reinterpret_cast<unsigned short*>((char*)uTS + swzB(sk0 + 8 + jj, sr * 2)) = up1[jj];  \
    }                                                                             \
  }

  {
    const size_t cb0 = (size_t)bh * 64 * 8192;
    const size_t ib0 = (size_t)bh * 64 * 4096;
    STAGE_LOAD(cb0, ib0);
    STAGE_WRITE();
  }
  __syncthreads();

  const int m = wave & 3, ntb = (wave >> 2) * 4;
  const int arow = 16 * m + l15;
  const int krow = 16 * wave + l15;

  for (int n = 0; n < NCc; ++n) {
    const size_t cb = ((size_t)bh * 64 + n) * 8192;
    const size_t ib = ((size_t)bh * 64 + n) * 4096;
    if (n < 63) { STAGE_LOAD(cb + 8192, ib + 4096); }
    bf16x8 aEw[4];
#pragma unroll
    for (int ks = 0; ks < 4; ++ks) aEw[ks] = ldsv8(ewS, swzA(arow, 16 * l4 + 64 * ks));
#pragma unroll
    for (int nt = 0; nt < 4; ++nt) {
      int v = 16 * (ntb + nt) + l15;
      f32x4 p = {};
#pragma unroll
      for (int ks = 0; ks < 4; ++ks)
        p = __builtin_amdgcn_mfma_f32_16x16x32_bf16(aEw[ks], ldsv8(sBT, swzA(v, 16 * l4 + 64 * ks)), p, 0, 0, 0);
      float d[4];
#pragma unroll
      for (int r = 0; r < 4; ++r) {
        int c = 16 * m + 4 * l4 + r;
        d[r] = bf2f(evb[cb + (size_t)c * 128 + v]) - p[r];
      }
      uint2 pk;
      pk.x = (unsigned)f2bf(d[0]) | ((unsigned)f2bf(d[1]) << 16);
      pk.y = (unsigned)f2bf(d[2]) | ((unsigned)f2bf(d[3]) << 16);
      stsv8B(dBT, swzB(v, (16 * m + 4 * l4) * 2), pk);
    }
    __syncthreads();
    bf16x8 aQt[4], aIa[2], aU[2];
#pragma unroll
    for (int ks = 0; ks < 4; ++ks) aQt[ks] = ldsv8(qtS, swzA(arow, 16 * l4 + 64 * ks));
#pragma unroll
    for (int ks = 0; ks < 2; ++ks) aIa[ks] = ldsv8(iaS, swzB(arow, 16 * l4 + 64 * ks));
#pragma unroll
    for (int ks = 0; ks < 2; ++ks) aU[ks] = ldsv8(uTS, swzB(krow, 16 * l4 + 64 * ks));
#pragma unroll
    for (int nt = 0; nt < 4; ++nt) {
      int v = 16 * (ntb + nt) + l15;
      f32x4 o = {};
#pragma unroll
      for (int ks = 0; ks < 4; ++ks)
        o = __builtin_amdgcn_mfma_f32_16x16x32_bf16(aQt[ks], ldsv8(sBT, swzA(v, 16 * l4 + 64 * ks)), o, 0, 0, 0);
#pragma unroll
      for (int ks = 0; ks < 2; ++ks)
        o = __builtin_amdgcn_mfma_f32_16x16x32_bf16(aIa[ks], ldsv8(dBT, swzB(v, 16 * l4 + 64 * ks)), o, 0, 0, 0);
#pragma unroll
      for (int r = 0; r < 4; ++r) {
        int c = 16 * m + 4 * l4 + r;
        int t = n * 64 + c;
        attn_o[((size_t)(b * Tc + t) * Hc + h) * Kc + v] = f2bf(o[r]);
      }
    }
    float wlv[4];
#pragma unroll
    for (int r = 0; r < 4; ++r)
      wlv[r] = wlast[((size_t)bh * 64 + n) * 128 + 16 * wave + 4 * l4 + r];
#pragma unroll
    for (int nt8 = 0; nt8 < 8; ++nt8) {
      int v = 16 * nt8 + l15;
      f32x4 U = {};
#pragma unroll
      for (int ks = 0; ks < 2; ++ks)
        U = __builtin_amdgcn_mfma_f32_16x16x32_bf16(aU[ks], ldsv8(dBT, swzB(v, 16 * l4 + 64 * ks)), U, 0, 0, 0);
#pragma unroll
      for (int r = 0; r < 4; ++r) S[nt8][r] = wlv[r] * (S[nt8][r] + U[r]);
    }
    __syncthreads();
#pragma unroll
    for (int nt8 = 0; nt8 < 8; ++nt8) {
      int v = 16 * nt8 + l15;
      uint2 pk;
      pk.x = (unsigned)f2bf(S[nt8][0]) | ((unsigned)f2bf(S[nt8][1]) << 16);
      pk.y = (unsigned)f2bf(S[nt8][2]) | ((unsigned)f2bf(S[nt8][3]) << 16);
      stsv8B(sBT, swzA(v, (16 * wave + 4 * l4) * 2), pk);
    }
    if (n < 63) { STAGE_WRITE(); }
    if ((n & 3) == 3) {
      int ns = n >> 2;
      size_t sb = (size_t)((ns * Bc + b) * Hc + h) * 16384;
#pragma unroll
      for (int nt8 = 0; nt8 < 8; ++nt8)
#pragma unroll
        for (int r = 0; r < 4; ++r) {
          int k = 16 * wave + 4 * l4 + r;
          snapb[sb + (size_t)k * 128 + 16 * nt8 + l15] = f2bf(S[nt8][r]);
        }
    }
    __syncthreads();
  }
#undef STAGE_LOAD
#undef STAGE_WRITE
}

// ---------------- snapshot helpers ----------------
__global__ void sdw_mul_bf16(const float* __restrict__ snap_down, const float* __restrict__ w,
                             unsigned short* __restrict__ sdwb) {
  int i = (blockIdx.x * 256 + threadIdx.x) * 4;
  float4 v = ld4(snap_down + i);
  int k = i & 16383;
  float4 ww = ld4(w + k);
  ushort4 o;
  o.x = f2bf(v.x * ww.x); o.y = f2bf(v.y * ww.y); o.z = f2bf(v.z * ww.z); o.w = f2bf(v.w * ww.w);
  *reinterpret_cast<ushort4*>(sdwb + i) = o;
}

__global__ __launch_bounds__(256) void snap_scale_kernel(const unsigned short* __restrict__ snapb,
                                                         float* __restrict__ scale) {
  int r = blockIdx.x;
  const unsigned short* row = snapb + (size_t)r * 16384;
  float s = 0.f;
  for (int ii = threadIdx.x * 4; ii < 16384; ii += 1024) {
    float4 x = ld4(row + ii);
    s += x.x * x.x + x.y * x.y + x.z * x.z + x.w * x.w;
  }
#pragma unroll
  for (int off = 32; off > 0; off >>= 1) s += __shfl_down(s, off, 64);
  __shared__ float red[4];
  if ((threadIdx.x & 63) == 0) red[threadIdx.x >> 6] = s;
  __syncthreads();
  if (threadIdx.x == 0) {
    float tot = red[0] + red[1] + red[2] + red[3];
    scale[r] = rsqrtf(tot * (1.f / 16384.f) + 1e-6f);
  }
}

__global__ void snap_reduce_scatter(const float* __restrict__ part,
                                    const float* __restrict__ scale,
                                    float* __restrict__ outp) {
  int idx = blockIdx.x * 256 + threadIdx.x;
  int l = idx & 127;
  int hh = (idx >> 7) & 15;
  int ns = (idx >> 11) & 15;
  int bb = idx >> 15;
  int r = (ns * Bc + bb) * Hc + hh;
  float s = 0.f;
#pragma unroll
  for (int z = 0; z < 16; ++z) s += part[(size_t)z * 65536 + r * 128 + l];
  outp[idx] = s * scale[r];
}

// ---------------- final rmsnorm * sigmoid(gate) ----------------
__global__ __launch_bounds__(128) void out_norm_gate(unsigned short* __restrict__ attn_io,
                                                     const unsigned short* __restrict__ gate_raw,
                                                     const float* __restrict__ bgb,
                                                     const float* __restrict__ o_norm_w) {
  const int blk = blockIdx.x;
  const int kk = threadIdx.x;
  const int h = blk & 15;
  const size_t row = (size_t)(blk >> 4);
  const int p = h * Kc + kk;
  const size_t base = (size_t)blk * Kc;
  float x = bf2f(attn_io[base + kk]);
  float ss = x * x;
#pragma unroll
  for (int off = 32; off > 0; off >>= 1) ss += __shfl_down(ss, off, 64);
  __shared__ float red[2];
  if ((kk & 63) == 0) red[kk >> 6] = ss;
  __syncthreads();
  float tot = red[0] + red[1];
  float normed = x * rsqrtf(tot * (1.f / 128.f) + 1e-6f) * o_norm_w[kk];
  float g = bf2f(gate_raw[row * Pc + p]) + bgb[p];
  float o = normed / (1.f + expf(-g));
  attn_io[base + kk] = f2bf(o);
}

// ---------------- launch ----------------
extern "C" void kernel_launch(void* const* d_in, const int* in_sizes, int n_in,
                              void* d_out, int out_size, void* d_ws, size_t ws_size,
                              hipStream_t stream) {
  (void)in_sizes; (void)n_in;
  const float* x        = (const float*)d_in[0];
  const float* Wq       = (const float*)d_in[1];
  const float* Wk       = (const float*)d_in[2];
  const float* Wv       = (const float*)d_in[3];
  const float* conv_q   = (const float*)d_in[4];
  const float* conv_k   = (const float*)d_in[5];
  const float* conv_v   = (const float*)d_in[6];
  const float* A_log    = (const float*)d_in[7];
  const float* dt_bias  = (const float*)d_in[8];
  const float* Wfa      = (const float*)d_in[9];
  const float* Wfb      = (const float*)d_in[10];
  const float* Wb       = (const float*)d_in[11];
  const float* Wga      = (const float*)d_in[12];
  const float* Wgb      = (const float*)d_in[13];
  const float* bgb      = (const float*)d_in[14];
  const float* o_norm_w = (const float*)d_in[15];
  const float* Wo       = (const float*)d_in[16];
  const float* snap_nw  = (const float*)d_in[17];
  const float* snap_down= (const float*)d_in[18];

  const size_t MP2 = (size_t)Mc * Pc * 2;
  const size_t NEED = 6 * MP2
                    + 2 * (size_t)Mc * Kc * 4
                    + (size_t)Mc * Hc * 4
                    + (size_t)Bc * Hc * NCc * Kc * 4;
  if (ws_size < NEED + 4096) {
    hipMemsetAsync(d_out, 0, (size_t)out_size * 4, stream);
    return;
  }
  char* w = (char*)d_ws;
  auto alloc = [&](size_t bytes) {
    char* r = w;
    w += (bytes + 255) & ~(size_t)255;
    return r;
  };
  unsigned short* q_lin = (unsigned short*)alloc(MP2);
  unsigned short* k_lin = (unsigned short*)alloc(MP2);
  unsigned short* v_lin = (unsigned short*)alloc(MP2);
  unsigned short* g_raw = (unsigned short*)alloc(MP2);
  unsigned short* evb   = (unsigned short*)alloc(MP2);
  unsigned short* ewb   = (unsigned short*)alloc(MP2);
  float* fa    = (float*)alloc((size_t)Mc * Kc * 4);
  float* ga    = (float*)alloc((size_t)Mc * Kc * 4);
  float* betab = (float*)alloc((size_t)Mc * Hc * 4);
  float* wlast = (float*)alloc((size_t)Bc * Hc * NCc * Kc * 4);

  unsigned short* qt = (unsigned short*)d_out;
  unsigned short* u_ = (unsigned short*)((char*)d_out + MP2);

  unsigned short* xb    = evb;
  unsigned short* Wqb   = ewb;
  unsigned short* Wkb   = ewb + 4194304;
  unsigned short* Wvb   = ewb + 8388608;
  unsigned short* Wfab  = ewb + 12582912;
  unsigned short* Wgab  = ewb + 12845056;
  unsigned short* Wfbb  = ewb + 13107200;
  unsigned short* fab   = (unsigned short*)fa;
  unsigned short* gab   = (unsigned short*)ga;

  unsigned short* intra = q_lin;
  unsigned short* Wob   = q_lin + 8388608;
  unsigned short* Wgbb  = q_lin + 12582912;
  unsigned short* attn  = k_lin;
  unsigned short* gate_raw = g_raw;
  unsigned short* snapb = v_lin;
  unsigned short* sdwb  = v_lin + (size_t)512 * 16384;
  float* partial   = (float*)ewb;
  float* snapscale = (float*)(ewb + 4400000);

  float* y = (float*)d_out;
  float* snaps_out = (float*)d_out + (size_t)Bc * Tc * Dc;

  // 0) casts
  cast_f32_bf16<<<16384, 256, 0, stream>>>(x, xb, Mc * Dc);
  cast_f32_bf16<<<4096, 256, 0, stream>>>(Wq, Wqb, Pc * Dc);
  cast_f32_bf16<<<4096, 256, 0, stream>>>(Wk, Wkb, Pc * Dc);
  cast_f32_bf16<<<4096, 256, 0, stream>>>(Wv, Wvb, Pc * Dc);
  cast_f32_bf16<<<256, 256, 0, stream>>>(Wfa, Wfab, Kc * Dc);
  cast_f32_bf16<<<256, 256, 0, stream>>>(Wga, Wgab, Kc * Dc);
  cast_f32_bf16<<<256, 256, 0, stream>>>(Wfb, Wfbb, Pc * Kc);

  // 1) input GEMMs (bf16 MFMA)
  gemm_nt_mfma<unsigned short><<<dim3(64, 16), 256, 0, stream>>>(xb, Wqb, q_lin, Pc, Dc);
  gemm_nt_mfma<unsigned short><<<dim3(64, 16), 256, 0, stream>>>(xb, Wkb, k_lin, Pc, Dc);
  gemm_nt_mfma<unsigned short><<<dim3(64, 16), 256, 0, stream>>>(xb, Wvb, v_lin, Pc, Dc);
  gemm_nt_mfma<unsigned short><<<dim3(64, 1), 256, 0, stream>>>(xb, Wfab, fab, Kc, Dc);
  gemm_nt_mfma<unsigned short><<<dim3(64, 1), 256, 0, stream>>>(xb, Wgab, gab, Kc, Dc);
  gemm_nt<float, float, float><<<dim3(64, 1), 256, 0, stream>>>(x, Wb, betab, Hc, Dc);
  gemm_nt_mfma<unsigned short><<<dim3(64, 16), 256, 0, stream>>>(fab, Wfbb, g_raw, Pc, Kc);

  // 2) chunk prep
  chunk_prep<<<Bc * Hc * NCc, 128, 0, stream>>>(q_lin, k_lin, v_lin, g_raw, betab, conv_q,
                                                conv_k, conv_v, A_log, dt_bias, qt, u_, evb,
                                                ewb, wlast);

  // 3) late casts into q_lin's dead tail
  cast_f32_bf16<<<4096, 256, 0, stream>>>(Wo, Wob, Dc * Pc);
  cast_f32_bf16<<<256, 256, 0, stream>>>(Wgb, Wgbb, Pc * Kc);

  chunk_solve_mfma<<<Bc * Hc * NCc, 256, 0, stream>>>(qt, u_, evb, ewb, intra);

  // 4) gate projection
  gemm_nt_mfma<unsigned short><<<dim3(64, 16), 256, 0, stream>>>(gab, Wgbb, gate_raw, Pc, Kc);

  // 5) MFMA scan
  scan_mfma<<<Bc * Hc, 512, 0, stream>>>(qt, u_, evb, ewb, intra, wlast, attn, snapb);

  // 6) snapshots
  sdw_mul_bf16<<<2048, 256, 0, stream>>>(snap_down, snap_nw, sdwb);
  snap_scale_kernel<<<512, 256, 0, stream>>>(snapb, snapscale);
  gemm_nt_mfma_sk<<<dim3(4, 1, 16), 256, 0, stream>>>(snapb, sdwb, partial, 128, 16384, 1024, 512);
  snap_reduce_scatter<<<256, 256, 0, stream>>>(partial, snapscale, snaps_out);

  // 7) output norm*gate + final projection
  out_norm_gate<<<Mc * Hc, 128, 0, stream>>>(attn, gate_raw, bgb, o_norm_w);
  gemm_nt_mfma<float><<<dim3(64, 16), 256, 0, stream>>>(attn, Wob, y, Dc, Pc);
}

// Round 7
// 1372.689 us; speedup vs baseline: 5.8259x; 1.0121x over previous
//
#include <hip/hip_runtime.h>

// ---------------- problem constants ----------------
constexpr int Bc   = 2;
constexpr int Tc   = 4096;
constexpr int Dc   = 2048;
constexpr int Hc   = 16;
constexpr int Kc   = 128;
constexpr int Pc   = Hc * Kc;     // 2048
constexpr int Cc   = 64;          // chunk size
constexpr int NCc  = Tc / Cc;     // 64 chunks
constexpr int Mc   = Bc * Tc;     // 8192 rows
constexpr int LATc = 128;

// ---------------- helpers ----------------
__device__ __forceinline__ float bf2f(unsigned short u) {
  unsigned int x = ((unsigned int)u) << 16;
  return __builtin_bit_cast(float, x);
}
__device__ __forceinline__ unsigned short f2bf(float f) {
  unsigned int x = __builtin_bit_cast(unsigned int, f);
  x += 0x7fffu + ((x >> 16) & 1u);
  return (unsigned short)(x >> 16);
}
__device__ __forceinline__ float4 ld4(const float* p) {
  return *reinterpret_cast<const float4*>(p);
}
__device__ __forceinline__ float4 ld4(const unsigned short* p) {
  ushort4 u = *reinterpret_cast<const ushort4*>(p);
  return make_float4(bf2f(u.x), bf2f(u.y), bf2f(u.z), bf2f(u.w));
}
__device__ __forceinline__ void st1(float* p, float v) { *p = v; }
__device__ __forceinline__ void st1(unsigned short* p, float v) { *p = f2bf(v); }

typedef __attribute__((ext_vector_type(8))) short bf16x8;
typedef __attribute__((ext_vector_type(4))) float f32x4;

// LDS swizzles: rows of stride 256B (swzA) and 128B (swzB); byte ^= ((row&7)<<4)
__device__ __forceinline__ int swzA(int row, int kbyte) { return row * 256 + (kbyte ^ ((row & 7) << 4)); }
__device__ __forceinline__ int swzB(int row, int kbyte) { return row * 128 + (kbyte ^ ((row & 7) << 4)); }
__device__ __forceinline__ bf16x8 ldsv8(const unsigned short* base, int byteoff) {
  return *reinterpret_cast<const bf16x8*>(reinterpret_cast<const char*>(base) + byteoff);
}
__device__ __forceinline__ void stsv16B(unsigned short* base, int byteoff, int4 v) {
  *reinterpret_cast<int4*>(reinterpret_cast<char*>(base) + byteoff) = v;
}
__device__ __forceinline__ void stsv8B(unsigned short* base, int byteoff, uint2 v) {
  *reinterpret_cast<uint2*>(reinterpret_cast<char*>(base) + byteoff) = v;
}
__device__ __forceinline__ unsigned short lds16(const unsigned short* base, int byteoff) {
  return *reinterpret_cast<const unsigned short*>(reinterpret_cast<const char*>(base) + byteoff);
}

// bijective XCD-aware block swizzle (T1); identity unless nwg%8==0 && nwg>=16
__device__ __forceinline__ int xcd_swz(int id, int nwg) {
  if ((nwg & 7) != 0 || nwg < 16) return id;
  return (id & 7) * (nwg >> 3) + (id >> 3);
}

// ---------------- f32 -> bf16 cast ----------------
__global__ void cast_f32_bf16(const float* __restrict__ in, unsigned short* __restrict__ out,
                              int n) {
  int i = (blockIdx.x * 256 + threadIdx.x) * 4;
  if (i < n) {
    float4 v = ld4(in + i);
    ushort4 o;
    o.x = f2bf(v.x); o.y = f2bf(v.y); o.z = f2bf(v.z); o.w = f2bf(v.w);
    *reinterpret_cast<ushort4*>(out + i) = o;
  }
}

// ---------------- bf16 MFMA NT GEMM (128x128 tile, m97 structure, XCD swizzle) ------
__device__ __forceinline__ void gload_lds16(const unsigned short* g, unsigned short* l) {
  __builtin_amdgcn_global_load_lds(
      (const __attribute__((address_space(1))) void*)g,
      (__attribute__((address_space(3))) void*)l, 16, 0, 0);
}

template <typename OT>
__global__ __launch_bounds__(256) void gemm_nt_mfma(const unsigned short* __restrict__ A,
                                                    const unsigned short* __restrict__ Bm,
                                                    OT* __restrict__ Out,
                                                    int Ndim, int Kd) {
  __shared__ __align__(16) unsigned short As[128 * 32];
  __shared__ __align__(16) unsigned short Bs[128 * 32];
  int id = blockIdx.y * gridDim.x + blockIdx.x;
  id = xcd_swz(id, gridDim.x * gridDim.y);
  const int m0 = (id % gridDim.x) * 128;
  const int n0 = (id / gridDim.x) * 128;
  const int tid = threadIdx.x;
  const int wave = tid >> 6;
  const int lane = tid & 63;
  const int wr = wave >> 1, wc = wave & 1;
  const int l15 = lane & 15, l4 = lane >> 4;
  f32x4 acc[4][4] = {};

  for (int k0 = 0; k0 < Kd; k0 += 32) {
#pragma unroll
    for (int i = 0; i < 2; ++i) {
      int e = (wave * 2 + i) * 512 + lane * 8;
      int r = e >> 5, c = e & 31;
      gload_lds16(&A[(size_t)(m0 + r) * Kd + k0 + c], &As[(wave * 2 + i) * 512]);
      gload_lds16(&Bm[(size_t)(n0 + r) * Kd + k0 + c], &Bs[(wave * 2 + i) * 512]);
    }
    __syncthreads();
    bf16x8 af[4], bfr[4];
#pragma unroll
    for (int m = 0; m < 4; ++m)
      af[m] = *reinterpret_cast<const bf16x8*>(&As[(wr * 64 + m * 16 + l15) * 32 + l4 * 8]);
#pragma unroll
    for (int n = 0; n < 4; ++n)
      bfr[n] = *reinterpret_cast<const bf16x8*>(&Bs[(wc * 64 + n * 16 + l15) * 32 + l4 * 8]);
#pragma unroll
    for (int m = 0; m < 4; ++m)
#pragma unroll
      for (int n = 0; n < 4; ++n)
        acc[m][n] = __builtin_amdgcn_mfma_f32_16x16x32_bf16(af[m], bfr[n], acc[m][n], 0, 0, 0);
    __syncthreads();
  }
#pragma unroll
  for (int m = 0; m < 4; ++m)
#pragma unroll
    for (int n = 0; n < 4; ++n)
#pragma unroll
      for (int r = 0; r < 4; ++r) {
        int row = m0 + wr * 64 + m * 16 + l4 * 4 + r;
        int col = n0 + wc * 64 + n * 16 + l15;
        st1(&Out[(size_t)row * Ndim + col], acc[m][n][r]);
      }
}

// ---- splitK variant ----
__global__ __launch_bounds__(256) void gemm_nt_mfma_sk(const unsigned short* __restrict__ A,
                                                       const unsigned short* __restrict__ Bm,
                                                       float* __restrict__ Part,
                                                       int Ndim, int Kd, int kslice, int Mtot) {
  __shared__ __align__(16) unsigned short As[128 * 32];
  __shared__ __align__(16) unsigned short Bs[128 * 32];
  const int m0 = blockIdx.x * 128;
  const int n0 = blockIdx.y * 128;
  const int kz = blockIdx.z * kslice;
  const int tid = threadIdx.x;
  const int wave = tid >> 6;
  const int lane = tid & 63;
  const int wr = wave >> 1, wc = wave & 1;
  const int l15 = lane & 15, l4 = lane >> 4;
  f32x4 acc[4][4] = {};

  for (int k0 = kz; k0 < kz + kslice; k0 += 32) {
#pragma unroll
    for (int i = 0; i < 2; ++i) {
      int e = (wave * 2 + i) * 512 + lane * 8;
      int r = e >> 5, c = e & 31;
      gload_lds16(&A[(size_t)(m0 + r) * Kd + k0 + c], &As[(wave * 2 + i) * 512]);
      gload_lds16(&Bm[(size_t)(n0 + r) * Kd + k0 + c], &Bs[(wave * 2 + i) * 512]);
    }
    __syncthreads();
    bf16x8 af[4], bfr[4];
#pragma unroll
    for (int m = 0; m < 4; ++m)
      af[m] = *reinterpret_cast<const bf16x8*>(&As[(wr * 64 + m * 16 + l15) * 32 + l4 * 8]);
#pragma unroll
    for (int n = 0; n < 4; ++n)
      bfr[n] = *reinterpret_cast<const bf16x8*>(&Bs[(wc * 64 + n * 16 + l15) * 32 + l4 * 8]);
#pragma unroll
    for (int m = 0; m < 4; ++m)
#pragma unroll
      for (int n = 0; n < 4; ++n)
        acc[m][n] = __builtin_amdgcn_mfma_f32_16x16x32_bf16(af[m], bfr[n], acc[m][n], 0, 0, 0);
    __syncthreads();
  }
  float* out = Part + (size_t)blockIdx.z * Mtot * Ndim;
#pragma unroll
  for (int m = 0; m < 4; ++m)
#pragma unroll
    for (int n = 0; n < 4; ++n)
#pragma unroll
      for (int r = 0; r < 4; ++r) {
        int row = m0 + wr * 64 + m * 16 + l4 * 4 + r;
        int col = n0 + wc * 64 + n * 16 + l15;
        out[(size_t)row * Ndim + col] = acc[m][n][r];
      }
}

// ---------------- generic fp32 NT GEMM (kept only for N=16 beta) --------
template <typename AT, typename BT, typename OT>
__global__ __launch_bounds__(256) void gemm_nt(const AT* __restrict__ A,
                                               const BT* __restrict__ Bm,
                                               OT* __restrict__ Out,
                                               int Ndim, int Kd) {
  __shared__ float As[32][132];
  __shared__ float Bs[32][68];
  const int m0 = blockIdx.x * 128;
  const int n0 = blockIdx.y * 64;
  const int tid = threadIdx.x;
  const int tx = tid & 15, ty = tid >> 4;
  float acc[8][4];
#pragma unroll
  for (int i = 0; i < 8; ++i)
#pragma unroll
    for (int j = 0; j < 4; ++j) acc[i][j] = 0.f;

  for (int k0 = 0; k0 < Kd; k0 += 32) {
#pragma unroll
    for (int p = 0; p < 4; ++p) {
      int e = tid + p * 256;
      int r = e >> 3;
      int c = (e & 7) << 2;
      float4 v = ld4(A + (size_t)(m0 + r) * Kd + k0 + c);
      As[c + 0][r] = v.x; As[c + 1][r] = v.y; As[c + 2][r] = v.z; As[c + 3][r] = v.w;
    }
#pragma unroll
    for (int p = 0; p < 2; ++p) {
      int e = tid + p * 256;
      int r = e >> 3;
      int c = (e & 7) << 2;
      float4 v = make_float4(0.f, 0.f, 0.f, 0.f);
      if (n0 + r < Ndim) v = ld4(Bm + (size_t)(n0 + r) * Kd + k0 + c);
      Bs[c + 0][r] = v.x; Bs[c + 1][r] = v.y; Bs[c + 2][r] = v.z; Bs[c + 3][r] = v.w;
    }
    __syncthreads();
#pragma unroll
    for (int kk = 0; kk < 32; ++kk) {
      const float4* ar = reinterpret_cast<const float4*>(&As[kk][0]);
      const float4* br = reinterpret_cast<const float4*>(&Bs[kk][0]);
      float4 b4 = br[tx];
      float4 a0 = ar[ty * 2], a1 = ar[ty * 2 + 1];
      float av[8] = {a0.x, a0.y, a0.z, a0.w, a1.x, a1.y, a1.z, a1.w};
      float bv4[4] = {b4.x, b4.y, b4.z, b4.w};
#pragma unroll
      for (int i = 0; i < 8; ++i)
#pragma unroll
        for (int j = 0; j < 4; ++j) acc[i][j] = fmaf(av[i], bv4[j], acc[i][j]);
    }
    __syncthreads();
  }
#pragma unroll
  for (int i = 0; i < 8; ++i) {
    int m = m0 + ty * 8 + i;
#pragma unroll
    for (int j = 0; j < 4; ++j) {
      int n = n0 + tx * 4 + j;
      if (n < Ndim) st1(Out + (size_t)m * Ndim + n, acc[i][j]);
    }
  }
}

// ---------------- chunk prep (rolling conv window) ----------------
__global__ __launch_bounds__(128) void chunk_prep(
    const unsigned short* __restrict__ q_lin, const unsigned short* __restrict__ k_lin,
    const unsigned short* __restrict__ v_lin, const unsigned short* __restrict__ g_raw,
    const float* __restrict__ beta_lin, const float* __restrict__ conv_q,
    const float* __restrict__ conv_k, const float* __restrict__ conv_v,
    const float* __restrict__ A_log, const float* __restrict__ dt_bias,
    unsigned short* __restrict__ qt, unsigned short* __restrict__ u_,
    unsigned short* __restrict__ bv, unsigned short* __restrict__ bw,
    float* __restrict__ wlast) {
  const int blk = blockIdx.x;
  const int n = blk & 63;
  const int h = (blk >> 6) & 15;
  const int b = blk >> 10;
  const int kk = threadIdx.x;
  const int p = h * Kc + kk;
  float cq[4], ck[4], cv[4];
#pragma unroll
  for (int j = 0; j < 4; ++j) {
    cq[j] = conv_q[p * 4 + j];
    ck[j] = conv_k[p * 4 + j];
    cv[j] = conv_v[p * 4 + j];
  }
  const float aneg = -expf(A_log[h]);
  const float db = dt_bias[p];
  __shared__ float red[4];
  float cum = 0.f;
  const int t0 = n * Cc;
  float xq0 = 0.f, xq1 = 0.f, xq2 = 0.f;
  float xk0 = 0.f, xk1 = 0.f, xk2 = 0.f;
  float xv0 = 0.f, xv1 = 0.f, xv2 = 0.f;
  {
    if (t0 - 3 >= 0) {
      size_t o = ((size_t)(b * Tc + t0 - 3)) * Pc + p;
      xq0 = bf2f(q_lin[o]); xk0 = bf2f(k_lin[o]); xv0 = bf2f(v_lin[o]);
    }
    if (t0 - 2 >= 0) {
      size_t o = ((size_t)(b * Tc + t0 - 2)) * Pc + p;
      xq1 = bf2f(q_lin[o]); xk1 = bf2f(k_lin[o]); xv1 = bf2f(v_lin[o]);
    }
    if (t0 - 1 >= 0) {
      size_t o = ((size_t)(b * Tc + t0 - 1)) * Pc + p;
      xq2 = bf2f(q_lin[o]); xk2 = bf2f(k_lin[o]); xv2 = bf2f(v_lin[o]);
    }
  }
  for (int c = 0; c < Cc; ++c) {
    const int t = t0 + c;
    size_t off = ((size_t)(b * Tc + t)) * Pc + p;
    float nq = bf2f(q_lin[off]), nk = bf2f(k_lin[off]), nv = bf2f(v_lin[off]);
    float qv = cq[0] * xq0 + cq[1] * xq1 + cq[2] * xq2 + cq[3] * nq;
    float kv = ck[0] * xk0 + ck[1] * xk1 + ck[2] * xk2 + ck[3] * nk;
    float vv = cv[0] * xv0 + cv[1] * xv1 + cv[2] * xv2 + cv[3] * nv;
    xq0 = xq1; xq1 = xq2; xq2 = nq;
    xk0 = xk1; xk1 = xk2; xk2 = nk;
    xv0 = xv1; xv1 = xv2; xv2 = nv;
    qv = qv / (1.f + expf(-qv));
    kv = kv / (1.f + expf(-kv));
    vv = vv / (1.f + expf(-vv));
    float a = qv * qv, bb = kv * kv;
#pragma unroll
    for (int off2 = 32; off2 > 0; off2 >>= 1) {
      a += __shfl_down(a, off2, 64);
      bb += __shfl_down(bb, off2, 64);
    }
    __syncthreads();
    if ((kk & 63) == 0) { red[(kk >> 6) * 2] = a; red[(kk >> 6) * 2 + 1] = bb; }
    __syncthreads();
    float sq = red[0] + red[2];
    float sk = red[1] + red[3];
    float qn = qv * rsqrtf(sq + 1e-12f) * 0.08838834764831845f;
    float kn = kv * rsqrtf(sk + 1e-12f);
    float g = bf2f(g_raw[off]) + db;
    float sp = (g > 20.f) ? g : log1pf(expf(g));
    cum += aneg * sp;
    float cc = fmaxf(cum, -15.f);
    float Wg = expf(cc);
    float Wi = expf(-cc);
    float beta = 1.f / (1.f + expf(-beta_lin[((size_t)(b * Tc + t)) * Hc + h]));
    size_t idx = ((size_t)blk * Cc + c) * Kc + kk;
    qt[idx] = f2bf(qn * Wg);
    u_[idx] = f2bf(kn * Wi);
    bw[idx] = f2bf(beta * kn * Wg);
    bv[idx] = f2bf(beta * vv);
    if (c == Cc - 1) wlast[(size_t)blk * Kc + kk] = Wg;
  }
}

// ---------------- MFMA chunk solve + in-place u -> u^T transpose ----------------
// T = (I+L)^{-1} via nilpotent doubling. Also rewrites u_ chunk tile as [128 k][64 c]
// (the scan consumes the transposed layout; this block is the last reader of row-major u).
__global__ __launch_bounds__(256) void chunk_solve_mfma(
    const unsigned short* __restrict__ qt, unsigned short* __restrict__ u_,
    unsigned short* __restrict__ evb,  // in: bv, out: ev
    unsigned short* __restrict__ ewb,  // in: bw, out: ew
    unsigned short* __restrict__ intra_out) {
  const int blk = blockIdx.x;
  const size_t base = (size_t)blk * (Cc * Kc);
  const size_t ibase = (size_t)blk * (Cc * Cc);
  const int tid = threadIdx.x, wave = tid >> 6, lane = tid & 63;
  const int l15 = lane & 15, l4 = lane >> 4;

  __shared__ __align__(16) char lds[65536];
  unsigned short* uS   = (unsigned short*)(lds);            // [64][128] swzA
  unsigned short* qtS  = (unsigned short*)(lds + 16384);    // [64][128] swzA
  unsigned short* bwS  = (unsigned short*)(lds + 32768);    // [64][128] swzA
  unsigned short* NLrm = (unsigned short*)(lds + 49152);    // [64][64] swzB
  unsigned short* NLT  = (unsigned short*)(lds + 57344);    // [64][64] swzB
  unsigned short* Trm  = (unsigned short*)(lds);            // over uS
  unsigned short* TT   = (unsigned short*)(lds + 8192);
  unsigned short* Prm  = (unsigned short*)(lds + 16384);    // over qtS
  unsigned short* PT   = (unsigned short*)(lds + 24576);
  unsigned short* bvT  = (unsigned short*)(lds + 32768);    // [128][64] swzB, over bwS
  unsigned short* bwT  = (unsigned short*)(lds + 49152);    // [128][64] swzB, over NL

  // ---- phase 1: stage u, bw, qt ----
#pragma unroll
  for (int i = 0; i < 4; ++i) {
    int cid = tid + i * 256;             // 0..1023
    int r = cid >> 4, c8 = (cid & 15) * 8, cb2 = (cid & 15) * 16;
    int4 vu = *(const int4*)(u_ + base + (size_t)r * 128 + c8);
    int4 vb = *(const int4*)(ewb + base + (size_t)r * 128 + c8);
    int4 vq = *(const int4*)(qt + base + (size_t)r * 128 + c8);
    stsv16B(uS, swzA(r, cb2), vu);
    stsv16B(bwS, swzA(r, cb2), vb);
    stsv16B(qtS, swzA(r, cb2), vq);
  }
  __syncthreads();

  // ---- L = bw@u^T, I = qt@u^T ----
  const int arow = 16 * wave + l15;
  bf16x8 aBw[4], aQt[4];
#pragma unroll
  for (int ks = 0; ks < 4; ++ks) {
    aBw[ks] = ldsv8(bwS, swzA(arow, 16 * l4 + 64 * ks));
    aQt[ks] = ldsv8(qtS, swzA(arow, 16 * l4 + 64 * ks));
  }
  f32x4 Lc[4], Ic[4];
#pragma unroll
  for (int nt = 0; nt < 4; ++nt) {
    f32x4 a = {}, bq = {};
#pragma unroll
    for (int ks = 0; ks < 4; ++ks) {
      bf16x8 bu = ldsv8(uS, swzA(16 * nt + l15, 16 * l4 + 64 * ks));
      a = __builtin_amdgcn_mfma_f32_16x16x32_bf16(aBw[ks], bu, a, 0, 0, 0);
      bq = __builtin_amdgcn_mfma_f32_16x16x32_bf16(aQt[ks], bu, bq, 0, 0, 0);
    }
    Lc[nt] = a; Ic[nt] = bq;
  }
  // intra out (tril incl diag)
#pragma unroll
  for (int nt = 0; nt < 4; ++nt)
#pragma unroll
    for (int r = 0; r < 4; ++r) {
      int row = 16 * wave + 4 * l4 + r, col = 16 * nt + l15;
      intra_out[ibase + (size_t)row * 64 + col] = f2bf((col <= row) ? Ic[nt][r] : 0.f);
    }

  // ---- in-place u^T write-back (uS still live; global u_ not re-read after this) ----
  // item w2: k = w2>>3 in [0,128), cg = w2&7; lane reads column slices c = cg + 8j
  // (c&7 varies per lane -> conflict-free swizzled reads), writes u_[k*64 + c].
#pragma unroll
  for (int i = 0; i < 4; ++i) {
    int w2 = tid + i * 256;
    int k = w2 >> 3, cg = w2 & 7;
    unsigned short tmp[8];
#pragma unroll
    for (int j = 0; j < 8; ++j) {
      int c = cg + 8 * j;
      tmp[j] = lds16(uS, swzA(c, 2 * k));
    }
#pragma unroll
    for (int j = 0; j < 8; ++j)
      u_[base + (size_t)k * 64 + cg + 8 * j] = tmp[j];
  }
  __syncthreads();  // all uS reads done; overlay with T

  // ---- write NL, T0 = I + NL ----
  f32x4 Tf[4];
#pragma unroll
  for (int nt = 0; nt < 4; ++nt)
#pragma unroll
    for (int r = 0; r < 4; ++r) {
      int row = 16 * wave + 4 * l4 + r, col = 16 * nt + l15;
      float nl = (col < row) ? -Lc[nt][r] : 0.f;
      unsigned short nb = f2bf(nl);
      sts16_hlp:;
      *reinterpret_cast<unsigned short*>((char*)NLrm + swzB(row, col * 2)) = nb;
      *reinterpret_cast<unsigned short*>((char*)NLT + swzB(col, row * 2)) = nb;
      float t0 = nl + ((row == col) ? 1.f : 0.f);
      Tf[nt][r] = t0;
      unsigned short tb = f2bf(t0);
      *reinterpret_cast<unsigned short*>((char*)Trm + swzB(row, col * 2)) = tb;
      *reinterpret_cast<unsigned short*>((char*)TT + swzB(col, row * 2)) = tb;
    }
  __syncthreads();

  // ---- P1 = NL@NL ; prefetch bv/bw ----
  bf16x8 aN[2];
#pragma unroll
  for (int ks = 0; ks < 2; ++ks) aN[ks] = ldsv8(NLrm, swzB(arow, 16 * l4 + 64 * ks));
  f32x4 Pf[4];
#pragma unroll
  for (int nt = 0; nt < 4; ++nt) {
    f32x4 acc = {};
#pragma unroll
    for (int ks = 0; ks < 2; ++ks)
      acc = __builtin_amdgcn_mfma_f32_16x16x32_bf16(aN[ks], ldsv8(NLT, swzB(16 * nt + l15, 16 * l4 + 64 * ks)), acc, 0, 0, 0);
    Pf[nt] = acc;
  }
  int4 rv[4], rw[4];
#pragma unroll
  for (int i = 0; i < 4; ++i) {
    int cid = tid + i * 256;
    int r = cid >> 4, c8 = (cid & 15) * 8;
    rv[i] = *(const int4*)(evb + base + (size_t)r * 128 + c8);
    rw[i] = *(const int4*)(ewb + base + (size_t)r * 128 + c8);
  }
#pragma unroll
  for (int nt = 0; nt < 4; ++nt)
#pragma unroll
    for (int r = 0; r < 4; ++r) {
      int row = 16 * wave + 4 * l4 + r, col = 16 * nt + l15;
      unsigned short pb = f2bf(Pf[nt][r]);
      *reinterpret_cast<unsigned short*>((char*)Prm + swzB(row, col * 2)) = pb;
      *reinterpret_cast<unsigned short*>((char*)PT + swzB(col, row * 2)) = pb;
    }
  __syncthreads();

  // ---- doubling: it=0..4: T = T + P@T ; if it<4: P = P@P ----
  for (int it = 0; it < 5; ++it) {
    bf16x8 aP[2];
#pragma unroll
    for (int ks = 0; ks < 2; ++ks) aP[ks] = ldsv8(Prm, swzB(arow, 16 * l4 + 64 * ks));
    f32x4 Tn[4], Pn[4];
#pragma unroll
    for (int nt = 0; nt < 4; ++nt) {
      f32x4 acc = Tf[nt];
#pragma unroll
      for (int ks = 0; ks < 2; ++ks)
        acc = __builtin_amdgcn_mfma_f32_16x16x32_bf16(aP[ks], ldsv8(TT, swzB(16 * nt + l15, 16 * l4 + 64 * ks)), acc, 0, 0, 0);
      Tn[nt] = acc;
    }
    if (it < 4) {
#pragma unroll
      for (int nt = 0; nt < 4; ++nt) {
        f32x4 acc = {};
#pragma unroll
        for (int ks = 0; ks < 2; ++ks)
          acc = __builtin_amdgcn_mfma_f32_16x16x32_bf16(aP[ks], ldsv8(PT, swzB(16 * nt + l15, 16 * l4 + 64 * ks)), acc, 0, 0, 0);
        Pn[nt] = acc;
      }
    }
    __syncthreads();
#pragma unroll
    for (int nt = 0; nt < 4; ++nt)
#pragma unroll
      for (int r = 0; r < 4; ++r) {
        int row = 16 * wave + 4 * l4 + r, col = 16 * nt + l15;
        unsigned short tb = f2bf(Tn[nt][r]);
        *reinterpret_cast<unsigned short*>((char*)Trm + swzB(row, col * 2)) = tb;
        *reinterpret_cast<unsigned short*>((char*)TT + swzB(col, row * 2)) = tb;
        if (it < 4) {
          unsigned short pb = f2bf(Pn[nt][r]);
          *reinterpret_cast<unsigned short*>((char*)Prm + swzB(row, col * 2)) = pb;
          *reinterpret_cast<unsigned short*>((char*)PT + swzB(col, row * 2)) = pb;
        }
      }
#pragma unroll
    for (int nt = 0; nt < 4; ++nt) Tf[nt] = Tn[nt];
    __syncthreads();
  }

  // ---- stage bv^T, bw^T from pre-loaded regs ----
#pragma unroll
  for (int i = 0; i < 4; ++i) {
    int cid = tid + i * 256;
    int r = cid >> 4;
    const unsigned short* pv = reinterpret_cast<const unsigned short*>(&rv[i]);
    const unsigned short* pw = reinterpret_cast<const unsigned short*>(&rw[i]);
#pragma unroll
    for (int j = 0; j < 8; ++j) {
      int v = (cid & 15) * 8 + j;
      *reinterpret_cast<unsigned short*>((char*)bvT + swzB(v, r * 2)) = pv[j];
      *reinterpret_cast<unsigned short*>((char*)bwT + swzB(v, r * 2)) = pw[j];
    }
  }
  __syncthreads();

  // ---- ev = T@bv, ew = T@bw ----
  bf16x8 aT[2];
#pragma unroll
  for (int ks = 0; ks < 2; ++ks) aT[ks] = ldsv8(Trm, swzB(arow, 16 * l4 + 64 * ks));
#pragma unroll
  for (int nt = 0; nt < 8; ++nt) {
    f32x4 e = {}, w2 = {};
#pragma unroll
    for (int ks = 0; ks < 2; ++ks) {
      e = __builtin_amdgcn_mfma_f32_16x16x32_bf16(aT[ks], ldsv8(bvT, swzB(16 * nt + l15, 16 * l4 + 64 * ks)), e, 0, 0, 0);
      w2 = __builtin_amdgcn_mfma_f32_16x16x32_bf16(aT[ks], ldsv8(bwT, swzB(16 * nt + l15, 16 * l4 + 64 * ks)), w2, 0, 0, 0);
    }
#pragma unroll
    for (int r = 0; r < 4; ++r) {
      int row = 16 * wave + 4 * l4 + r, col = 16 * nt + l15;
      evb[base + (size_t)row * 128 + col] = f2bf(e[r]);
      ewb[base + (size_t)row * 128 + col] = f2bf(w2[r]);
    }
  }
}

// ---------------- MFMA scan: 1 block per (b,h), 8 waves, S in MFMA accumulators ------
// uT param is the transposed u ([128 k][64 c] per chunk, produced by chunk_solve_mfma).
__global__ __launch_bounds__(512) void scan_mfma(
    const unsigned short* __restrict__ qt, const unsigned short* __restrict__ uT,
    const unsigned short* __restrict__ evb, const unsigned short* __restrict__ ewb,
    const unsigned short* __restrict__ intra, const float* __restrict__ wlast,
    unsigned short* __restrict__ attn_o, unsigned short* __restrict__ snapb) {
  const int bh = blockIdx.x, b = bh >> 4, h = bh & 15;
  const int tid = threadIdx.x, wave = tid >> 6, lane = tid & 63;
  const int l15 = lane & 15, l4 = lane >> 4;
  __shared__ __align__(16) unsigned short ewS[8192];   // [64 c][128 k]  swzA
  __shared__ __align__(16) unsigned short qtS[8192];   // [64 c][128 k]  swzA
  __shared__ __align__(16) unsigned short evS[8192];   // [64 c][128 v]  swzA
  __shared__ __align__(16) unsigned short uTS[8192];   // [128 k][64 c]  swzB
  __shared__ __align__(16) unsigned short iaS[4096];   // [64 c][64 j]   swzB
  __shared__ __align__(16) unsigned short sBT[16384];  // [128 v][128 k] swzA (S^T bf16)
  __shared__ __align__(16) unsigned short dBT[8192];   // [128 v][64 c]  swzB (delta^T bf16)

  f32x4 S[8] = {};
  {
    int4 z = {0, 0, 0, 0};
#pragma unroll
    for (int i = 0; i < 4; ++i) stsv16B(sBT, tid * 64 + i * 16, z);
  }

  const int sr = tid >> 3;           // 0..63
  const int sk0 = (tid & 7) * 16;    // ushort col base (128-wide)
  const int sc0 = (tid & 7) * 8;     // ushort col base (64-wide)
  const int tk = tid >> 3;           // uT row base (k = tk and tk+64)
  const int wloff = 16 * wave + 4 * l4;
  int4 rEw0, rEw1, rQt0, rQt1, rEv0, rEv1, rUT0, rUT1, rIa;
  float4 rWlN, rWlC;

#define STAGE_LOAD(CB, IB, NN)                                                    \
  rEw0 = *(const int4*)(ewb + (CB) + sr * 128 + sk0);                             \
  rEw1 = *(const int4*)(ewb + (CB) + sr * 128 + sk0 + 8);                         \
  rQt0 = *(const int4*)(qt + (CB) + sr * 128 + sk0);                              \
  rQt1 = *(const int4*)(qt + (CB) + sr * 128 + sk0 + 8);                          \
  rEv0 = *(const int4*)(evb + (CB) + sr * 128 + sk0);                             \
  rEv1 = *(const int4*)(evb + (CB) + sr * 128 + sk0 + 8);                         \
  rUT0 = *(const int4*)(uT + (CB) + (size_t)tk * 64 + sc0);                       \
  rUT1 = *(const int4*)(uT + (CB) + (size_t)(tk + 64) * 64 + sc0);                \
  rIa = *(const int4*)(intra + (IB) + sr * 64 + sc0);                             \
  rWlN = ld4(wlast + ((size_t)bh * 64 + (NN)) * 128 + wloff);

#define STAGE_WRITE()                                                             \
  stsv16B(ewS, swzA(sr, sk0 * 2), rEw0);                                          \
  stsv16B(ewS, swzA(sr, sk0 * 2 + 16), rEw1);                                     \
  stsv16B(qtS, swzA(sr, sk0 * 2), rQt0);                                          \
  stsv16B(qtS, swzA(sr, sk0 * 2 + 16), rQt1);                                     \
  stsv16B(evS, swzA(sr, sk0 * 2), rEv0);                                          \
  stsv16B(evS, swzA(sr, sk0 * 2 + 16), rEv1);                                     \
  stsv16B(iaS, swzB(sr, sc0 * 2), rIa);                                           \
  stsv16B(uTS, swzB(tk, sc0 * 2), rUT0);                                          \
  stsv16B(uTS, swzB(tk + 64, sc0 * 2), rUT1);

  // prologue: stage chunk 0
  {
    const size_t cb0 = (size_t)bh * 64 * 8192;
    const size_t ib0 = (size_t)bh * 64 * 4096;
    STAGE_LOAD(cb0, ib0, 0);
    STAGE_WRITE();
    rWlC = rWlN;
  }
  __syncthreads();

  const int m = wave & 3, ntb = (wave >> 2) * 4;
  const int arow = 16 * m + l15;
  const int krow = 16 * wave + l15;

  for (int n = 0; n < NCc; ++n) {
    const size_t cb = ((size_t)bh * 64 + n) * 8192;
    const size_t ib = ((size_t)bh * 64 + n) * 4096;
    // ---- Phase A: prefetch n+1 + delta = ev - ew@S -> dBT ----
    if (n < 63) { STAGE_LOAD(cb + 8192, ib + 4096, n + 1); }
    bf16x8 aEw[4];
#pragma unroll
    for (int ks = 0; ks < 4; ++ks) aEw[ks] = ldsv8(ewS, swzA(arow, 16 * l4 + 64 * ks));
#pragma unroll
    for (int nt = 0; nt < 4; ++nt) {
      int v = 16 * (ntb + nt) + l15;
      f32x4 p = {};
#pragma unroll
      for (int ks = 0; ks < 4; ++ks)
        p = __builtin_amdgcn_mfma_f32_16x16x32_bf16(aEw[ks], ldsv8(sBT, swzA(v, 16 * l4 + 64 * ks)), p, 0, 0, 0);
      float d[4];
#pragma unroll
      for (int r = 0; r < 4; ++r) {
        int c = 16 * m + 4 * l4 + r;
        d[r] = bf2f(lds16(evS, swzA(c, 2 * v))) - p[r];
      }
      uint2 pk;
      pk.x = (unsigned)f2bf(d[0]) | ((unsigned)f2bf(d[1]) << 16);
      pk.y = (unsigned)f2bf(d[2]) | ((unsigned)f2bf(d[3]) << 16);
      stsv8B(dBT, swzB(v, (16 * m + 4 * l4) * 2), pk);
    }
    __syncthreads();
    // ---- Phase B1: o = qt@S + ia@delta -> global; S = wl*(S + uT@delta) ----
    bf16x8 aQt[4], aIa[2], aU[2];
#pragma unroll
    for (int ks = 0; ks < 4; ++ks) aQt[ks] = ldsv8(qtS, swzA(arow, 16 * l4 + 64 * ks));
#pragma unroll
    for (int ks = 0; ks < 2; ++ks) aIa[ks] = ldsv8(iaS, swzB(arow, 16 * l4 + 64 * ks));
#pragma unroll
    for (int ks = 0; ks < 2; ++ks) aU[ks] = ldsv8(uTS, swzB(krow, 16 * l4 + 64 * ks));
#pragma unroll
    for (int nt = 0; nt < 4; ++nt) {
      int v = 16 * (ntb + nt) + l15;
      f32x4 o = {};
#pragma unroll
      for (int ks = 0; ks < 4; ++ks)
        o = __builtin_amdgcn_mfma_f32_16x16x32_bf16(aQt[ks], ldsv8(sBT, swzA(v, 16 * l4 + 64 * ks)), o, 0, 0, 0);
#pragma unroll
      for (int ks = 0; ks < 2; ++ks)
        o = __builtin_amdgcn_mfma_f32_16x16x32_bf16(aIa[ks], ldsv8(dBT, swzB(v, 16 * l4 + 64 * ks)), o, 0, 0, 0);
#pragma unroll
      for (int r = 0; r < 4; ++r) {
        int c = 16 * m + 4 * l4 + r;
        int t = n * 64 + c;
        attn_o[((size_t)(b * Tc + t) * Hc + h) * Kc + v] = f2bf(o[r]);
      }
    }
    float wlv[4] = {rWlC.x, rWlC.y, rWlC.z, rWlC.w};
#pragma unroll
    for (int nt8 = 0; nt8 < 8; ++nt8) {
      int v = 16 * nt8 + l15;
      f32x4 U = {};
#pragma unroll
      for (int ks = 0; ks < 2; ++ks)
        U = __builtin_amdgcn_mfma_f32_16x16x32_bf16(aU[ks], ldsv8(dBT, swzB(v, 16 * l4 + 64 * ks)), U, 0, 0, 0);
#pragma unroll
      for (int r = 0; r < 4; ++r) S[nt8][r] = wlv[r] * (S[nt8][r] + U[r]);
    }
    __syncthreads();
    // ---- Phase B2: S -> sBT (bf16), staging writes for n+1, snapshot ----
#pragma unroll
    for (int nt8 = 0; nt8 < 8; ++nt8) {
      int v = 16 * nt8 + l15;
      uint2 pk;
      pk.x = (unsigned)f2bf(S[nt8][0]) | ((unsigned)f2bf(S[nt8][1]) << 16);
      pk.y = (unsigned)f2bf(S[nt8][2]) | ((unsigned)f2bf(S[nt8][3]) << 16);
      stsv8B(sBT, swzA(v, (16 * wave + 4 * l4) * 2), pk);
    }
    if (n < 63) { STAGE_WRITE(); rWlC = rWlN; }
    if ((n & 3) == 3) {
      int ns = n >> 2;
      size_t sb = (size_t)((ns * Bc + b) * Hc + h) * 16384;
#pragma unroll
      for (int nt8 = 0; nt8 < 8; ++nt8)
#pragma unroll
        for (int r = 0; r < 4; ++r) {
          int k = 16 * wave + 4 * l4 + r;
          snapb[sb + (size_t)k * 128 + 16 * nt8 + l15] = f2bf(S[nt8][r]);
        }
    }
    __syncthreads();
  }
#undef STAGE_LOAD
#undef STAGE_WRITE
}

// ---------------- snapshot helpers ----------------
__global__ void sdw_mul_bf16(const float* __restrict__ snap_down, const float* __restrict__ w,
                             unsigned short* __restrict__ sdwb) {
  int i = (blockIdx.x * 256 + threadIdx.x) * 4;
  float4 v = ld4(snap_down + i);
  int k = i & 16383;
  float4 ww = ld4(w + k);
  ushort4 o;
  o.x = f2bf(v.x * ww.x); o.y = f2bf(v.y * ww.y); o.z = f2bf(v.z * ww.z); o.w = f2bf(v.w * ww.w);
  *reinterpret_cast<ushort4*>(sdwb + i) = o;
}

__global__ __launch_bounds__(256) void snap_scale_kernel(const unsigned short* __restrict__ snapb,
                                                         float* __restrict__ scale) {
  int r = blockIdx.x;
  const unsigned short* row = snapb + (size_t)r * 16384;
  float s = 0.f;
  for (int ii = threadIdx.x * 4; ii < 16384; ii += 1024) {
    float4 x = ld4(row + ii);
    s += x.x * x.x + x.y * x.y + x.z * x.z + x.w * x.w;
  }
#pragma unroll
  for (int off = 32; off > 0; off >>= 1) s += __shfl_down(s, off, 64);
  __shared__ float red[4];
  if ((threadIdx.x & 63) == 0) red[threadIdx.x >> 6] = s;
  __syncthreads();
  if (threadIdx.x == 0) {
    float tot = red[0] + red[1] + red[2] + red[3];
    scale[r] = rsqrtf(tot * (1.f / 16384.f) + 1e-6f);
  }
}

__global__ void snap_reduce_scatter(const float* __restrict__ part,
                                    const float* __restrict__ scale,
                                    float* __restrict__ outp) {
  int idx = blockIdx.x * 256 + threadIdx.x;
  int l = idx & 127;
  int hh = (idx >> 7) & 15;
  int ns = (idx >> 11) & 15;
  int bb = idx >> 15;
  int r = (ns * Bc + bb) * Hc + hh;
  float s = 0.f;
#pragma unroll
  for (int z = 0; z < 16; ++z) s += part[(size_t)z * 65536 + r * 128 + l];
  outp[idx] = s * scale[r];
}

// ---------------- final rmsnorm * sigmoid(gate): wave-per-row, no barriers ----------
__global__ __launch_bounds__(256) void out_norm_gate(unsigned short* __restrict__ attn_io,
                                                     const unsigned short* __restrict__ gate_raw,
                                                     const float* __restrict__ bgb,
                                                     const float* __restrict__ o_norm_w) {
  const int wave = threadIdx.x >> 6, lane = threadIdx.x & 63;
  const int blk = blockIdx.x * 4 + wave;  // (b*T + t)*H + h
  const int h = blk & 15;
  const size_t row = (size_t)(blk >> 4);
  const size_t base = (size_t)blk * Kc;
  ushort2 xv = *reinterpret_cast<const ushort2*>(attn_io + base + 2 * lane);
  float x0 = bf2f(xv.x), x1 = bf2f(xv.y);
  float ss = x0 * x0 + x1 * x1;
#pragma unroll
  for (int off = 32; off > 0; off >>= 1) ss += __shfl_xor(ss, off, 64);
  float inv = rsqrtf(ss * (1.f / 128.f) + 1e-6f);
  const int p0 = h * Kc + 2 * lane;
  ushort2 gv = *reinterpret_cast<const ushort2*>(gate_raw + row * Pc + p0);
  float g0 = bf2f(gv.x) + bgb[p0];
  float g1 = bf2f(gv.y) + bgb[p0 + 1];
  float o0 = x0 * inv * o_norm_w[2 * lane] / (1.f + expf(-g0));
  float o1 = x1 * inv * o_norm_w[2 * lane + 1] / (1.f + expf(-g1));
  ushort2 ov; ov.x = f2bf(o0); ov.y = f2bf(o1);
  *reinterpret_cast<ushort2*>(attn_io + base + 2 * lane) = ov;
}

// ---------------- launch ----------------
extern "C" void kernel_launch(void* const* d_in, const int* in_sizes, int n_in,
                              void* d_out, int out_size, void* d_ws, size_t ws_size,
                              hipStream_t stream) {
  (void)in_sizes; (void)n_in;
  const float* x        = (const float*)d_in[0];
  const float* Wq       = (const float*)d_in[1];
  const float* Wk       = (const float*)d_in[2];
  const float* Wv       = (const float*)d_in[3];
  const float* conv_q   = (const float*)d_in[4];
  const float* conv_k   = (const float*)d_in[5];
  const float* conv_v   = (const float*)d_in[6];
  const float* A_log    = (const float*)d_in[7];
  const float* dt_bias  = (const float*)d_in[8];
  const float* Wfa      = (const float*)d_in[9];
  const float* Wfb      = (const float*)d_in[10];
  const float* Wb       = (const float*)d_in[11];
  const float* Wga      = (const float*)d_in[12];
  const float* Wgb      = (const float*)d_in[13];
  const float* bgb      = (const float*)d_in[14];
  const float* o_norm_w = (const float*)d_in[15];
  const float* Wo       = (const float*)d_in[16];
  const float* snap_nw  = (const float*)d_in[17];
  const float* snap_down= (const float*)d_in[18];

  const size_t MP2 = (size_t)Mc * Pc * 2;
  const size_t NEED = 6 * MP2
                    + 2 * (size_t)Mc * Kc * 4
                    + (size_t)Mc * Hc * 4
                    + (size_t)Bc * Hc * NCc * Kc * 4;
  if (ws_size < NEED + 4096) {
    hipMemsetAsync(d_out, 0, (size_t)out_size * 4, stream);
    return;
  }
  char* w = (char*)d_ws;
  auto alloc = [&](size_t bytes) {
    char* r = w;
    w += (bytes + 255) & ~(size_t)255;
    return r;
  };
  unsigned short* q_lin = (unsigned short*)alloc(MP2);
  unsigned short* k_lin = (unsigned short*)alloc(MP2);
  unsigned short* v_lin = (unsigned short*)alloc(MP2);
  unsigned short* g_raw = (unsigned short*)alloc(MP2);
  unsigned short* evb   = (unsigned short*)alloc(MP2);
  unsigned short* ewb   = (unsigned short*)alloc(MP2);
  float* fa    = (float*)alloc((size_t)Mc * Kc * 4);
  float* ga    = (float*)alloc((size_t)Mc * Kc * 4);
  float* betab = (float*)alloc((size_t)Mc * Hc * 4);
  float* wlast = (float*)alloc((size_t)Bc * Hc * NCc * Kc * 4);

  unsigned short* qt = (unsigned short*)d_out;
  unsigned short* u_ = (unsigned short*)((char*)d_out + MP2);

  unsigned short* xb    = evb;
  unsigned short* Wqb   = ewb;
  unsigned short* Wkb   = ewb + 4194304;
  unsigned short* Wvb   = ewb + 8388608;
  unsigned short* Wfab  = ewb + 12582912;
  unsigned short* Wgab  = ewb + 12845056;
  unsigned short* Wfbb  = ewb + 13107200;
  unsigned short* fab   = (unsigned short*)fa;
  unsigned short* gab   = (unsigned short*)ga;

  unsigned short* intra = q_lin;
  unsigned short* Wob   = q_lin + 8388608;
  unsigned short* Wgbb  = q_lin + 12582912;
  unsigned short* attn  = k_lin;
  unsigned short* gate_raw = g_raw;
  unsigned short* snapb = v_lin;
  unsigned short* sdwb  = v_lin + (size_t)512 * 16384;
  float* partial   = (float*)ewb;
  float* snapscale = (float*)(ewb + 4400000);

  float* y = (float*)d_out;
  float* snaps_out = (float*)d_out + (size_t)Bc * Tc * Dc;

  // 0) casts
  cast_f32_bf16<<<16384, 256, 0, stream>>>(x, xb, Mc * Dc);
  cast_f32_bf16<<<4096, 256, 0, stream>>>(Wq, Wqb, Pc * Dc);
  cast_f32_bf16<<<4096, 256, 0, stream>>>(Wk, Wkb, Pc * Dc);
  cast_f32_bf16<<<4096, 256, 0, stream>>>(Wv, Wvb, Pc * Dc);
  cast_f32_bf16<<<256, 256, 0, stream>>>(Wfa, Wfab, Kc * Dc);
  cast_f32_bf16<<<256, 256, 0, stream>>>(Wga, Wgab, Kc * Dc);
  cast_f32_bf16<<<256, 256, 0, stream>>>(Wfb, Wfbb, Pc * Kc);

  // 1) input GEMMs (bf16 MFMA)
  gemm_nt_mfma<unsigned short><<<dim3(64, 16), 256, 0, stream>>>(xb, Wqb, q_lin, Pc, Dc);
  gemm_nt_mfma<unsigned short><<<dim3(64, 16), 256, 0, stream>>>(xb, Wkb, k_lin, Pc, Dc);
  gemm_nt_mfma<unsigned short><<<dim3(64, 16), 256, 0, stream>>>(xb, Wvb, v_lin, Pc, Dc);
  gemm_nt_mfma<unsigned short><<<dim3(64, 1), 256, 0, stream>>>(xb, Wfab, fab, Kc, Dc);
  gemm_nt_mfma<unsigned short><<<dim3(64, 1), 256, 0, stream>>>(xb, Wgab, gab, Kc, Dc);
  gemm_nt<float, float, float><<<dim3(64, 1), 256, 0, stream>>>(x, Wb, betab, Hc, Dc);
  gemm_nt_mfma<unsigned short><<<dim3(64, 16), 256, 0, stream>>>(fab, Wfbb, g_raw, Pc, Kc);

  // 2) chunk prep
  chunk_prep<<<Bc * Hc * NCc, 128, 0, stream>>>(q_lin, k_lin, v_lin, g_raw, betab, conv_q,
                                                conv_k, conv_v, A_log, dt_bias, qt, u_, evb,
                                                ewb, wlast);

  // 3) late casts into q_lin's dead tail
  cast_f32_bf16<<<4096, 256, 0, stream>>>(Wo, Wob, Dc * Pc);
  cast_f32_bf16<<<256, 256, 0, stream>>>(Wgb, Wgbb, Pc * Kc);

  // chunk solve (also transposes u -> uT in place)
  chunk_solve_mfma<<<Bc * Hc * NCc, 256, 0, stream>>>(qt, u_, evb, ewb, intra);

  // 4) gate projection
  gemm_nt_mfma<unsigned short><<<dim3(64, 16), 256, 0, stream>>>(gab, Wgbb, gate_raw, Pc, Kc);

  // 5) MFMA scan (u_ now holds uT)
  scan_mfma<<<Bc * Hc, 512, 0, stream>>>(qt, u_, evb, ewb, intra, wlast, attn, snapb);

  // 6) snapshots
  sdw_mul_bf16<<<2048, 256, 0, stream>>>(snap_down, snap_nw, sdwb);
  snap_scale_kernel<<<512, 256, 0, stream>>>(snapb, snapscale);
  gemm_nt_mfma_sk<<<dim3(4, 1, 16), 256, 0, stream>>>(snapb, sdwb, partial, 128, 16384, 1024, 512);
  snap_reduce_scatter<<<256, 256, 0, stream>>>(partial, snapscale, snaps_out);

  // 7) output norm*gate + final projection
  out_norm_gate<<<Mc * Hc / 4, 256, 0, stream>>>(attn, gate_raw, bgb, o_norm_w);
  gemm_nt_mfma<float><<<dim3(64, 16), 256, 0, stream>>>(attn, Wob, y, Dc, Pc);
}

// Round 8
// 1259.145 us; speedup vs baseline: 6.3512x; 1.0902x over previous
//
#include <hip/hip_runtime.h>

// ---------------- problem constants ----------------
constexpr int Bc   = 2;
constexpr int Tc   = 4096;
constexpr int Dc   = 2048;
constexpr int Hc   = 16;
constexpr int Kc   = 128;
constexpr int Pc   = Hc * Kc;     // 2048
constexpr int Cc   = 64;          // chunk size
constexpr int NCc  = Tc / Cc;     // 64 chunks
constexpr int Mc   = Bc * Tc;     // 8192 rows
constexpr int LATc = 128;

// ---------------- helpers ----------------
__device__ __forceinline__ float bf2f(unsigned short u) {
  unsigned int x = ((unsigned int)u) << 16;
  return __builtin_bit_cast(float, x);
}
__device__ __forceinline__ unsigned short f2bf(float f) {
  unsigned int x = __builtin_bit_cast(unsigned int, f);
  x += 0x7fffu + ((x >> 16) & 1u);
  return (unsigned short)(x >> 16);
}
__device__ __forceinline__ float4 ld4(const float* p) {
  return *reinterpret_cast<const float4*>(p);
}
__device__ __forceinline__ float4 ld4(const unsigned short* p) {
  ushort4 u = *reinterpret_cast<const ushort4*>(p);
  return make_float4(bf2f(u.x), bf2f(u.y), bf2f(u.z), bf2f(u.w));
}
__device__ __forceinline__ void st1(float* p, float v) { *p = v; }
__device__ __forceinline__ void st1(unsigned short* p, float v) { *p = f2bf(v); }

typedef __attribute__((ext_vector_type(8))) short bf16x8;
typedef __attribute__((ext_vector_type(4))) float f32x4;

// LDS swizzles: rows of stride 256B (swzA) and 128B (swzB); byte ^= ((row&7)<<4)
__device__ __forceinline__ int swzA(int row, int kbyte) { return row * 256 + (kbyte ^ ((row & 7) << 4)); }
__device__ __forceinline__ int swzB(int row, int kbyte) { return row * 128 + (kbyte ^ ((row & 7) << 4)); }
__device__ __forceinline__ bf16x8 ldsv8(const unsigned short* base, int byteoff) {
  return *reinterpret_cast<const bf16x8*>(reinterpret_cast<const char*>(base) + byteoff);
}
__device__ __forceinline__ void stsv16B(unsigned short* base, int byteoff, int4 v) {
  *reinterpret_cast<int4*>(reinterpret_cast<char*>(base) + byteoff) = v;
}
__device__ __forceinline__ void stsv8B(unsigned short* base, int byteoff, uint2 v) {
  *reinterpret_cast<uint2*>(reinterpret_cast<char*>(base) + byteoff) = v;
}
__device__ __forceinline__ unsigned short lds16(const unsigned short* base, int byteoff) {
  return *reinterpret_cast<const unsigned short*>(reinterpret_cast<const char*>(base) + byteoff);
}

// bijective XCD-aware block swizzle (T1); identity unless nwg%8==0 && nwg>=16
__device__ __forceinline__ int xcd_swz(int id, int nwg) {
  if ((nwg & 7) != 0 || nwg < 16) return id;
  return (id & 7) * (nwg >> 3) + (id >> 3);
}

// ---------------- f32 -> bf16 cast ----------------
__global__ void cast_f32_bf16(const float* __restrict__ in, unsigned short* __restrict__ out,
                              int n) {
  int i = (blockIdx.x * 256 + threadIdx.x) * 4;
  if (i < n) {
    float4 v = ld4(in + i);
    ushort4 o;
    o.x = f2bf(v.x); o.y = f2bf(v.y); o.z = f2bf(v.z); o.w = f2bf(v.w);
    *reinterpret_cast<ushort4*>(out + i) = o;
  }
}

// ---------------- bf16 MFMA NT GEMM (128x128 tile, m97 structure, XCD swizzle) ------
__device__ __forceinline__ void gload_lds16(const unsigned short* g, unsigned short* l) {
  __builtin_amdgcn_global_load_lds(
      (const __attribute__((address_space(1))) void*)g,
      (__attribute__((address_space(3))) void*)l, 16, 0, 0);
}

template <typename OT>
__global__ __launch_bounds__(256) void gemm_nt_mfma(const unsigned short* __restrict__ A,
                                                    const unsigned short* __restrict__ Bm,
                                                    OT* __restrict__ Out,
                                                    int Ndim, int Kd) {
  __shared__ __align__(16) unsigned short As[128 * 32];
  __shared__ __align__(16) unsigned short Bs[128 * 32];
  int id = blockIdx.y * gridDim.x + blockIdx.x;
  id = xcd_swz(id, gridDim.x * gridDim.y);
  const int m0 = (id % gridDim.x) * 128;
  const int n0 = (id / gridDim.x) * 128;
  const int tid = threadIdx.x;
  const int wave = tid >> 6;
  const int lane = tid & 63;
  const int wr = wave >> 1, wc = wave & 1;
  const int l15 = lane & 15, l4 = lane >> 4;
  f32x4 acc[4][4] = {};

  for (int k0 = 0; k0 < Kd; k0 += 32) {
#pragma unroll
    for (int i = 0; i < 2; ++i) {
      int e = (wave * 2 + i) * 512 + lane * 8;
      int r = e >> 5, c = e & 31;
      gload_lds16(&A[(size_t)(m0 + r) * Kd + k0 + c], &As[(wave * 2 + i) * 512]);
      gload_lds16(&Bm[(size_t)(n0 + r) * Kd + k0 + c], &Bs[(wave * 2 + i) * 512]);
    }
    __syncthreads();
    bf16x8 af[4], bfr[4];
#pragma unroll
    for (int m = 0; m < 4; ++m)
      af[m] = *reinterpret_cast<const bf16x8*>(&As[(wr * 64 + m * 16 + l15) * 32 + l4 * 8]);
#pragma unroll
    for (int n = 0; n < 4; ++n)
      bfr[n] = *reinterpret_cast<const bf16x8*>(&Bs[(wc * 64 + n * 16 + l15) * 32 + l4 * 8]);
#pragma unroll
    for (int m = 0; m < 4; ++m)
#pragma unroll
      for (int n = 0; n < 4; ++n)
        acc[m][n] = __builtin_amdgcn_mfma_f32_16x16x32_bf16(af[m], bfr[n], acc[m][n], 0, 0, 0);
    __syncthreads();
  }
#pragma unroll
  for (int m = 0; m < 4; ++m)
#pragma unroll
    for (int n = 0; n < 4; ++n)
#pragma unroll
      for (int r = 0; r < 4; ++r) {
        int row = m0 + wr * 64 + m * 16 + l4 * 4 + r;
        int col = n0 + wc * 64 + n * 16 + l15;
        st1(&Out[(size_t)row * Ndim + col], acc[m][n][r]);
      }
}

// ---- splitK variant ----
__global__ __launch_bounds__(256) void gemm_nt_mfma_sk(const unsigned short* __restrict__ A,
                                                       const unsigned short* __restrict__ Bm,
                                                       float* __restrict__ Part,
                                                       int Ndim, int Kd, int kslice, int Mtot) {
  __shared__ __align__(16) unsigned short As[128 * 32];
  __shared__ __align__(16) unsigned short Bs[128 * 32];
  const int m0 = blockIdx.x * 128;
  const int n0 = blockIdx.y * 128;
  const int kz = blockIdx.z * kslice;
  const int tid = threadIdx.x;
  const int wave = tid >> 6;
  const int lane = tid & 63;
  const int wr = wave >> 1, wc = wave & 1;
  const int l15 = lane & 15, l4 = lane >> 4;
  f32x4 acc[4][4] = {};

  for (int k0 = kz; k0 < kz + kslice; k0 += 32) {
#pragma unroll
    for (int i = 0; i < 2; ++i) {
      int e = (wave * 2 + i) * 512 + lane * 8;
      int r = e >> 5, c = e & 31;
      gload_lds16(&A[(size_t)(m0 + r) * Kd + k0 + c], &As[(wave * 2 + i) * 512]);
      gload_lds16(&Bm[(size_t)(n0 + r) * Kd + k0 + c], &Bs[(wave * 2 + i) * 512]);
    }
    __syncthreads();
    bf16x8 af[4], bfr[4];
#pragma unroll
    for (int m = 0; m < 4; ++m)
      af[m] = *reinterpret_cast<const bf16x8*>(&As[(wr * 64 + m * 16 + l15) * 32 + l4 * 8]);
#pragma unroll
    for (int n = 0; n < 4; ++n)
      bfr[n] = *reinterpret_cast<const bf16x8*>(&Bs[(wc * 64 + n * 16 + l15) * 32 + l4 * 8]);
#pragma unroll
    for (int m = 0; m < 4; ++m)
#pragma unroll
      for (int n = 0; n < 4; ++n)
        acc[m][n] = __builtin_amdgcn_mfma_f32_16x16x32_bf16(af[m], bfr[n], acc[m][n], 0, 0, 0);
    __syncthreads();
  }
  float* out = Part + (size_t)blockIdx.z * Mtot * Ndim;
#pragma unroll
  for (int m = 0; m < 4; ++m)
#pragma unroll
    for (int n = 0; n < 4; ++n)
#pragma unroll
      for (int r = 0; r < 4; ++r) {
        int row = m0 + wr * 64 + m * 16 + l4 * 4 + r;
        int col = n0 + wc * 64 + n * 16 + l15;
        out[(size_t)row * Ndim + col] = acc[m][n][r];
      }
}

// ---------------- generic fp32 NT GEMM (kept only for N=16 beta) --------
template <typename AT, typename BT, typename OT>
__global__ __launch_bounds__(256) void gemm_nt(const AT* __restrict__ A,
                                               const BT* __restrict__ Bm,
                                               OT* __restrict__ Out,
                                               int Ndim, int Kd) {
  __shared__ float As[32][132];
  __shared__ float Bs[32][68];
  const int m0 = blockIdx.x * 128;
  const int n0 = blockIdx.y * 64;
  const int tid = threadIdx.x;
  const int tx = tid & 15, ty = tid >> 4;
  float acc[8][4];
#pragma unroll
  for (int i = 0; i < 8; ++i)
#pragma unroll
    for (int j = 0; j < 4; ++j) acc[i][j] = 0.f;

  for (int k0 = 0; k0 < Kd; k0 += 32) {
#pragma unroll
    for (int p = 0; p < 4; ++p) {
      int e = tid + p * 256;
      int r = e >> 3;
      int c = (e & 7) << 2;
      float4 v = ld4(A + (size_t)(m0 + r) * Kd + k0 + c);
      As[c + 0][r] = v.x; As[c + 1][r] = v.y; As[c + 2][r] = v.z; As[c + 3][r] = v.w;
    }
#pragma unroll
    for (int p = 0; p < 2; ++p) {
      int e = tid + p * 256;
      int r = e >> 3;
      int c = (e & 7) << 2;
      float4 v = make_float4(0.f, 0.f, 0.f, 0.f);
      if (n0 + r < Ndim) v = ld4(Bm + (size_t)(n0 + r) * Kd + k0 + c);
      Bs[c + 0][r] = v.x; Bs[c + 1][r] = v.y; Bs[c + 2][r] = v.z; Bs[c + 3][r] = v.w;
    }
    __syncthreads();
#pragma unroll
    for (int kk = 0; kk < 32; ++kk) {
      const float4* ar = reinterpret_cast<const float4*>(&As[kk][0]);
      const float4* br = reinterpret_cast<const float4*>(&Bs[kk][0]);
      float4 b4 = br[tx];
      float4 a0 = ar[ty * 2], a1 = ar[ty * 2 + 1];
      float av[8] = {a0.x, a0.y, a0.z, a0.w, a1.x, a1.y, a1.z, a1.w};
      float bv4[4] = {b4.x, b4.y, b4.z, b4.w};
#pragma unroll
      for (int i = 0; i < 8; ++i)
#pragma unroll
        for (int j = 0; j < 4; ++j) acc[i][j] = fmaf(av[i], bv4[j], acc[i][j]);
    }
    __syncthreads();
  }
#pragma unroll
  for (int i = 0; i < 8; ++i) {
    int m = m0 + ty * 8 + i;
#pragma unroll
    for (int j = 0; j < 4; ++j) {
      int n = n0 + tx * 4 + j;
      if (n < Ndim) st1(Out + (size_t)m * Ndim + n, acc[i][j]);
    }
  }
}

// ---------------- chunk prep: one WAVE per chunk, lane owns 2 channels, no barriers ----
// grid: Bc*Hc*NCc/4 = 512 blocks x 256 threads (4 waves = 4 chunks)
__global__ __launch_bounds__(256) void chunk_prep(
    const unsigned short* __restrict__ q_lin, const unsigned short* __restrict__ k_lin,
    const unsigned short* __restrict__ v_lin, const unsigned short* __restrict__ g_raw,
    const float* __restrict__ beta_lin, const float* __restrict__ conv_q,
    const float* __restrict__ conv_k, const float* __restrict__ conv_v,
    const float* __restrict__ A_log, const float* __restrict__ dt_bias,
    unsigned short* __restrict__ qt, unsigned short* __restrict__ u_,
    unsigned short* __restrict__ bv, unsigned short* __restrict__ bw,
    float* __restrict__ wlast) {
  const int wave = threadIdx.x >> 6, lane = threadIdx.x & 63;
  const int cid = blockIdx.x * 4 + wave;  // (b*H+h)*NC + n
  const int n = cid & 63;
  const int h = (cid >> 6) & 15;
  const int b = cid >> 10;
  const int k0 = 2 * lane;
  const int p = h * Kc + k0;
  float cq[2][4], ck[2][4], cv[2][4];
#pragma unroll
  for (int s = 0; s < 2; ++s)
#pragma unroll
    for (int j = 0; j < 4; ++j) {
      cq[s][j] = conv_q[(p + s) * 4 + j];
      ck[s][j] = conv_k[(p + s) * 4 + j];
      cv[s][j] = conv_v[(p + s) * 4 + j];
    }
  const float aneg = -expf(A_log[h]);
  const float db0 = dt_bias[p], db1 = dt_bias[p + 1];
  float cum0 = 0.f, cum1 = 0.f;
  const int t0 = n * Cc;
  // rolling windows (raw lin at t-3,t-2,t-1) for 2 channels x 3 streams
  float wq[2][3] = {}, wk[2][3] = {}, wv[2][3] = {};
#pragma unroll
  for (int d = 0; d < 3; ++d) {
    int ts = t0 - 3 + d;
    if (ts >= 0) {
      size_t o = ((size_t)(b * Tc + ts)) * Pc + p;
      ushort2 q2 = *(const ushort2*)(q_lin + o);
      ushort2 k2 = *(const ushort2*)(k_lin + o);
      ushort2 v2 = *(const ushort2*)(v_lin + o);
      wq[0][d] = bf2f(q2.x); wq[1][d] = bf2f(q2.y);
      wk[0][d] = bf2f(k2.x); wk[1][d] = bf2f(k2.y);
      wv[0][d] = bf2f(v2.x); wv[1][d] = bf2f(v2.y);
    }
  }
  for (int c = 0; c < Cc; ++c) {
    const int t = t0 + c;
    size_t off = ((size_t)(b * Tc + t)) * Pc + p;
    ushort2 q2 = *(const ushort2*)(q_lin + off);
    ushort2 k2 = *(const ushort2*)(k_lin + off);
    ushort2 v2 = *(const ushort2*)(v_lin + off);
    ushort2 g2 = *(const ushort2*)(g_raw + off);
    float nq[2] = {bf2f(q2.x), bf2f(q2.y)};
    float nk[2] = {bf2f(k2.x), bf2f(k2.y)};
    float nv[2] = {bf2f(v2.x), bf2f(v2.y)};
    float qv[2], kv[2], vv[2];
#pragma unroll
    for (int s = 0; s < 2; ++s) {
      qv[s] = cq[s][0] * wq[s][0] + cq[s][1] * wq[s][1] + cq[s][2] * wq[s][2] + cq[s][3] * nq[s];
      kv[s] = ck[s][0] * wk[s][0] + ck[s][1] * wk[s][1] + ck[s][2] * wk[s][2] + ck[s][3] * nk[s];
      vv[s] = cv[s][0] * wv[s][0] + cv[s][1] * wv[s][1] + cv[s][2] * wv[s][2] + cv[s][3] * nv[s];
      wq[s][0] = wq[s][1]; wq[s][1] = wq[s][2]; wq[s][2] = nq[s];
      wk[s][0] = wk[s][1]; wk[s][1] = wk[s][2]; wk[s][2] = nk[s];
      wv[s][0] = wv[s][1]; wv[s][1] = wv[s][2]; wv[s][2] = nv[s];
      qv[s] = qv[s] / (1.f + expf(-qv[s]));
      kv[s] = kv[s] / (1.f + expf(-kv[s]));
      vv[s] = vv[s] / (1.f + expf(-vv[s]));
    }
    float a = qv[0] * qv[0] + qv[1] * qv[1];
    float bb = kv[0] * kv[0] + kv[1] * kv[1];
#pragma unroll
    for (int off2 = 32; off2 > 0; off2 >>= 1) {
      a += __shfl_xor(a, off2, 64);
      bb += __shfl_xor(bb, off2, 64);
    }
    float rq = rsqrtf(a + 1e-12f) * 0.08838834764831845f;  // * K^-0.5
    float rk = rsqrtf(bb + 1e-12f);
    float g0 = bf2f(g2.x) + db0, g1 = bf2f(g2.y) + db1;
    float sp0 = (g0 > 20.f) ? g0 : log1pf(expf(g0));
    float sp1 = (g1 > 20.f) ? g1 : log1pf(expf(g1));
    cum0 += aneg * sp0; cum1 += aneg * sp1;
    float cc0 = fmaxf(cum0, -15.f), cc1 = fmaxf(cum1, -15.f);
    float Wg0 = expf(cc0), Wg1 = expf(cc1);
    float Wi0 = expf(-cc0), Wi1 = expf(-cc1);
    float beta = 1.f / (1.f + expf(-beta_lin[((size_t)(b * Tc + t)) * Hc + h]));
    size_t idx = ((size_t)cid * Cc + c) * Kc + k0;
    ushort2 o1, o2, o3, o4;
    o1.x = f2bf(qv[0] * rq * Wg0); o1.y = f2bf(qv[1] * rq * Wg1);
    o2.x = f2bf(kv[0] * rk * Wi0); o2.y = f2bf(kv[1] * rk * Wi1);
    o3.x = f2bf(beta * kv[0] * rk * Wg0); o3.y = f2bf(beta * kv[1] * rk * Wg1);
    o4.x = f2bf(beta * vv[0]); o4.y = f2bf(beta * vv[1]);
    *(ushort2*)(qt + idx) = o1;
    *(ushort2*)(u_ + idx) = o2;
    *(ushort2*)(bw + idx) = o3;
    *(ushort2*)(bv + idx) = o4;
    if (c == Cc - 1) {
      wlast[(size_t)cid * Kc + k0] = Wg0;
      wlast[(size_t)cid * Kc + k0 + 1] = Wg1;
    }
  }
}

// ---------------- MFMA chunk solve + in-place u -> u^T transpose ----------------
__global__ __launch_bounds__(256) void chunk_solve_mfma(
    const unsigned short* __restrict__ qt, unsigned short* __restrict__ u_,
    unsigned short* __restrict__ evb,  // in: bv, out: ev
    unsigned short* __restrict__ ewb,  // in: bw, out: ew
    unsigned short* __restrict__ intra_out) {
  const int blk = blockIdx.x;
  const size_t base = (size_t)blk * (Cc * Kc);
  const size_t ibase = (size_t)blk * (Cc * Cc);
  const int tid = threadIdx.x, wave = tid >> 6, lane = tid & 63;
  const int l15 = lane & 15, l4 = lane >> 4;

  __shared__ __align__(16) char lds[65536];
  unsigned short* uS   = (unsigned short*)(lds);            // [64][128] swzA
  unsigned short* qtS  = (unsigned short*)(lds + 16384);    // [64][128] swzA
  unsigned short* bwS  = (unsigned short*)(lds + 32768);    // [64][128] swzA
  unsigned short* NLrm = (unsigned short*)(lds + 49152);    // [64][64] swzB
  unsigned short* NLT  = (unsigned short*)(lds + 57344);    // [64][64] swzB
  unsigned short* Trm  = (unsigned short*)(lds);            // over uS
  unsigned short* TT   = (unsigned short*)(lds + 8192);
  unsigned short* Prm  = (unsigned short*)(lds + 16384);    // over qtS
  unsigned short* PT   = (unsigned short*)(lds + 24576);
  unsigned short* bvT  = (unsigned short*)(lds + 32768);    // [128][64] swzB, over bwS
  unsigned short* bwT  = (unsigned short*)(lds + 49152);    // [128][64] swzB, over NL

#pragma unroll
  for (int i = 0; i < 4; ++i) {
    int cid = tid + i * 256;
    int r = cid >> 4, c8 = (cid & 15) * 8, cb2 = (cid & 15) * 16;
    int4 vu = *(const int4*)(u_ + base + (size_t)r * 128 + c8);
    int4 vb = *(const int4*)(ewb + base + (size_t)r * 128 + c8);
    int4 vq = *(const int4*)(qt + base + (size_t)r * 128 + c8);
    stsv16B(uS, swzA(r, cb2), vu);
    stsv16B(bwS, swzA(r, cb2), vb);
    stsv16B(qtS, swzA(r, cb2), vq);
  }
  __syncthreads();

  const int arow = 16 * wave + l15;
  bf16x8 aBw[4], aQt[4];
#pragma unroll
  for (int ks = 0; ks < 4; ++ks) {
    aBw[ks] = ldsv8(bwS, swzA(arow, 16 * l4 + 64 * ks));
    aQt[ks] = ldsv8(qtS, swzA(arow, 16 * l4 + 64 * ks));
  }
  f32x4 Lc[4], Ic[4];
#pragma unroll
  for (int nt = 0; nt < 4; ++nt) {
    f32x4 a = {}, bq = {};
#pragma unroll
    for (int ks = 0; ks < 4; ++ks) {
      bf16x8 bu = ldsv8(uS, swzA(16 * nt + l15, 16 * l4 + 64 * ks));
      a = __builtin_amdgcn_mfma_f32_16x16x32_bf16(aBw[ks], bu, a, 0, 0, 0);
      bq = __builtin_amdgcn_mfma_f32_16x16x32_bf16(aQt[ks], bu, bq, 0, 0, 0);
    }
    Lc[nt] = a; Ic[nt] = bq;
  }
#pragma unroll
  for (int nt = 0; nt < 4; ++nt)
#pragma unroll
    for (int r = 0; r < 4; ++r) {
      int row = 16 * wave + 4 * l4 + r, col = 16 * nt + l15;
      intra_out[ibase + (size_t)row * 64 + col] = f2bf((col <= row) ? Ic[nt][r] : 0.f);
    }

  // in-place u^T write-back
#pragma unroll
  for (int i = 0; i < 4; ++i) {
    int w2 = tid + i * 256;
    int k = w2 >> 3, cg = w2 & 7;
    unsigned short tmp[8];
#pragma unroll
    for (int j = 0; j < 8; ++j) {
      int c = cg + 8 * j;
      tmp[j] = lds16(uS, swzA(c, 2 * k));
    }
#pragma unroll
    for (int j = 0; j < 8; ++j)
      u_[base + (size_t)k * 64 + cg + 8 * j] = tmp[j];
  }
  __syncthreads();

  f32x4 Tf[4];
#pragma unroll
  for (int nt = 0; nt < 4; ++nt)
#pragma unroll
    for (int r = 0; r < 4; ++r) {
      int row = 16 * wave + 4 * l4 + r, col = 16 * nt + l15;
      float nl = (col < row) ? -Lc[nt][r] : 0.f;
      unsigned short nb = f2bf(nl);
      *reinterpret_cast<unsigned short*>((char*)NLrm + swzB(row, col * 2)) = nb;
      *reinterpret_cast<unsigned short*>((char*)NLT + swzB(col, row * 2)) = nb;
      float t0 = nl + ((row == col) ? 1.f : 0.f);
      Tf[nt][r] = t0;
      unsigned short tb = f2bf(t0);
      *reinterpret_cast<unsigned short*>((char*)Trm + swzB(row, col * 2)) = tb;
      *reinterpret_cast<unsigned short*>((char*)TT + swzB(col, row * 2)) = tb;
    }
  __syncthreads();

  bf16x8 aN[2];
#pragma unroll
  for (int ks = 0; ks < 2; ++ks) aN[ks] = ldsv8(NLrm, swzB(arow, 16 * l4 + 64 * ks));
  f32x4 Pf[4];
#pragma unroll
  for (int nt = 0; nt < 4; ++nt) {
    f32x4 acc = {};
#pragma unroll
    for (int ks = 0; ks < 2; ++ks)
      acc = __builtin_amdgcn_mfma_f32_16x16x32_bf16(aN[ks], ldsv8(NLT, swzB(16 * nt + l15, 16 * l4 + 64 * ks)), acc, 0, 0, 0);
    Pf[nt] = acc;
  }
  int4 rv[4], rw[4];
#pragma unroll
  for (int i = 0; i < 4; ++i) {
    int cid = tid + i * 256;
    int r = cid >> 4, c8 = (cid & 15) * 8;
    rv[i] = *(const int4*)(evb + base + (size_t)r * 128 + c8);
    rw[i] = *(const int4*)(ewb + base + (size_t)r * 128 + c8);
  }
#pragma unroll
  for (int nt = 0; nt < 4; ++nt)
#pragma unroll
    for (int r = 0; r < 4; ++r) {
      int row = 16 * wave + 4 * l4 + r, col = 16 * nt + l15;
      unsigned short pb = f2bf(Pf[nt][r]);
      *reinterpret_cast<unsigned short*>((char*)Prm + swzB(row, col * 2)) = pb;
      *reinterpret_cast<unsigned short*>((char*)PT + swzB(col, row * 2)) = pb;
    }
  __syncthreads();

  for (int it = 0; it < 5; ++it) {
    bf16x8 aP[2];
#pragma unroll
    for (int ks = 0; ks < 2; ++ks) aP[ks] = ldsv8(Prm, swzB(arow, 16 * l4 + 64 * ks));
    f32x4 Tn[4], Pn[4];
#pragma unroll
    for (int nt = 0; nt < 4; ++nt) {
      f32x4 acc = Tf[nt];
#pragma unroll
      for (int ks = 0; ks < 2; ++ks)
        acc = __builtin_amdgcn_mfma_f32_16x16x32_bf16(aP[ks], ldsv8(TT, swzB(16 * nt + l15, 16 * l4 + 64 * ks)), acc, 0, 0, 0);
      Tn[nt] = acc;
    }
    if (it < 4) {
#pragma unroll
      for (int nt = 0; nt < 4; ++nt) {
        f32x4 acc = {};
#pragma unroll
        for (int ks = 0; ks < 2; ++ks)
          acc = __builtin_amdgcn_mfma_f32_16x16x32_bf16(aP[ks], ldsv8(PT, swzB(16 * nt + l15, 16 * l4 + 64 * ks)), acc, 0, 0, 0);
        Pn[nt] = acc;
      }
    }
    __syncthreads();
#pragma unroll
    for (int nt = 0; nt < 4; ++nt)
#pragma unroll
      for (int r = 0; r < 4; ++r) {
        int row = 16 * wave + 4 * l4 + r, col = 16 * nt + l15;
        unsigned short tb = f2bf(Tn[nt][r]);
        *reinterpret_cast<unsigned short*>((char*)Trm + swzB(row, col * 2)) = tb;
        *reinterpret_cast<unsigned short*>((char*)TT + swzB(col, row * 2)) = tb;
        if (it < 4) {
          unsigned short pb = f2bf(Pn[nt][r]);
          *reinterpret_cast<unsigned short*>((char*)Prm + swzB(row, col * 2)) = pb;
          *reinterpret_cast<unsigned short*>((char*)PT + swzB(col, row * 2)) = pb;
        }
      }
#pragma unroll
    for (int nt = 0; nt < 4; ++nt) Tf[nt] = Tn[nt];
    __syncthreads();
  }

#pragma unroll
  for (int i = 0; i < 4; ++i) {
    int cid = tid + i * 256;
    int r = cid >> 4;
    const unsigned short* pv = reinterpret_cast<const unsigned short*>(&rv[i]);
    const unsigned short* pw = reinterpret_cast<const unsigned short*>(&rw[i]);
#pragma unroll
    for (int j = 0; j < 8; ++j) {
      int v = (cid & 15) * 8 + j;
      *reinterpret_cast<unsigned short*>((char*)bvT + swzB(v, r * 2)) = pv[j];
      *reinterpret_cast<unsigned short*>((char*)bwT + swzB(v, r * 2)) = pw[j];
    }
  }
  __syncthreads();

  bf16x8 aT[2];
#pragma unroll
  for (int ks = 0; ks < 2; ++ks) aT[ks] = ldsv8(Trm, swzB(arow, 16 * l4 + 64 * ks));
#pragma unroll
  for (int nt = 0; nt < 8; ++nt) {
    f32x4 e = {}, w2 = {};
#pragma unroll
    for (int ks = 0; ks < 2; ++ks) {
      e = __builtin_amdgcn_mfma_f32_16x16x32_bf16(aT[ks], ldsv8(bvT, swzB(16 * nt + l15, 16 * l4 + 64 * ks)), e, 0, 0, 0);
      w2 = __builtin_amdgcn_mfma_f32_16x16x32_bf16(aT[ks], ldsv8(bwT, swzB(16 * nt + l15, 16 * l4 + 64 * ks)), w2, 0, 0, 0);
    }
#pragma unroll
    for (int r = 0; r < 4; ++r) {
      int row = 16 * wave + 4 * l4 + r, col = 16 * nt + l15;
      evb[base + (size_t)row * 128 + col] = f2bf(e[r]);
      ewb[base + (size_t)row * 128 + col] = f2bf(w2[r]);
    }
  }
}

// ---------------- MFMA scan, v-split x2: grid = B*H*2, 8 waves --------------------
// blk = bh*2 + vh; block owns v-columns [vh*64, vh*64+64). Wave = (m = wave&3,
// vg = wave>>2): owns o-tiles (m, nt=2vg..2vg+1) and S k-rows 16*wave.
__global__ __launch_bounds__(512) void scan_mfma(
    const unsigned short* __restrict__ qt, const unsigned short* __restrict__ uT,
    const unsigned short* __restrict__ evb, const unsigned short* __restrict__ ewb,
    const unsigned short* __restrict__ intra, const float* __restrict__ wlast,
    unsigned short* __restrict__ attn_o, unsigned short* __restrict__ snapb) {
  const int blk = blockIdx.x;
  const int bh = blk >> 1, vh = blk & 1;
  const int b = bh >> 4, h = bh & 15;
  const int v0 = vh * 64;
  const int tid = threadIdx.x, wave = tid >> 6, lane = tid & 63;
  const int l15 = lane & 15, l4 = lane >> 4;
  __shared__ __align__(16) unsigned short ewS[8192];  // [64 c][128 k] swzA
  __shared__ __align__(16) unsigned short qtS[8192];  // [64 c][128 k] swzA
  __shared__ __align__(16) unsigned short uTS[8192];  // [128 k][64 c] swzB
  __shared__ __align__(16) unsigned short iaS[4096];  // [64 c][64 j]  swzB
  __shared__ __align__(16) unsigned short evS[4096];  // [64 c][64 v]  swzB (slice)
  __shared__ __align__(16) unsigned short sBT[8192];  // [64 v][128 k] swzA (S^T slice)
  __shared__ __align__(16) unsigned short dBT[4096];  // [64 v][64 c]  swzB (delta^T)

  f32x4 S[4] = {};
  {
    int4 z = {0, 0, 0, 0};
    stsv16B(sBT, tid * 32, z);
    stsv16B(sBT, tid * 32 + 16, z);
  }

  const int sr = tid >> 3;           // 0..63
  const int sk0 = (tid & 7) * 16;    // 128-wide col base
  const int sc0 = (tid & 7) * 8;     // 64-wide col base
  const int tk = tid >> 3;           // uT rows tk, tk+64
  const int wloff = 16 * wave + 4 * l4;
  int4 rEw0, rEw1, rQt0, rQt1, rEv, rUT0, rUT1, rIa;
  float4 rWlN, rWlC;

#define STAGE_LOAD(CB, IB, NN)                                                    \
  rEw0 = *(const int4*)(ewb + (CB) + sr * 128 + sk0);                             \
  rEw1 = *(const int4*)(ewb + (CB) + sr * 128 + sk0 + 8);                         \
  rQt0 = *(const int4*)(qt + (CB) + sr * 128 + sk0);                              \
  rQt1 = *(const int4*)(qt + (CB) + sr * 128 + sk0 + 8);                          \
  rEv = *(const int4*)(evb + (CB) + sr * 128 + v0 + sc0);                         \
  rUT0 = *(const int4*)(uT + (CB) + (size_t)tk * 64 + sc0);                       \
  rUT1 = *(const int4*)(uT + (CB) + (size_t)(tk + 64) * 64 + sc0);                \
  rIa = *(const int4*)(intra + (IB) + sr * 64 + sc0);                             \
  rWlN = ld4(wlast + ((size_t)bh * 64 + (NN)) * 128 + wloff);

#define STAGE_WRITE()                                                             \
  stsv16B(ewS, swzA(sr, sk0 * 2), rEw0);                                          \
  stsv16B(ewS, swzA(sr, sk0 * 2 + 16), rEw1);                                     \
  stsv16B(qtS, swzA(sr, sk0 * 2), rQt0);                                          \
  stsv16B(qtS, swzA(sr, sk0 * 2 + 16), rQt1);                                     \
  stsv16B(evS, swzB(sr, sc0 * 2), rEv);                                           \
  stsv16B(iaS, swzB(sr, sc0 * 2), rIa);                                           \
  stsv16B(uTS, swzB(tk, sc0 * 2), rUT0);                                          \
  stsv16B(uTS, swzB(tk + 64, sc0 * 2), rUT1);

  {
    const size_t cb0 = (size_t)bh * 64 * 8192;
    const size_t ib0 = (size_t)bh * 64 * 4096;
    STAGE_LOAD(cb0, ib0, 0);
    STAGE_WRITE();
    rWlC = rWlN;
  }
  __syncthreads();

  const int m = wave & 3, ntb = (wave >> 2) * 2;
  const int arow = 16 * m + l15;
  const int krow = 16 * wave + l15;

  for (int n = 0; n < NCc; ++n) {
    const size_t cb = ((size_t)bh * 64 + n) * 8192;
    const size_t ib = ((size_t)bh * 64 + n) * 4096;
    // ---- Phase A: prefetch n+1; delta = ev - ew@S -> dBT ----
    if (n < 63) { STAGE_LOAD(cb + 8192, ib + 4096, n + 1); }
    bf16x8 aEw[4];
#pragma unroll
    for (int ks = 0; ks < 4; ++ks) aEw[ks] = ldsv8(ewS, swzA(arow, 16 * l4 + 64 * ks));
#pragma unroll
    for (int i = 0; i < 2; ++i) {
      int vl = 16 * (ntb + i) + l15;
      f32x4 p = {};
#pragma unroll
      for (int ks = 0; ks < 4; ++ks)
        p = __builtin_amdgcn_mfma_f32_16x16x32_bf16(aEw[ks], ldsv8(sBT, swzA(vl, 16 * l4 + 64 * ks)), p, 0, 0, 0);
      float d[4];
#pragma unroll
      for (int r = 0; r < 4; ++r) {
        int c = 16 * m + 4 * l4 + r;
        d[r] = bf2f(lds16(evS, swzB(c, 2 * vl))) - p[r];
      }
      uint2 pk;
      pk.x = (unsigned)f2bf(d[0]) | ((unsigned)f2bf(d[1]) << 16);
      pk.y = (unsigned)f2bf(d[2]) | ((unsigned)f2bf(d[3]) << 16);
      stsv8B(dBT, swzB(vl, (16 * m + 4 * l4) * 2), pk);
    }
    __syncthreads();
    // ---- Phase B1: o = qt@S + ia@delta; S = wl*(S + uT@delta) ----
    bf16x8 aQt[4], aIa[2], aU[2];
#pragma unroll
    for (int ks = 0; ks < 4; ++ks) aQt[ks] = ldsv8(qtS, swzA(arow, 16 * l4 + 64 * ks));
#pragma unroll
    for (int ks = 0; ks < 2; ++ks) aIa[ks] = ldsv8(iaS, swzB(arow, 16 * l4 + 64 * ks));
#pragma unroll
    for (int ks = 0; ks < 2; ++ks) aU[ks] = ldsv8(uTS, swzB(krow, 16 * l4 + 64 * ks));
#pragma unroll
    for (int i = 0; i < 2; ++i) {
      int vl = 16 * (ntb + i) + l15;
      f32x4 o = {};
#pragma unroll
      for (int ks = 0; ks < 4; ++ks)
        o = __builtin_amdgcn_mfma_f32_16x16x32_bf16(aQt[ks], ldsv8(sBT, swzA(vl, 16 * l4 + 64 * ks)), o, 0, 0, 0);
#pragma unroll
      for (int ks = 0; ks < 2; ++ks)
        o = __builtin_amdgcn_mfma_f32_16x16x32_bf16(aIa[ks], ldsv8(dBT, swzB(vl, 16 * l4 + 64 * ks)), o, 0, 0, 0);
#pragma unroll
      for (int r = 0; r < 4; ++r) {
        int c = 16 * m + 4 * l4 + r;
        int t = n * 64 + c;
        attn_o[((size_t)(b * Tc + t) * Hc + h) * Kc + v0 + vl] = f2bf(o[r]);
      }
    }
    float wlv[4] = {rWlC.x, rWlC.y, rWlC.z, rWlC.w};
#pragma unroll
    for (int nt4 = 0; nt4 < 4; ++nt4) {
      int vl = 16 * nt4 + l15;
      f32x4 U = {};
#pragma unroll
      for (int ks = 0; ks < 2; ++ks)
        U = __builtin_amdgcn_mfma_f32_16x16x32_bf16(aU[ks], ldsv8(dBT, swzB(vl, 16 * l4 + 64 * ks)), U, 0, 0, 0);
#pragma unroll
      for (int r = 0; r < 4; ++r) S[nt4][r] = wlv[r] * (S[nt4][r] + U[r]);
    }
    __syncthreads();
    // ---- Phase B2: S -> sBT, staging writes, snapshot ----
#pragma unroll
    for (int nt4 = 0; nt4 < 4; ++nt4) {
      int vl = 16 * nt4 + l15;
      uint2 pk;
      pk.x = (unsigned)f2bf(S[nt4][0]) | ((unsigned)f2bf(S[nt4][1]) << 16);
      pk.y = (unsigned)f2bf(S[nt4][2]) | ((unsigned)f2bf(S[nt4][3]) << 16);
      stsv8B(sBT, swzA(vl, (16 * wave + 4 * l4) * 2), pk);
    }
    if (n < 63) { STAGE_WRITE(); rWlC = rWlN; }
    if ((n & 3) == 3) {
      int ns = n >> 2;
      size_t sb = (size_t)((ns * Bc + b) * Hc + h) * 16384;
#pragma unroll
      for (int nt4 = 0; nt4 < 4; ++nt4)
#pragma unroll
        for (int r = 0; r < 4; ++r) {
          int k = 16 * wave + 4 * l4 + r;
          snapb[sb + (size_t)k * 128 + v0 + 16 * nt4 + l15] = f2bf(S[nt4][r]);
        }
    }
    __syncthreads();
  }
#undef STAGE_LOAD
#undef STAGE_WRITE
}

// ---------------- snapshot helpers ----------------
__global__ void sdw_mul_bf16(const float* __restrict__ snap_down, const float* __restrict__ w,
                             unsigned short* __restrict__ sdwb) {
  int i = (blockIdx.x * 256 + threadIdx.x) * 4;
  float4 v = ld4(snap_down + i);
  int k = i & 16383;
  float4 ww = ld4(w + k);
  ushort4 o;
  o.x = f2bf(v.x * ww.x); o.y = f2bf(v.y * ww.y); o.z = f2bf(v.z * ww.z); o.w = f2bf(v.w * ww.w);
  *reinterpret_cast<ushort4*>(sdwb + i) = o;
}

__global__ __launch_bounds__(256) void snap_scale_kernel(const unsigned short* __restrict__ snapb,
                                                         float* __restrict__ scale) {
  int r = blockIdx.x;
  const unsigned short* row = snapb + (size_t)r * 16384;
  float s = 0.f;
  for (int ii = threadIdx.x * 4; ii < 16384; ii += 1024) {
    float4 x = ld4(row + ii);
    s += x.x * x.x + x.y * x.y + x.z * x.z + x.w * x.w;
  }
#pragma unroll
  for (int off = 32; off > 0; off >>= 1) s += __shfl_down(s, off, 64);
  __shared__ float red[4];
  if ((threadIdx.x & 63) == 0) red[threadIdx.x >> 6] = s;
  __syncthreads();
  if (threadIdx.x == 0) {
    float tot = red[0] + red[1] + red[2] + red[3];
    scale[r] = rsqrtf(tot * (1.f / 16384.f) + 1e-6f);
  }
}

__global__ void snap_reduce_scatter(const float* __restrict__ part,
                                    const float* __restrict__ scale,
                                    float* __restrict__ outp) {
  int idx = blockIdx.x * 256 + threadIdx.x;
  int l = idx & 127;
  int hh = (idx >> 7) & 15;
  int ns = (idx >> 11) & 15;
  int bb = idx >> 15;
  int r = (ns * Bc + bb) * Hc + hh;
  float s = 0.f;
#pragma unroll
  for (int z = 0; z < 16; ++z) s += part[(size_t)z * 65536 + r * 128 + l];
  outp[idx] = s * scale[r];
}

// ---------------- final rmsnorm * sigmoid(gate): wave-per-row ----------
__global__ __launch_bounds__(256) void out_norm_gate(unsigned short* __restrict__ attn_io,
                                                     const unsigned short* __restrict__ gate_raw,
                                                     const float* __restrict__ bgb,
                                                     const float* __restrict__ o_norm_w) {
  const int wave = threadIdx.x >> 6, lane = threadIdx.x & 63;
  const int blk = blockIdx.x * 4 + wave;  // (b*T + t)*H + h
  const int h = blk & 15;
  const size_t row = (size_t)(blk >> 4);
  const size_t base = (size_t)blk * Kc;
  ushort2 xv = *reinterpret_cast<const ushort2*>(attn_io + base + 2 * lane);
  float x0 = bf2f(xv.x), x1 = bf2f(xv.y);
  float ss = x0 * x0 + x1 * x1;
#pragma unroll
  for (int off = 32; off > 0; off >>= 1) ss += __shfl_xor(ss, off, 64);
  float inv = rsqrtf(ss * (1.f / 128.f) + 1e-6f);
  const int p0 = h * Kc + 2 * lane;
  ushort2 gv = *reinterpret_cast<const ushort2*>(gate_raw + row * Pc + p0);
  float g0 = bf2f(gv.x) + bgb[p0];
  float g1 = bf2f(gv.y) + bgb[p0 + 1];
  float o0 = x0 * inv * o_norm_w[2 * lane] / (1.f + expf(-g0));
  float o1 = x1 * inv * o_norm_w[2 * lane + 1] / (1.f + expf(-g1));
  ushort2 ov; ov.x = f2bf(o0); ov.y = f2bf(o1);
  *reinterpret_cast<ushort2*>(attn_io + base + 2 * lane) = ov;
}

// ---------------- launch ----------------
extern "C" void kernel_launch(void* const* d_in, const int* in_sizes, int n_in,
                              void* d_out, int out_size, void* d_ws, size_t ws_size,
                              hipStream_t stream) {
  (void)in_sizes; (void)n_in;
  const float* x        = (const float*)d_in[0];
  const float* Wq       = (const float*)d_in[1];
  const float* Wk       = (const float*)d_in[2];
  const float* Wv       = (const float*)d_in[3];
  const float* conv_q   = (const float*)d_in[4];
  const float* conv_k   = (const float*)d_in[5];
  const float* conv_v   = (const float*)d_in[6];
  const float* A_log    = (const float*)d_in[7];
  const float* dt_bias  = (const float*)d_in[8];
  const float* Wfa      = (const float*)d_in[9];
  const float* Wfb      = (const float*)d_in[10];
  const float* Wb       = (const float*)d_in[11];
  const float* Wga      = (const float*)d_in[12];
  const float* Wgb      = (const float*)d_in[13];
  const float* bgb      = (const float*)d_in[14];
  const float* o_norm_w = (const float*)d_in[15];
  const float* Wo       = (const float*)d_in[16];
  const float* snap_nw  = (const float*)d_in[17];
  const float* snap_down= (const float*)d_in[18];

  const size_t MP2 = (size_t)Mc * Pc * 2;
  const size_t NEED = 6 * MP2
                    + 2 * (size_t)Mc * Kc * 4
                    + (size_t)Mc * Hc * 4
                    + (size_t)Bc * Hc * NCc * Kc * 4;
  if (ws_size < NEED + 4096) {
    hipMemsetAsync(d_out, 0, (size_t)out_size * 4, stream);
    return;
  }
  char* w = (char*)d_ws;
  auto alloc = [&](size_t bytes) {
    char* r = w;
    w += (bytes + 255) & ~(size_t)255;
    return r;
  };
  unsigned short* q_lin = (unsigned short*)alloc(MP2);
  unsigned short* k_lin = (unsigned short*)alloc(MP2);
  unsigned short* v_lin = (unsigned short*)alloc(MP2);
  unsigned short* g_raw = (unsigned short*)alloc(MP2);
  unsigned short* evb   = (unsigned short*)alloc(MP2);
  unsigned short* ewb   = (unsigned short*)alloc(MP2);
  float* fa    = (float*)alloc((size_t)Mc * Kc * 4);
  float* ga    = (float*)alloc((size_t)Mc * Kc * 4);
  float* betab = (float*)alloc((size_t)Mc * Hc * 4);
  float* wlast = (float*)alloc((size_t)Bc * Hc * NCc * Kc * 4);

  unsigned short* qt = (unsigned short*)d_out;
  unsigned short* u_ = (unsigned short*)((char*)d_out + MP2);

  unsigned short* xb    = evb;
  unsigned short* Wqb   = ewb;
  unsigned short* Wkb   = ewb + 4194304;
  unsigned short* Wvb   = ewb + 8388608;
  unsigned short* Wfab  = ewb + 12582912;
  unsigned short* Wgab  = ewb + 12845056;
  unsigned short* Wfbb  = ewb + 13107200;
  unsigned short* fab   = (unsigned short*)fa;
  unsigned short* gab   = (unsigned short*)ga;

  unsigned short* intra = q_lin;
  unsigned short* Wob   = q_lin + 8388608;
  unsigned short* Wgbb  = q_lin + 12582912;
  unsigned short* attn  = k_lin;
  unsigned short* gate_raw = g_raw;
  unsigned short* snapb = v_lin;
  unsigned short* sdwb  = v_lin + (size_t)512 * 16384;
  float* partial   = (float*)ewb;
  float* snapscale = (float*)(ewb + 4400000);

  float* y = (float*)d_out;
  float* snaps_out = (float*)d_out + (size_t)Bc * Tc * Dc;

  // 0) casts
  cast_f32_bf16<<<16384, 256, 0, stream>>>(x, xb, Mc * Dc);
  cast_f32_bf16<<<4096, 256, 0, stream>>>(Wq, Wqb, Pc * Dc);
  cast_f32_bf16<<<4096, 256, 0, stream>>>(Wk, Wkb, Pc * Dc);
  cast_f32_bf16<<<4096, 256, 0, stream>>>(Wv, Wvb, Pc * Dc);
  cast_f32_bf16<<<256, 256, 0, stream>>>(Wfa, Wfab, Kc * Dc);
  cast_f32_bf16<<<256, 256, 0, stream>>>(Wga, Wgab, Kc * Dc);
  cast_f32_bf16<<<256, 256, 0, stream>>>(Wfb, Wfbb, Pc * Kc);

  // 1) input GEMMs (bf16 MFMA)
  gemm_nt_mfma<unsigned short><<<dim3(64, 16), 256, 0, stream>>>(xb, Wqb, q_lin, Pc, Dc);
  gemm_nt_mfma<unsigned short><<<dim3(64, 16), 256, 0, stream>>>(xb, Wkb, k_lin, Pc, Dc);
  gemm_nt_mfma<unsigned short><<<dim3(64, 16), 256, 0, stream>>>(xb, Wvb, v_lin, Pc, Dc);
  gemm_nt_mfma<unsigned short><<<dim3(64, 1), 256, 0, stream>>>(xb, Wfab, fab, Kc, Dc);
  gemm_nt_mfma<unsigned short><<<dim3(64, 1), 256, 0, stream>>>(xb, Wgab, gab, Kc, Dc);
  gemm_nt<float, float, float><<<dim3(64, 1), 256, 0, stream>>>(x, Wb, betab, Hc, Dc);
  gemm_nt_mfma<unsigned short><<<dim3(64, 16), 256, 0, stream>>>(fab, Wfbb, g_raw, Pc, Kc);

  // 2) chunk prep (wave-per-chunk, no barriers)
  chunk_prep<<<Bc * Hc * NCc / 4, 256, 0, stream>>>(q_lin, k_lin, v_lin, g_raw, betab, conv_q,
                                                    conv_k, conv_v, A_log, dt_bias, qt, u_, evb,
                                                    ewb, wlast);

  // 3) late casts into q_lin's dead tail
  cast_f32_bf16<<<4096, 256, 0, stream>>>(Wo, Wob, Dc * Pc);
  cast_f32_bf16<<<256, 256, 0, stream>>>(Wgb, Wgbb, Pc * Kc);

  // chunk solve (also transposes u -> uT in place)
  chunk_solve_mfma<<<Bc * Hc * NCc, 256, 0, stream>>>(qt, u_, evb, ewb, intra);

  // 4) gate projection
  gemm_nt_mfma<unsigned short><<<dim3(64, 16), 256, 0, stream>>>(gab, Wgbb, gate_raw, Pc, Kc);

  // 5) MFMA scan, v-split x2 (u_ holds uT)
  scan_mfma<<<Bc * Hc * 2, 512, 0, stream>>>(qt, u_, evb, ewb, intra, wlast, attn, snapb);

  // 6) snapshots
  sdw_mul_bf16<<<2048, 256, 0, stream>>>(snap_down, snap_nw, sdwb);
  snap_scale_kernel<<<512, 256, 0, stream>>>(snapb, snapscale);
  gemm_nt_mfma_sk<<<dim3(4, 1, 16), 256, 0, stream>>>(snapb, sdwb, partial, 128, 16384, 1024, 512);
  snap_reduce_scatter<<<256, 256, 0, stream>>>(partial, snapscale, snaps_out);

  // 7) output norm*gate + final projection
  out_norm_gate<<<Mc * Hc / 4, 256, 0, stream>>>(attn, gate_raw, bgb, o_norm_w);
  gemm_nt_mfma<float><<<dim3(64, 16), 256, 0, stream>>>(attn, Wob, y, Dc, Pc);
}

// Round 9
// 1201.087 us; speedup vs baseline: 6.6582x; 1.0483x over previous
//
#include <hip/hip_runtime.h>

// ---------------- problem constants ----------------
constexpr int Bc   = 2;
constexpr int Tc   = 4096;
constexpr int Dc   = 2048;
constexpr int Hc   = 16;
constexpr int Kc   = 128;
constexpr int Pc   = Hc * Kc;     // 2048
constexpr int Cc   = 64;          // chunk size
constexpr int NCc  = Tc / Cc;     // 64 chunks
constexpr int Mc   = Bc * Tc;     // 8192 rows
constexpr int LATc = 128;

// ---------------- helpers ----------------
__device__ __forceinline__ float bf2f(unsigned short u) {
  unsigned int x = ((unsigned int)u) << 16;
  return __builtin_bit_cast(float, x);
}
__device__ __forceinline__ unsigned short f2bf(float f) {
  unsigned int x = __builtin_bit_cast(unsigned int, f);
  x += 0x7fffu + ((x >> 16) & 1u);
  return (unsigned short)(x >> 16);
}
__device__ __forceinline__ float4 ld4(const float* p) {
  return *reinterpret_cast<const float4*>(p);
}
__device__ __forceinline__ float4 ld4(const unsigned short* p) {
  ushort4 u = *reinterpret_cast<const ushort4*>(p);
  return make_float4(bf2f(u.x), bf2f(u.y), bf2f(u.z), bf2f(u.w));
}
__device__ __forceinline__ void st1(float* p, float v) { *p = v; }
__device__ __forceinline__ void st1(unsigned short* p, float v) { *p = f2bf(v); }

// fast transcendentals (native v_exp_f32 / v_log_f32 / v_rcp_f32)
__device__ __forceinline__ float fsig(float x) {
  return __fdividef(1.f, 1.f + __expf(-x));
}
__device__ __forceinline__ float fsoftplus(float g) {
  return (g > 20.f) ? g : __logf(1.f + __expf(g));
}

typedef __attribute__((ext_vector_type(8))) short bf16x8;
typedef __attribute__((ext_vector_type(4))) float f32x4;

// LDS swizzles: rows of stride 256B (swzA) and 128B (swzB); byte ^= ((row&7)<<4)
__device__ __forceinline__ int swzA(int row, int kbyte) { return row * 256 + (kbyte ^ ((row & 7) << 4)); }
__device__ __forceinline__ int swzB(int row, int kbyte) { return row * 128 + (kbyte ^ ((row & 7) << 4)); }
__device__ __forceinline__ bf16x8 ldsv8(const unsigned short* base, int byteoff) {
  return *reinterpret_cast<const bf16x8*>(reinterpret_cast<const char*>(base) + byteoff);
}
__device__ __forceinline__ void stsv16B(unsigned short* base, int byteoff, int4 v) {
  *reinterpret_cast<int4*>(reinterpret_cast<char*>(base) + byteoff) = v;
}
__device__ __forceinline__ void stsv8B(unsigned short* base, int byteoff, uint2 v) {
  *reinterpret_cast<uint2*>(reinterpret_cast<char*>(base) + byteoff) = v;
}
__device__ __forceinline__ unsigned short lds16(const unsigned short* base, int byteoff) {
  return *reinterpret_cast<const unsigned short*>(reinterpret_cast<const char*>(base) + byteoff);
}

// bijective XCD-aware block swizzle (T1); identity unless nwg%8==0 && nwg>=16
__device__ __forceinline__ int xcd_swz(int id, int nwg) {
  if ((nwg & 7) != 0 || nwg < 16) return id;
  return (id & 7) * (nwg >> 3) + (id >> 3);
}

// ---------------- f32 -> bf16 cast ----------------
__global__ void cast_f32_bf16(const float* __restrict__ in, unsigned short* __restrict__ out,
                              int n) {
  int i = (blockIdx.x * 256 + threadIdx.x) * 4;
  if (i < n) {
    float4 v = ld4(in + i);
    ushort4 o;
    o.x = f2bf(v.x); o.y = f2bf(v.y); o.z = f2bf(v.z); o.w = f2bf(v.w);
    *reinterpret_cast<ushort4*>(out + i) = o;
  }
}

// ---------------- bf16 MFMA NT GEMM (128x128 tile, m97 structure, XCD swizzle) ------
__device__ __forceinline__ void gload_lds16(const unsigned short* g, unsigned short* l) {
  __builtin_amdgcn_global_load_lds(
      (const __attribute__((address_space(1))) void*)g,
      (__attribute__((address_space(3))) void*)l, 16, 0, 0);
}

template <typename OT>
__global__ __launch_bounds__(256) void gemm_nt_mfma(const unsigned short* __restrict__ A,
                                                    const unsigned short* __restrict__ Bm,
                                                    OT* __restrict__ Out,
                                                    int Ndim, int Kd) {
  __shared__ __align__(16) unsigned short As[128 * 32];
  __shared__ __align__(16) unsigned short Bs[128 * 32];
  int id = blockIdx.y * gridDim.x + blockIdx.x;
  id = xcd_swz(id, gridDim.x * gridDim.y);
  const int m0 = (id % gridDim.x) * 128;
  const int n0 = (id / gridDim.x) * 128;
  const int tid = threadIdx.x;
  const int wave = tid >> 6;
  const int lane = tid & 63;
  const int wr = wave >> 1, wc = wave & 1;
  const int l15 = lane & 15, l4 = lane >> 4;
  f32x4 acc[4][4] = {};

  for (int k0 = 0; k0 < Kd; k0 += 32) {
#pragma unroll
    for (int i = 0; i < 2; ++i) {
      int e = (wave * 2 + i) * 512 + lane * 8;
      int r = e >> 5, c = e & 31;
      gload_lds16(&A[(size_t)(m0 + r) * Kd + k0 + c], &As[(wave * 2 + i) * 512]);
      gload_lds16(&Bm[(size_t)(n0 + r) * Kd + k0 + c], &Bs[(wave * 2 + i) * 512]);
    }
    __syncthreads();
    bf16x8 af[4], bfr[4];
#pragma unroll
    for (int m = 0; m < 4; ++m)
      af[m] = *reinterpret_cast<const bf16x8*>(&As[(wr * 64 + m * 16 + l15) * 32 + l4 * 8]);
#pragma unroll
    for (int n = 0; n < 4; ++n)
      bfr[n] = *reinterpret_cast<const bf16x8*>(&Bs[(wc * 64 + n * 16 + l15) * 32 + l4 * 8]);
#pragma unroll
    for (int m = 0; m < 4; ++m)
#pragma unroll
      for (int n = 0; n < 4; ++n)
        acc[m][n] = __builtin_amdgcn_mfma_f32_16x16x32_bf16(af[m], bfr[n], acc[m][n], 0, 0, 0);
    __syncthreads();
  }
#pragma unroll
  for (int m = 0; m < 4; ++m)
#pragma unroll
    for (int n = 0; n < 4; ++n)
#pragma unroll
      for (int r = 0; r < 4; ++r) {
        int row = m0 + wr * 64 + m * 16 + l4 * 4 + r;
        int col = n0 + wc * 64 + n * 16 + l15;
        st1(&Out[(size_t)row * Ndim + col], acc[m][n][r]);
      }
}

// ---- splitK variant ----
__global__ __launch_bounds__(256) void gemm_nt_mfma_sk(const unsigned short* __restrict__ A,
                                                       const unsigned short* __restrict__ Bm,
                                                       float* __restrict__ Part,
                                                       int Ndim, int Kd, int kslice, int Mtot) {
  __shared__ __align__(16) unsigned short As[128 * 32];
  __shared__ __align__(16) unsigned short Bs[128 * 32];
  const int m0 = blockIdx.x * 128;
  const int n0 = blockIdx.y * 128;
  const int kz = blockIdx.z * kslice;
  const int tid = threadIdx.x;
  const int wave = tid >> 6;
  const int lane = tid & 63;
  const int wr = wave >> 1, wc = wave & 1;
  const int l15 = lane & 15, l4 = lane >> 4;
  f32x4 acc[4][4] = {};

  for (int k0 = kz; k0 < kz + kslice; k0 += 32) {
#pragma unroll
    for (int i = 0; i < 2; ++i) {
      int e = (wave * 2 + i) * 512 + lane * 8;
      int r = e >> 5, c = e & 31;
      gload_lds16(&A[(size_t)(m0 + r) * Kd + k0 + c], &As[(wave * 2 + i) * 512]);
      gload_lds16(&Bm[(size_t)(n0 + r) * Kd + k0 + c], &Bs[(wave * 2 + i) * 512]);
    }
    __syncthreads();
    bf16x8 af[4], bfr[4];
#pragma unroll
    for (int m = 0; m < 4; ++m)
      af[m] = *reinterpret_cast<const bf16x8*>(&As[(wr * 64 + m * 16 + l15) * 32 + l4 * 8]);
#pragma unroll
    for (int n = 0; n < 4; ++n)
      bfr[n] = *reinterpret_cast<const bf16x8*>(&Bs[(wc * 64 + n * 16 + l15) * 32 + l4 * 8]);
#pragma unroll
    for (int m = 0; m < 4; ++m)
#pragma unroll
      for (int n = 0; n < 4; ++n)
        acc[m][n] = __builtin_amdgcn_mfma_f32_16x16x32_bf16(af[m], bfr[n], acc[m][n], 0, 0, 0);
    __syncthreads();
  }
  float* out = Part + (size_t)blockIdx.z * Mtot * Ndim;
#pragma unroll
  for (int m = 0; m < 4; ++m)
#pragma unroll
    for (int n = 0; n < 4; ++n)
#pragma unroll
      for (int r = 0; r < 4; ++r) {
        int row = m0 + wr * 64 + m * 16 + l4 * 4 + r;
        int col = n0 + wc * 64 + n * 16 + l15;
        out[(size_t)row * Ndim + col] = acc[m][n][r];
      }
}

// ---------------- generic fp32 NT GEMM (kept only for N=16 beta) --------
template <typename AT, typename BT, typename OT>
__global__ __launch_bounds__(256) void gemm_nt(const AT* __restrict__ A,
                                               const BT* __restrict__ Bm,
                                               OT* __restrict__ Out,
                                               int Ndim, int Kd) {
  __shared__ float As[32][132];
  __shared__ float Bs[32][68];
  const int m0 = blockIdx.x * 128;
  const int n0 = blockIdx.y * 64;
  const int tid = threadIdx.x;
  const int tx = tid & 15, ty = tid >> 4;
  float acc[8][4];
#pragma unroll
  for (int i = 0; i < 8; ++i)
#pragma unroll
    for (int j = 0; j < 4; ++j) acc[i][j] = 0.f;

  for (int k0 = 0; k0 < Kd; k0 += 32) {
#pragma unroll
    for (int p = 0; p < 4; ++p) {
      int e = tid + p * 256;
      int r = e >> 3;
      int c = (e & 7) << 2;
      float4 v = ld4(A + (size_t)(m0 + r) * Kd + k0 + c);
      As[c + 0][r] = v.x; As[c + 1][r] = v.y; As[c + 2][r] = v.z; As[c + 3][r] = v.w;
    }
#pragma unroll
    for (int p = 0; p < 2; ++p) {
      int e = tid + p * 256;
      int r = e >> 3;
      int c = (e & 7) << 2;
      float4 v = make_float4(0.f, 0.f, 0.f, 0.f);
      if (n0 + r < Ndim) v = ld4(Bm + (size_t)(n0 + r) * Kd + k0 + c);
      Bs[c + 0][r] = v.x; Bs[c + 1][r] = v.y; Bs[c + 2][r] = v.z; Bs[c + 3][r] = v.w;
    }
    __syncthreads();
#pragma unroll
    for (int kk = 0; kk < 32; ++kk) {
      const float4* ar = reinterpret_cast<const float4*>(&As[kk][0]);
      const float4* br = reinterpret_cast<const float4*>(&Bs[kk][0]);
      float4 b4 = br[tx];
      float4 a0 = ar[ty * 2], a1 = ar[ty * 2 + 1];
      float av[8] = {a0.x, a0.y, a0.z, a0.w, a1.x, a1.y, a1.z, a1.w};
      float bv4[4] = {b4.x, b4.y, b4.z, b4.w};
#pragma unroll
      for (int i = 0; i < 8; ++i)
#pragma unroll
        for (int j = 0; j < 4; ++j) acc[i][j] = fmaf(av[i], bv4[j], acc[i][j]);
    }
    __syncthreads();
  }
#pragma unroll
  for (int i = 0; i < 8; ++i) {
    int m = m0 + ty * 8 + i;
#pragma unroll
    for (int j = 0; j < 4; ++j) {
      int n = n0 + tx * 4 + j;
      if (n < Ndim) st1(Out + (size_t)m * Ndim + n, acc[i][j]);
    }
  }
}

// ---------------- chunk prep: one WAVE per chunk, fast transcendentals ----------------
// grid: Bc*Hc*NCc/4 = 512 blocks x 256 threads (4 waves = 4 chunks)
__global__ __launch_bounds__(256) void chunk_prep(
    const unsigned short* __restrict__ q_lin, const unsigned short* __restrict__ k_lin,
    const unsigned short* __restrict__ v_lin, const unsigned short* __restrict__ g_raw,
    const float* __restrict__ beta_lin, const float* __restrict__ conv_q,
    const float* __restrict__ conv_k, const float* __restrict__ conv_v,
    const float* __restrict__ A_log, const float* __restrict__ dt_bias,
    unsigned short* __restrict__ qt, unsigned short* __restrict__ u_,
    unsigned short* __restrict__ bv, unsigned short* __restrict__ bw,
    float* __restrict__ wlast) {
  const int wave = threadIdx.x >> 6, lane = threadIdx.x & 63;
  const int cid = blockIdx.x * 4 + wave;  // (b*H+h)*NC + n
  const int n = cid & 63;
  const int h = (cid >> 6) & 15;
  const int b = cid >> 10;
  const int k0 = 2 * lane;
  const int p = h * Kc + k0;
  float cq[2][4], ck[2][4], cv[2][4];
#pragma unroll
  for (int s = 0; s < 2; ++s)
#pragma unroll
    for (int j = 0; j < 4; ++j) {
      cq[s][j] = conv_q[(p + s) * 4 + j];
      ck[s][j] = conv_k[(p + s) * 4 + j];
      cv[s][j] = conv_v[(p + s) * 4 + j];
    }
  const float aneg = -__expf(A_log[h]);
  const float db0 = dt_bias[p], db1 = dt_bias[p + 1];
  float cum0 = 0.f, cum1 = 0.f;
  const int t0 = n * Cc;
  float wq[2][3] = {}, wk[2][3] = {}, wv[2][3] = {};
#pragma unroll
  for (int d = 0; d < 3; ++d) {
    int ts = t0 - 3 + d;
    if (ts >= 0) {
      size_t o = ((size_t)(b * Tc + ts)) * Pc + p;
      ushort2 q2 = *(const ushort2*)(q_lin + o);
      ushort2 k2 = *(const ushort2*)(k_lin + o);
      ushort2 v2 = *(const ushort2*)(v_lin + o);
      wq[0][d] = bf2f(q2.x); wq[1][d] = bf2f(q2.y);
      wk[0][d] = bf2f(k2.x); wk[1][d] = bf2f(k2.y);
      wv[0][d] = bf2f(v2.x); wv[1][d] = bf2f(v2.y);
    }
  }
  for (int c = 0; c < Cc; ++c) {
    const int t = t0 + c;
    size_t off = ((size_t)(b * Tc + t)) * Pc + p;
    ushort2 q2 = *(const ushort2*)(q_lin + off);
    ushort2 k2 = *(const ushort2*)(k_lin + off);
    ushort2 v2 = *(const ushort2*)(v_lin + off);
    ushort2 g2 = *(const ushort2*)(g_raw + off);
    float nq[2] = {bf2f(q2.x), bf2f(q2.y)};
    float nk[2] = {bf2f(k2.x), bf2f(k2.y)};
    float nv[2] = {bf2f(v2.x), bf2f(v2.y)};
    float qv[2], kv[2], vv[2];
#pragma unroll
    for (int s = 0; s < 2; ++s) {
      qv[s] = cq[s][0] * wq[s][0] + cq[s][1] * wq[s][1] + cq[s][2] * wq[s][2] + cq[s][3] * nq[s];
      kv[s] = ck[s][0] * wk[s][0] + ck[s][1] * wk[s][1] + ck[s][2] * wk[s][2] + ck[s][3] * nk[s];
      vv[s] = cv[s][0] * wv[s][0] + cv[s][1] * wv[s][1] + cv[s][2] * wv[s][2] + cv[s][3] * nv[s];
      wq[s][0] = wq[s][1]; wq[s][1] = wq[s][2]; wq[s][2] = nq[s];
      wk[s][0] = wk[s][1]; wk[s][1] = wk[s][2]; wk[s][2] = nk[s];
      wv[s][0] = wv[s][1]; wv[s][1] = wv[s][2]; wv[s][2] = nv[s];
      qv[s] = qv[s] * fsig(qv[s]);  // silu
      kv[s] = kv[s] * fsig(kv[s]);
      vv[s] = vv[s] * fsig(vv[s]);
    }
    float a = qv[0] * qv[0] + qv[1] * qv[1];
    float bb = kv[0] * kv[0] + kv[1] * kv[1];
#pragma unroll
    for (int off2 = 32; off2 > 0; off2 >>= 1) {
      a += __shfl_xor(a, off2, 64);
      bb += __shfl_xor(bb, off2, 64);
    }
    float rq = rsqrtf(a + 1e-12f) * 0.08838834764831845f;  // * K^-0.5
    float rk = rsqrtf(bb + 1e-12f);
    float g0 = bf2f(g2.x) + db0, g1 = bf2f(g2.y) + db1;
    cum0 += aneg * fsoftplus(g0);
    cum1 += aneg * fsoftplus(g1);
    float cc0 = fmaxf(cum0, -15.f), cc1 = fmaxf(cum1, -15.f);
    float Wg0 = __expf(cc0), Wg1 = __expf(cc1);
    float Wi0 = __fdividef(1.f, Wg0), Wi1 = __fdividef(1.f, Wg1);
    float beta = fsig(beta_lin[((size_t)(b * Tc + t)) * Hc + h]);
    size_t idx = ((size_t)cid * Cc + c) * Kc + k0;
    ushort2 o1, o2, o3, o4;
    o1.x = f2bf(qv[0] * rq * Wg0); o1.y = f2bf(qv[1] * rq * Wg1);
    o2.x = f2bf(kv[0] * rk * Wi0); o2.y = f2bf(kv[1] * rk * Wi1);
    o3.x = f2bf(beta * kv[0] * rk * Wg0); o3.y = f2bf(beta * kv[1] * rk * Wg1);
    o4.x = f2bf(beta * vv[0]); o4.y = f2bf(beta * vv[1]);
    *(ushort2*)(qt + idx) = o1;
    *(ushort2*)(u_ + idx) = o2;
    *(ushort2*)(bw + idx) = o3;
    *(ushort2*)(bv + idx) = o4;
    if (c == Cc - 1) {
      wlast[(size_t)cid * Kc + k0] = Wg0;
      wlast[(size_t)cid * Kc + k0 + 1] = Wg1;
    }
  }
}

// ---------------- MFMA chunk solve + in-place u -> u^T transpose ----------------
__global__ __launch_bounds__(256) void chunk_solve_mfma(
    const unsigned short* __restrict__ qt, unsigned short* __restrict__ u_,
    unsigned short* __restrict__ evb,  // in: bv, out: ev
    unsigned short* __restrict__ ewb,  // in: bw, out: ew
    unsigned short* __restrict__ intra_out) {
  const int blk = blockIdx.x;
  const size_t base = (size_t)blk * (Cc * Kc);
  const size_t ibase = (size_t)blk * (Cc * Cc);
  const int tid = threadIdx.x, wave = tid >> 6, lane = tid & 63;
  const int l15 = lane & 15, l4 = lane >> 4;

  __shared__ __align__(16) char lds[65536];
  unsigned short* uS   = (unsigned short*)(lds);            // [64][128] swzA
  unsigned short* qtS  = (unsigned short*)(lds + 16384);    // [64][128] swzA
  unsigned short* bwS  = (unsigned short*)(lds + 32768);    // [64][128] swzA
  unsigned short* NLrm = (unsigned short*)(lds + 49152);    // [64][64] swzB
  unsigned short* NLT  = (unsigned short*)(lds + 57344);    // [64][64] swzB
  unsigned short* Trm  = (unsigned short*)(lds);            // over uS
  unsigned short* TT   = (unsigned short*)(lds + 8192);
  unsigned short* Prm  = (unsigned short*)(lds + 16384);    // over qtS
  unsigned short* PT   = (unsigned short*)(lds + 24576);
  unsigned short* bvT  = (unsigned short*)(lds + 32768);    // [128][64] swzB, over bwS
  unsigned short* bwT  = (unsigned short*)(lds + 49152);    // [128][64] swzB, over NL

#pragma unroll
  for (int i = 0; i < 4; ++i) {
    int cid = tid + i * 256;
    int r = cid >> 4, c8 = (cid & 15) * 8, cb2 = (cid & 15) * 16;
    int4 vu = *(const int4*)(u_ + base + (size_t)r * 128 + c8);
    int4 vb = *(const int4*)(ewb + base + (size_t)r * 128 + c8);
    int4 vq = *(const int4*)(qt + base + (size_t)r * 128 + c8);
    stsv16B(uS, swzA(r, cb2), vu);
    stsv16B(bwS, swzA(r, cb2), vb);
    stsv16B(qtS, swzA(r, cb2), vq);
  }
  __syncthreads();

  const int arow = 16 * wave + l15;
  bf16x8 aBw[4], aQt[4];
#pragma unroll
  for (int ks = 0; ks < 4; ++ks) {
    aBw[ks] = ldsv8(bwS, swzA(arow, 16 * l4 + 64 * ks));
    aQt[ks] = ldsv8(qtS, swzA(arow, 16 * l4 + 64 * ks));
  }
  f32x4 Lc[4], Ic[4];
#pragma unroll
  for (int nt = 0; nt < 4; ++nt) {
    f32x4 a = {}, bq = {};
#pragma unroll
    for (int ks = 0; ks < 4; ++ks) {
      bf16x8 bu = ldsv8(uS, swzA(16 * nt + l15, 16 * l4 + 64 * ks));
      a = __builtin_amdgcn_mfma_f32_16x16x32_bf16(aBw[ks], bu, a, 0, 0, 0);
      bq = __builtin_amdgcn_mfma_f32_16x16x32_bf16(aQt[ks], bu, bq, 0, 0, 0);
    }
    Lc[nt] = a; Ic[nt] = bq;
  }
#pragma unroll
  for (int nt = 0; nt < 4; ++nt)
#pragma unroll
    for (int r = 0; r < 4; ++r) {
      int row = 16 * wave + 4 * l4 + r, col = 16 * nt + l15;
      intra_out[ibase + (size_t)row * 64 + col] = f2bf((col <= row) ? Ic[nt][r] : 0.f);
    }

  // in-place u^T write-back
#pragma unroll
  for (int i = 0; i < 4; ++i) {
    int w2 = tid + i * 256;
    int k = w2 >> 3, cg = w2 & 7;
    unsigned short tmp[8];
#pragma unroll
    for (int j = 0; j < 8; ++j) {
      int c = cg + 8 * j;
      tmp[j] = lds16(uS, swzA(c, 2 * k));
    }
#pragma unroll
    for (int j = 0; j < 8; ++j)
      u_[base + (size_t)k * 64 + cg + 8 * j] = tmp[j];
  }
  __syncthreads();

  f32x4 Tf[4];
#pragma unroll
  for (int nt = 0; nt < 4; ++nt)
#pragma unroll
    for (int r = 0; r < 4; ++r) {
      int row = 16 * wave + 4 * l4 + r, col = 16 * nt + l15;
      float nl = (col < row) ? -Lc[nt][r] : 0.f;
      unsigned short nb = f2bf(nl);
      *reinterpret_cast<unsigned short*>((char*)NLrm + swzB(row, col * 2)) = nb;
      *reinterpret_cast<unsigned short*>((char*)NLT + swzB(col, row * 2)) = nb;
      float t0 = nl + ((row == col) ? 1.f : 0.f);
      Tf[nt][r] = t0;
      unsigned short tb = f2bf(t0);
      *reinterpret_cast<unsigned short*>((char*)Trm + swzB(row, col * 2)) = tb;
      *reinterpret_cast<unsigned short*>((char*)TT + swzB(col, row * 2)) = tb;
    }
  __syncthreads();

  bf16x8 aN[2];
#pragma unroll
  for (int ks = 0; ks < 2; ++ks) aN[ks] = ldsv8(NLrm, swzB(arow, 16 * l4 + 64 * ks));
  f32x4 Pf[4];
#pragma unroll
  for (int nt = 0; nt < 4; ++nt) {
    f32x4 acc = {};
#pragma unroll
    for (int ks = 0; ks < 2; ++ks)
      acc = __builtin_amdgcn_mfma_f32_16x16x32_bf16(aN[ks], ldsv8(NLT, swzB(16 * nt + l15, 16 * l4 + 64 * ks)), acc, 0, 0, 0);
    Pf[nt] = acc;
  }
  int4 rv[4], rw[4];
#pragma unroll
  for (int i = 0; i < 4; ++i) {
    int cid = tid + i * 256;
    int r = cid >> 4, c8 = (cid & 15) * 8;
    rv[i] = *(const int4*)(evb + base + (size_t)r * 128 + c8);
    rw[i] = *(const int4*)(ewb + base + (size_t)r * 128 + c8);
  }
#pragma unroll
  for (int nt = 0; nt < 4; ++nt)
#pragma unroll
    for (int r = 0; r < 4; ++r) {
      int row = 16 * wave + 4 * l4 + r, col = 16 * nt + l15;
      unsigned short pb = f2bf(Pf[nt][r]);
      *reinterpret_cast<unsigned short*>((char*)Prm + swzB(row, col * 2)) = pb;
      *reinterpret_cast<unsigned short*>((char*)PT + swzB(col, row * 2)) = pb;
    }
  __syncthreads();

  for (int it = 0; it < 5; ++it) {
    bf16x8 aP[2];
#pragma unroll
    for (int ks = 0; ks < 2; ++ks) aP[ks] = ldsv8(Prm, swzB(arow, 16 * l4 + 64 * ks));
    f32x4 Tn[4], Pn[4];
#pragma unroll
    for (int nt = 0; nt < 4; ++nt) {
      f32x4 acc = Tf[nt];
#pragma unroll
      for (int ks = 0; ks < 2; ++ks)
        acc = __builtin_amdgcn_mfma_f32_16x16x32_bf16(aP[ks], ldsv8(TT, swzB(16 * nt + l15, 16 * l4 + 64 * ks)), acc, 0, 0, 0);
      Tn[nt] = acc;
    }
    if (it < 4) {
#pragma unroll
      for (int nt = 0; nt < 4; ++nt) {
        f32x4 acc = {};
#pragma unroll
        for (int ks = 0; ks < 2; ++ks)
          acc = __builtin_amdgcn_mfma_f32_16x16x32_bf16(aP[ks], ldsv8(PT, swzB(16 * nt + l15, 16 * l4 + 64 * ks)), acc, 0, 0, 0);
        Pn[nt] = acc;
      }
    }
    __syncthreads();
#pragma unroll
    for (int nt = 0; nt < 4; ++nt)
#pragma unroll
      for (int r = 0; r < 4; ++r) {
        int row = 16 * wave + 4 * l4 + r, col = 16 * nt + l15;
        unsigned short tb = f2bf(Tn[nt][r]);
        *reinterpret_cast<unsigned short*>((char*)Trm + swzB(row, col * 2)) = tb;
        *reinterpret_cast<unsigned short*>((char*)TT + swzB(col, row * 2)) = tb;
        if (it < 4) {
          unsigned short pb = f2bf(Pn[nt][r]);
          *reinterpret_cast<unsigned short*>((char*)Prm + swzB(row, col * 2)) = pb;
          *reinterpret_cast<unsigned short*>((char*)PT + swzB(col, row * 2)) = pb;
        }
      }
#pragma unroll
    for (int nt = 0; nt < 4; ++nt) Tf[nt] = Tn[nt];
    __syncthreads();
  }

#pragma unroll
  for (int i = 0; i < 4; ++i) {
    int cid = tid + i * 256;
    int r = cid >> 4;
    const unsigned short* pv = reinterpret_cast<const unsigned short*>(&rv[i]);
    const unsigned short* pw = reinterpret_cast<const unsigned short*>(&rw[i]);
#pragma unroll
    for (int j = 0; j < 8; ++j) {
      int v = (cid & 15) * 8 + j;
      *reinterpret_cast<unsigned short*>((char*)bvT + swzB(v, r * 2)) = pv[j];
      *reinterpret_cast<unsigned short*>((char*)bwT + swzB(v, r * 2)) = pw[j];
    }
  }
  __syncthreads();

  bf16x8 aT[2];
#pragma unroll
  for (int ks = 0; ks < 2; ++ks) aT[ks] = ldsv8(Trm, swzB(arow, 16 * l4 + 64 * ks));
#pragma unroll
  for (int nt = 0; nt < 8; ++nt) {
    f32x4 e = {}, w2 = {};
#pragma unroll
    for (int ks = 0; ks < 2; ++ks) {
      e = __builtin_amdgcn_mfma_f32_16x16x32_bf16(aT[ks], ldsv8(bvT, swzB(16 * nt + l15, 16 * l4 + 64 * ks)), e, 0, 0, 0);
      w2 = __builtin_amdgcn_mfma_f32_16x16x32_bf16(aT[ks], ldsv8(bwT, swzB(16 * nt + l15, 16 * l4 + 64 * ks)), w2, 0, 0, 0);
    }
#pragma unroll
    for (int r = 0; r < 4; ++r) {
      int row = 16 * wave + 4 * l4 + r, col = 16 * nt + l15;
      evb[base + (size_t)row * 128 + col] = f2bf(e[r]);
      ewb[base + (size_t)row * 128 + col] = f2bf(w2[r]);
    }
  }
}

// ---------------- MFMA scan, v-split x2: grid = B*H*2, 8 waves --------------------
__global__ __launch_bounds__(512) void scan_mfma(
    const unsigned short* __restrict__ qt, const unsigned short* __restrict__ uT,
    const unsigned short* __restrict__ evb, const unsigned short* __restrict__ ewb,
    const unsigned short* __restrict__ intra, const float* __restrict__ wlast,
    unsigned short* __restrict__ attn_o, unsigned short* __restrict__ snapb) {
  const int blk = blockIdx.x;
  const int bh = blk >> 1, vh = blk & 1;
  const int b = bh >> 4, h = bh & 15;
  const int v0 = vh * 64;
  const int tid = threadIdx.x, wave = tid >> 6, lane = tid & 63;
  const int l15 = lane & 15, l4 = lane >> 4;
  __shared__ __align__(16) unsigned short ewS[8192];  // [64 c][128 k] swzA
  __shared__ __align__(16) unsigned short qtS[8192];  // [64 c][128 k] swzA
  __shared__ __align__(16) unsigned short uTS[8192];  // [128 k][64 c] swzB
  __shared__ __align__(16) unsigned short iaS[4096];  // [64 c][64 j]  swzB
  __shared__ __align__(16) unsigned short evS[4096];  // [64 c][64 v]  swzB (slice)
  __shared__ __align__(16) unsigned short sBT[8192];  // [64 v][128 k] swzA (S^T slice)
  __shared__ __align__(16) unsigned short dBT[4096];  // [64 v][64 c]  swzB (delta^T)

  f32x4 S[4] = {};
  {
    int4 z = {0, 0, 0, 0};
    stsv16B(sBT, tid * 32, z);
    stsv16B(sBT, tid * 32 + 16, z);
  }

  const int sr = tid >> 3;           // 0..63
  const int sk0 = (tid & 7) * 16;    // 128-wide col base
  const int sc0 = (tid & 7) * 8;     // 64-wide col base
  const int tk = tid >> 3;           // uT rows tk, tk+64
  const int wloff = 16 * wave + 4 * l4;
  int4 rEw0, rEw1, rQt0, rQt1, rEv, rUT0, rUT1, rIa;
  float4 rWlN, rWlC;

#define STAGE_LOAD(CB, IB, NN)                                                    \
  rEw0 = *(const int4*)(ewb + (CB) + sr * 128 + sk0);                             \
  rEw1 = *(const int4*)(ewb + (CB) + sr * 128 + sk0 + 8);                         \
  rQt0 = *(const int4*)(qt + (CB) + sr * 128 + sk0);                              \
  rQt1 = *(const int4*)(qt + (CB) + sr * 128 + sk0 + 8);                          \
  rEv = *(const int4*)(evb + (CB) + sr * 128 + v0 + sc0);                         \
  rUT0 = *(const int4*)(uT + (CB) + (size_t)tk * 64 + sc0);                       \
  rUT1 = *(const int4*)(uT + (CB) + (size_t)(tk + 64) * 64 + sc0);                \
  rIa = *(const int4*)(intra + (IB) + sr * 64 + sc0);                             \
  rWlN = ld4(wlast + ((size_t)bh * 64 + (NN)) * 128 + wloff);

#define STAGE_WRITE()                                                             \
  stsv16B(ewS, swzA(sr, sk0 * 2), rEw0);                                          \
  stsv16B(ewS, swzA(sr, sk0 * 2 + 16), rEw1);                                     \
  stsv16B(qtS, swzA(sr, sk0 * 2), rQt0);                                          \
  stsv16B(qtS, swzA(sr, sk0 * 2 + 16), rQt1);                                     \
  stsv16B(evS, swzB(sr, sc0 * 2), rEv);                                           \
  stsv16B(iaS, swzB(sr, sc0 * 2), rIa);                                           \
  stsv16B(uTS, swzB(tk, sc0 * 2), rUT0);                                          \
  stsv16B(uTS, swzB(tk + 64, sc0 * 2), rUT1);

  {
    const size_t cb0 = (size_t)bh * 64 * 8192;
    const size_t ib0 = (size_t)bh * 64 * 4096;
    STAGE_LOAD(cb0, ib0, 0);
    STAGE_WRITE();
    rWlC = rWlN;
  }
  __syncthreads();

  const int m = wave & 3, ntb = (wave >> 2) * 2;
  const int arow = 16 * m + l15;
  const int krow = 16 * wave + l15;

  for (int n = 0; n < NCc; ++n) {
    const size_t cb = ((size_t)bh * 64 + n) * 8192;
    const size_t ib = ((size_t)bh * 64 + n) * 4096;
    // ---- Phase A: prefetch n+1; delta = ev - ew@S -> dBT ----
    if (n < 63) { STAGE_LOAD(cb + 8192, ib + 4096, n + 1); }
    bf16x8 aEw[4];
#pragma unroll
    for (int ks = 0; ks < 4; ++ks) aEw[ks] = ldsv8(ewS, swzA(arow, 16 * l4 + 64 * ks));
#pragma unroll
    for (int i = 0; i < 2; ++i) {
      int vl = 16 * (ntb + i) + l15;
      f32x4 p = {};
#pragma unroll
      for (int ks = 0; ks < 4; ++ks)
        p = __builtin_amdgcn_mfma_f32_16x16x32_bf16(aEw[ks], ldsv8(sBT, swzA(vl, 16 * l4 + 64 * ks)), p, 0, 0, 0);
      float d[4];
#pragma unroll
      for (int r = 0; r < 4; ++r) {
        int c = 16 * m + 4 * l4 + r;
        d[r] = bf2f(lds16(evS, swzB(c, 2 * vl))) - p[r];
      }
      uint2 pk;
      pk.x = (unsigned)f2bf(d[0]) | ((unsigned)f2bf(d[1]) << 16);
      pk.y = (unsigned)f2bf(d[2]) | ((unsigned)f2bf(d[3]) << 16);
      stsv8B(dBT, swzB(vl, (16 * m + 4 * l4) * 2), pk);
    }
    __syncthreads();
    // ---- Phase B1: o = qt@S + ia@delta; S = wl*(S + uT@delta) ----
    bf16x8 aQt[4], aIa[2], aU[2];
#pragma unroll
    for (int ks = 0; ks < 4; ++ks) aQt[ks] = ldsv8(qtS, swzA(arow, 16 * l4 + 64 * ks));
#pragma unroll
    for (int ks = 0; ks < 2; ++ks) aIa[ks] = ldsv8(iaS, swzB(arow, 16 * l4 + 64 * ks));
#pragma unroll
    for (int ks = 0; ks < 2; ++ks) aU[ks] = ldsv8(uTS, swzB(krow, 16 * l4 + 64 * ks));
#pragma unroll
    for (int i = 0; i < 2; ++i) {
      int vl = 16 * (ntb + i) + l15;
      f32x4 o = {};
#pragma unroll
      for (int ks = 0; ks < 4; ++ks)
        o = __builtin_amdgcn_mfma_f32_16x16x32_bf16(aQt[ks], ldsv8(sBT, swzA(vl, 16 * l4 + 64 * ks)), o, 0, 0, 0);
#pragma unroll
      for (int ks = 0; ks < 2; ++ks)
        o = __builtin_amdgcn_mfma_f32_16x16x32_bf16(aIa[ks], ldsv8(dBT, swzB(vl, 16 * l4 + 64 * ks)), o, 0, 0, 0);
#pragma unroll
      for (int r = 0; r < 4; ++r) {
        int c = 16 * m + 4 * l4 + r;
        int t = n * 64 + c;
        attn_o[((size_t)(b * Tc + t) * Hc + h) * Kc + v0 + vl] = f2bf(o[r]);
      }
    }
    float wlv[4] = {rWlC.x, rWlC.y, rWlC.z, rWlC.w};
#pragma unroll
    for (int nt4 = 0; nt4 < 4; ++nt4) {
      int vl = 16 * nt4 + l15;
      f32x4 U = {};
#pragma unroll
      for (int ks = 0; ks < 2; ++ks)
        U = __builtin_amdgcn_mfma_f32_16x16x32_bf16(aU[ks], ldsv8(dBT, swzB(vl, 16 * l4 + 64 * ks)), U, 0, 0, 0);
#pragma unroll
      for (int r = 0; r < 4; ++r) S[nt4][r] = wlv[r] * (S[nt4][r] + U[r]);
    }
    __syncthreads();
    // ---- Phase B2: S -> sBT, staging writes, snapshot ----
#pragma unroll
    for (int nt4 = 0; nt4 < 4; ++nt4) {
      int vl = 16 * nt4 + l15;
      uint2 pk;
      pk.x = (unsigned)f2bf(S[nt4][0]) | ((unsigned)f2bf(S[nt4][1]) << 16);
      pk.y = (unsigned)f2bf(S[nt4][2]) | ((unsigned)f2bf(S[nt4][3]) << 16);
      stsv8B(sBT, swzA(vl, (16 * wave + 4 * l4) * 2), pk);
    }
    if (n < 63) { STAGE_WRITE(); rWlC = rWlN; }
    if ((n & 3) == 3) {
      int ns = n >> 2;
      size_t sb = (size_t)((ns * Bc + b) * Hc + h) * 16384;
#pragma unroll
      for (int nt4 = 0; nt4 < 4; ++nt4)
#pragma unroll
        for (int r = 0; r < 4; ++r) {
          int k = 16 * wave + 4 * l4 + r;
          snapb[sb + (size_t)k * 128 + v0 + 16 * nt4 + l15] = f2bf(S[nt4][r]);
        }
    }
    __syncthreads();
  }
#undef STAGE_LOAD
#undef STAGE_WRITE
}

// ---------------- snapshot helpers ----------------
__global__ void sdw_mul_bf16(const float* __restrict__ snap_down, const float* __restrict__ w,
                             unsigned short* __restrict__ sdwb) {
  int i = (blockIdx.x * 256 + threadIdx.x) * 4;
  float4 v = ld4(snap_down + i);
  int k = i & 16383;
  float4 ww = ld4(w + k);
  ushort4 o;
  o.x = f2bf(v.x * ww.x); o.y = f2bf(v.y * ww.y); o.z = f2bf(v.z * ww.z); o.w = f2bf(v.w * ww.w);
  *reinterpret_cast<ushort4*>(sdwb + i) = o;
}

__global__ __launch_bounds__(256) void snap_scale_kernel(const unsigned short* __restrict__ snapb,
                                                         float* __restrict__ scale) {
  int r = blockIdx.x;
  const unsigned short* row = snapb + (size_t)r * 16384;
  float s = 0.f;
  for (int ii = threadIdx.x * 4; ii < 16384; ii += 1024) {
    float4 x = ld4(row + ii);
    s += x.x * x.x + x.y * x.y + x.z * x.z + x.w * x.w;
  }
#pragma unroll
  for (int off = 32; off > 0; off >>= 1) s += __shfl_down(s, off, 64);
  __shared__ float red[4];
  if ((threadIdx.x & 63) == 0) red[threadIdx.x >> 6] = s;
  __syncthreads();
  if (threadIdx.x == 0) {
    float tot = red[0] + red[1] + red[2] + red[3];
    scale[r] = rsqrtf(tot * (1.f / 16384.f) + 1e-6f);
  }
}

__global__ void snap_reduce_scatter(const float* __restrict__ part,
                                    const float* __restrict__ scale,
                                    float* __restrict__ outp) {
  int idx = blockIdx.x * 256 + threadIdx.x;
  int l = idx & 127;
  int hh = (idx >> 7) & 15;
  int ns = (idx >> 11) & 15;
  int bb = idx >> 15;
  int r = (ns * Bc + bb) * Hc + hh;
  float s = 0.f;
#pragma unroll
  for (int z = 0; z < 16; ++z) s += part[(size_t)z * 65536 + r * 128 + l];
  outp[idx] = s * scale[r];
}

// ---------------- final rmsnorm * sigmoid(gate): wave-per-row ----------
__global__ __launch_bounds__(256) void out_norm_gate(unsigned short* __restrict__ attn_io,
                                                     const unsigned short* __restrict__ gate_raw,
                                                     const float* __restrict__ bgb,
                                                     const float* __restrict__ o_norm_w) {
  const int wave = threadIdx.x >> 6, lane = threadIdx.x & 63;
  const int blk = blockIdx.x * 4 + wave;  // (b*T + t)*H + h
  const int h = blk & 15;
  const size_t row = (size_t)(blk >> 4);
  const size_t base = (size_t)blk * Kc;
  ushort2 xv = *reinterpret_cast<const ushort2*>(attn_io + base + 2 * lane);
  float x0 = bf2f(xv.x), x1 = bf2f(xv.y);
  float ss = x0 * x0 + x1 * x1;
#pragma unroll
  for (int off = 32; off > 0; off >>= 1) ss += __shfl_xor(ss, off, 64);
  float inv = rsqrtf(ss * (1.f / 128.f) + 1e-6f);
  const int p0 = h * Kc + 2 * lane;
  ushort2 gv = *reinterpret_cast<const ushort2*>(gate_raw + row * Pc + p0);
  float g0 = bf2f(gv.x) + bgb[p0];
  float g1 = bf2f(gv.y) + bgb[p0 + 1];
  float o0 = x0 * inv * o_norm_w[2 * lane] * fsig(g0);
  float o1 = x1 * inv * o_norm_w[2 * lane + 1] * fsig(g1);
  ushort2 ov; ov.x = f2bf(o0); ov.y = f2bf(o1);
  *reinterpret_cast<ushort2*>(attn_io + base + 2 * lane) = ov;
}

// ---------------- launch ----------------
extern "C" void kernel_launch(void* const* d_in, const int* in_sizes, int n_in,
                              void* d_out, int out_size, void* d_ws, size_t ws_size,
                              hipStream_t stream) {
  (void)in_sizes; (void)n_in;
  const float* x        = (const float*)d_in[0];
  const float* Wq       = (const float*)d_in[1];
  const float* Wk       = (const float*)d_in[2];
  const float* Wv       = (const float*)d_in[3];
  const float* conv_q   = (const float*)d_in[4];
  const float* conv_k   = (const float*)d_in[5];
  const float* conv_v   = (const float*)d_in[6];
  const float* A_log    = (const float*)d_in[7];
  const float* dt_bias  = (const float*)d_in[8];
  const float* Wfa      = (const float*)d_in[9];
  const float* Wfb      = (const float*)d_in[10];
  const float* Wb       = (const float*)d_in[11];
  const float* Wga      = (const float*)d_in[12];
  const float* Wgb      = (const float*)d_in[13];
  const float* bgb      = (const float*)d_in[14];
  const float* o_norm_w = (const float*)d_in[15];
  const float* Wo       = (const float*)d_in[16];
  const float* snap_nw  = (const float*)d_in[17];
  const float* snap_down= (const float*)d_in[18];

  const size_t MP2 = (size_t)Mc * Pc * 2;
  const size_t NEED = 6 * MP2
                    + 2 * (size_t)Mc * Kc * 4
                    + (size_t)Mc * Hc * 4
                    + (size_t)Bc * Hc * NCc * Kc * 4;
  if (ws_size < NEED + 4096) {
    hipMemsetAsync(d_out, 0, (size_t)out_size * 4, stream);
    return;
  }
  char* w = (char*)d_ws;
  auto alloc = [&](size_t bytes) {
    char* r = w;
    w += (bytes + 255) & ~(size_t)255;
    return r;
  };
  unsigned short* q_lin = (unsigned short*)alloc(MP2);
  unsigned short* k_lin = (unsigned short*)alloc(MP2);
  unsigned short* v_lin = (unsigned short*)alloc(MP2);
  unsigned short* g_raw = (unsigned short*)alloc(MP2);
  unsigned short* evb   = (unsigned short*)alloc(MP2);
  unsigned short* ewb   = (unsigned short*)alloc(MP2);
  float* fa    = (float*)alloc((size_t)Mc * Kc * 4);
  float* ga    = (float*)alloc((size_t)Mc * Kc * 4);
  float* betab = (float*)alloc((size_t)Mc * Hc * 4);
  float* wlast = (float*)alloc((size_t)Bc * Hc * NCc * Kc * 4);

  unsigned short* qt = (unsigned short*)d_out;
  unsigned short* u_ = (unsigned short*)((char*)d_out + MP2);

  unsigned short* xb    = evb;
  unsigned short* Wqb   = ewb;
  unsigned short* Wkb   = ewb + 4194304;
  unsigned short* Wvb   = ewb + 8388608;
  unsigned short* Wfab  = ewb + 12582912;
  unsigned short* Wgab  = ewb + 12845056;
  unsigned short* Wfbb  = ewb + 13107200;
  unsigned short* fab   = (unsigned short*)fa;
  unsigned short* gab   = (unsigned short*)ga;

  unsigned short* intra = q_lin;
  unsigned short* Wob   = q_lin + 8388608;
  unsigned short* Wgbb  = q_lin + 12582912;
  unsigned short* attn  = k_lin;
  unsigned short* gate_raw = g_raw;
  unsigned short* snapb = v_lin;
  unsigned short* sdwb  = v_lin + (size_t)512 * 16384;
  float* partial   = (float*)ewb;
  float* snapscale = (float*)(ewb + 4400000);

  float* y = (float*)d_out;
  float* snaps_out = (float*)d_out + (size_t)Bc * Tc * Dc;

  // 0) casts
  cast_f32_bf16<<<16384, 256, 0, stream>>>(x, xb, Mc * Dc);
  cast_f32_bf16<<<4096, 256, 0, stream>>>(Wq, Wqb, Pc * Dc);
  cast_f32_bf16<<<4096, 256, 0, stream>>>(Wk, Wkb, Pc * Dc);
  cast_f32_bf16<<<4096, 256, 0, stream>>>(Wv, Wvb, Pc * Dc);
  cast_f32_bf16<<<256, 256, 0, stream>>>(Wfa, Wfab, Kc * Dc);
  cast_f32_bf16<<<256, 256, 0, stream>>>(Wga, Wgab, Kc * Dc);
  cast_f32_bf16<<<256, 256, 0, stream>>>(Wfb, Wfbb, Pc * Kc);

  // 1) input GEMMs (bf16 MFMA)
  gemm_nt_mfma<unsigned short><<<dim3(64, 16), 256, 0, stream>>>(xb, Wqb, q_lin, Pc, Dc);
  gemm_nt_mfma<unsigned short><<<dim3(64, 16), 256, 0, stream>>>(xb, Wkb, k_lin, Pc, Dc);
  gemm_nt_mfma<unsigned short><<<dim3(64, 16), 256, 0, stream>>>(xb, Wvb, v_lin, Pc, Dc);
  gemm_nt_mfma<unsigned short><<<dim3(64, 1), 256, 0, stream>>>(xb, Wfab, fab, Kc, Dc);
  gemm_nt_mfma<unsigned short><<<dim3(64, 1), 256, 0, stream>>>(xb, Wgab, gab, Kc, Dc);
  gemm_nt<unsigned short, float, float><<<dim3(64, 1), 256, 0, stream>>>(xb, Wb, betab, Hc, Dc);
  gemm_nt_mfma<unsigned short><<<dim3(64, 16), 256, 0, stream>>>(fab, Wfbb, g_raw, Pc, Kc);

  // 2) chunk prep (wave-per-chunk, fast transcendentals)
  chunk_prep<<<Bc * Hc * NCc / 4, 256, 0, stream>>>(q_lin, k_lin, v_lin, g_raw, betab, conv_q,
                                                    conv_k, conv_v, A_log, dt_bias, qt, u_, evb,
                                                    ewb, wlast);

  // 3) late casts into q_lin's dead tail
  cast_f32_bf16<<<4096, 256, 0, stream>>>(Wo, Wob, Dc * Pc);
  cast_f32_bf16<<<256, 256, 0, stream>>>(Wgb, Wgbb, Pc * Kc);

  // chunk solve (also transposes u -> uT in place)
  chunk_solve_mfma<<<Bc * Hc * NCc, 256, 0, stream>>>(qt, u_, evb, ewb, intra);

  // 4) gate projection
  gemm_nt_mfma<unsigned short><<<dim3(64, 16), 256, 0, stream>>>(gab, Wgbb, gate_raw, Pc, Kc);

  // 5) MFMA scan, v-split x2 (u_ holds uT)
  scan_mfma<<<Bc * Hc * 2, 512, 0, stream>>>(qt, u_, evb, ewb, intra, wlast, attn, snapb);

  // 6) snapshots
  sdw_mul_bf16<<<2048, 256, 0, stream>>>(snap_down, snap_nw, sdwb);
  snap_scale_kernel<<<512, 256, 0, stream>>>(snapb, snapscale);
  gemm_nt_mfma_sk<<<dim3(4, 1, 16), 256, 0, stream>>>(snapb, sdwb, partial, 128, 16384, 1024, 512);
  snap_reduce_scatter<<<256, 256, 0, stream>>>(partial, snapscale, snaps_out);

  // 7) output norm*gate + final projection
  out_norm_gate<<<Mc * Hc / 4, 256, 0, stream>>>(attn, gate_raw, bgb, o_norm_w);
  gemm_nt_mfma<float><<<dim3(64, 16), 256, 0, stream>>>(attn, Wob, y, Dc, Pc);
}

// Round 10
// 1017.968 us; speedup vs baseline: 7.8560x; 1.1799x over previous
//
#include <hip/hip_runtime.h>

// ---------------- problem constants ----------------
constexpr int Bc   = 2;
constexpr int Tc   = 4096;
constexpr int Dc   = 2048;
constexpr int Hc   = 16;
constexpr int Kc   = 128;
constexpr int Pc   = Hc * Kc;     // 2048
constexpr int Cc   = 64;          // chunk size
constexpr int NCc  = Tc / Cc;     // 64 chunks
constexpr int Mc   = Bc * Tc;     // 8192 rows
constexpr int LATc = 128;

// ---------------- helpers ----------------
__device__ __forceinline__ float bf2f(unsigned short u) {
  unsigned int x = ((unsigned int)u) << 16;
  return __builtin_bit_cast(float, x);
}
__device__ __forceinline__ unsigned short f2bf(float f) {
  unsigned int x = __builtin_bit_cast(unsigned int, f);
  x += 0x7fffu + ((x >> 16) & 1u);
  return (unsigned short)(x >> 16);
}
__device__ __forceinline__ float4 ld4(const float* p) {
  return *reinterpret_cast<const float4*>(p);
}
__device__ __forceinline__ float4 ld4(const unsigned short* p) {
  ushort4 u = *reinterpret_cast<const ushort4*>(p);
  return make_float4(bf2f(u.x), bf2f(u.y), bf2f(u.z), bf2f(u.w));
}
__device__ __forceinline__ void st1(float* p, float v) { *p = v; }
__device__ __forceinline__ void st1(unsigned short* p, float v) { *p = f2bf(v); }

// fast transcendentals (native v_exp_f32 / v_log_f32 / v_rcp_f32)
__device__ __forceinline__ float fsig(float x) {
  return __fdividef(1.f, 1.f + __expf(-x));
}
__device__ __forceinline__ float fsoftplus(float g) {
  return (g > 20.f) ? g : __logf(1.f + __expf(g));
}

typedef __attribute__((ext_vector_type(8))) short bf16x8;
typedef __attribute__((ext_vector_type(4))) float f32x4;

// LDS swizzles: rows of stride 256B (swzA) and 128B (swzB); byte ^= ((row&7)<<4)
__device__ __forceinline__ int swzA(int row, int kbyte) { return row * 256 + (kbyte ^ ((row & 7) << 4)); }
__device__ __forceinline__ int swzB(int row, int kbyte) { return row * 128 + (kbyte ^ ((row & 7) << 4)); }
__device__ __forceinline__ bf16x8 ldsv8(const unsigned short* base, int byteoff) {
  return *reinterpret_cast<const bf16x8*>(reinterpret_cast<const char*>(base) + byteoff);
}
__device__ __forceinline__ void stsv16B(unsigned short* base, int byteoff, int4 v) {
  *reinterpret_cast<int4*>(reinterpret_cast<char*>(base) + byteoff) = v;
}
__device__ __forceinline__ void stsv8B(unsigned short* base, int byteoff, uint2 v) {
  *reinterpret_cast<uint2*>(reinterpret_cast<char*>(base) + byteoff) = v;
}
__device__ __forceinline__ unsigned short lds16(const unsigned short* base, int byteoff) {
  return *reinterpret_cast<const unsigned short*>(reinterpret_cast<const char*>(base) + byteoff);
}

// bijective XCD-aware block swizzle (T1); identity unless nwg%8==0 && nwg>=16
__device__ __forceinline__ int xcd_swz(int id, int nwg) {
  if ((nwg & 7) != 0 || nwg < 16) return id;
  return (id & 7) * (nwg >> 3) + (id >> 3);
}

// ---------------- f32 -> bf16 cast ----------------
__global__ void cast_f32_bf16(const float* __restrict__ in, unsigned short* __restrict__ out,
                              int n) {
  int i = (blockIdx.x * 256 + threadIdx.x) * 4;
  if (i < n) {
    float4 v = ld4(in + i);
    ushort4 o;
    o.x = f2bf(v.x); o.y = f2bf(v.y); o.z = f2bf(v.z); o.w = f2bf(v.w);
    *reinterpret_cast<ushort4*>(out + i) = o;
  }
}

// ---------------- bf16 MFMA NT GEMM (128x128 tile, m97 structure, XCD swizzle) ------
__device__ __forceinline__ void gload_lds16(const unsigned short* g, unsigned short* l) {
  __builtin_amdgcn_global_load_lds(
      (const __attribute__((address_space(1))) void*)g,
      (__attribute__((address_space(3))) void*)l, 16, 0, 0);
}

template <typename OT>
__global__ __launch_bounds__(256) void gemm_nt_mfma(const unsigned short* __restrict__ A,
                                                    const unsigned short* __restrict__ Bm,
                                                    OT* __restrict__ Out,
                                                    int Ndim, int Kd) {
  __shared__ __align__(16) unsigned short As[128 * 32];
  __shared__ __align__(16) unsigned short Bs[128 * 32];
  int id = blockIdx.y * gridDim.x + blockIdx.x;
  id = xcd_swz(id, gridDim.x * gridDim.y);
  const int m0 = (id % gridDim.x) * 128;
  const int n0 = (id / gridDim.x) * 128;
  const int tid = threadIdx.x;
  const int wave = tid >> 6;
  const int lane = tid & 63;
  const int wr = wave >> 1, wc = wave & 1;
  const int l15 = lane & 15, l4 = lane >> 4;
  f32x4 acc[4][4] = {};

  for (int k0 = 0; k0 < Kd; k0 += 32) {
#pragma unroll
    for (int i = 0; i < 2; ++i) {
      int e = (wave * 2 + i) * 512 + lane * 8;
      int r = e >> 5, c = e & 31;
      gload_lds16(&A[(size_t)(m0 + r) * Kd + k0 + c], &As[(wave * 2 + i) * 512]);
      gload_lds16(&Bm[(size_t)(n0 + r) * Kd + k0 + c], &Bs[(wave * 2 + i) * 512]);
    }
    __syncthreads();
    bf16x8 af[4], bfr[4];
#pragma unroll
    for (int m = 0; m < 4; ++m)
      af[m] = *reinterpret_cast<const bf16x8*>(&As[(wr * 64 + m * 16 + l15) * 32 + l4 * 8]);
#pragma unroll
    for (int n = 0; n < 4; ++n)
      bfr[n] = *reinterpret_cast<const bf16x8*>(&Bs[(wc * 64 + n * 16 + l15) * 32 + l4 * 8]);
#pragma unroll
    for (int m = 0; m < 4; ++m)
#pragma unroll
      for (int n = 0; n < 4; ++n)
        acc[m][n] = __builtin_amdgcn_mfma_f32_16x16x32_bf16(af[m], bfr[n], acc[m][n], 0, 0, 0);
    __syncthreads();
  }
#pragma unroll
  for (int m = 0; m < 4; ++m)
#pragma unroll
    for (int n = 0; n < 4; ++n)
#pragma unroll
      for (int r = 0; r < 4; ++r) {
        int row = m0 + wr * 64 + m * 16 + l4 * 4 + r;
        int col = n0 + wc * 64 + n * 16 + l15;
        st1(&Out[(size_t)row * Ndim + col], acc[m][n][r]);
      }
}

// ---- fused QKV variant: B = [Wq;Wk;Wv] contiguous (6144 rows); output col>>11 picks
// one of 3 contiguous [Mc][2048] buffers starting at Out. grid (64, 48).
__global__ __launch_bounds__(256) void gemm_nt_mfma_qkv(const unsigned short* __restrict__ A,
                                                        const unsigned short* __restrict__ Bm,
                                                        unsigned short* __restrict__ Out,
                                                        int Kd) {
  __shared__ __align__(16) unsigned short As[128 * 32];
  __shared__ __align__(16) unsigned short Bs[128 * 32];
  int id = blockIdx.y * gridDim.x + blockIdx.x;
  id = xcd_swz(id, gridDim.x * gridDim.y);
  const int m0 = (id % gridDim.x) * 128;
  const int n0 = (id / gridDim.x) * 128;
  const int tid = threadIdx.x;
  const int wave = tid >> 6;
  const int lane = tid & 63;
  const int wr = wave >> 1, wc = wave & 1;
  const int l15 = lane & 15, l4 = lane >> 4;
  f32x4 acc[4][4] = {};

  for (int k0 = 0; k0 < Kd; k0 += 32) {
#pragma unroll
    for (int i = 0; i < 2; ++i) {
      int e = (wave * 2 + i) * 512 + lane * 8;
      int r = e >> 5, c = e & 31;
      gload_lds16(&A[(size_t)(m0 + r) * Kd + k0 + c], &As[(wave * 2 + i) * 512]);
      gload_lds16(&Bm[(size_t)(n0 + r) * Kd + k0 + c], &Bs[(wave * 2 + i) * 512]);
    }
    __syncthreads();
    bf16x8 af[4], bfr[4];
#pragma unroll
    for (int m = 0; m < 4; ++m)
      af[m] = *reinterpret_cast<const bf16x8*>(&As[(wr * 64 + m * 16 + l15) * 32 + l4 * 8]);
#pragma unroll
    for (int n = 0; n < 4; ++n)
      bfr[n] = *reinterpret_cast<const bf16x8*>(&Bs[(wc * 64 + n * 16 + l15) * 32 + l4 * 8]);
#pragma unroll
    for (int m = 0; m < 4; ++m)
#pragma unroll
      for (int n = 0; n < 4; ++n)
        acc[m][n] = __builtin_amdgcn_mfma_f32_16x16x32_bf16(af[m], bfr[n], acc[m][n], 0, 0, 0);
    __syncthreads();
  }
  // output: buffer index = col>>11, local col = col&2047
  unsigned short* dst = Out + (size_t)(n0 >> 11) * ((size_t)Mc * 2048);
  const int cbase = n0 & 2047;
#pragma unroll
  for (int m = 0; m < 4; ++m)
#pragma unroll
    for (int n = 0; n < 4; ++n)
#pragma unroll
      for (int r = 0; r < 4; ++r) {
        int row = m0 + wr * 64 + m * 16 + l4 * 4 + r;
        int col = cbase + wc * 64 + n * 16 + l15;
        dst[(size_t)row * 2048 + col] = f2bf(acc[m][n][r]);
      }
}

// ---- splitK variant ----
__global__ __launch_bounds__(256) void gemm_nt_mfma_sk(const unsigned short* __restrict__ A,
                                                       const unsigned short* __restrict__ Bm,
                                                       float* __restrict__ Part,
                                                       int Ndim, int Kd, int kslice, int Mtot) {
  __shared__ __align__(16) unsigned short As[128 * 32];
  __shared__ __align__(16) unsigned short Bs[128 * 32];
  const int m0 = blockIdx.x * 128;
  const int n0 = blockIdx.y * 128;
  const int kz = blockIdx.z * kslice;
  const int tid = threadIdx.x;
  const int wave = tid >> 6;
  const int lane = tid & 63;
  const int wr = wave >> 1, wc = wave & 1;
  const int l15 = lane & 15, l4 = lane >> 4;
  f32x4 acc[4][4] = {};

  for (int k0 = kz; k0 < kz + kslice; k0 += 32) {
#pragma unroll
    for (int i = 0; i < 2; ++i) {
      int e = (wave * 2 + i) * 512 + lane * 8;
      int r = e >> 5, c = e & 31;
      gload_lds16(&A[(size_t)(m0 + r) * Kd + k0 + c], &As[(wave * 2 + i) * 512]);
      gload_lds16(&Bm[(size_t)(n0 + r) * Kd + k0 + c], &Bs[(wave * 2 + i) * 512]);
    }
    __syncthreads();
    bf16x8 af[4], bfr[4];
#pragma unroll
    for (int m = 0; m < 4; ++m)
      af[m] = *reinterpret_cast<const bf16x8*>(&As[(wr * 64 + m * 16 + l15) * 32 + l4 * 8]);
#pragma unroll
    for (int n = 0; n < 4; ++n)
      bfr[n] = *reinterpret_cast<const bf16x8*>(&Bs[(wc * 64 + n * 16 + l15) * 32 + l4 * 8]);
#pragma unroll
    for (int m = 0; m < 4; ++m)
#pragma unroll
      for (int n = 0; n < 4; ++n)
        acc[m][n] = __builtin_amdgcn_mfma_f32_16x16x32_bf16(af[m], bfr[n], acc[m][n], 0, 0, 0);
    __syncthreads();
  }
  float* out = Part + (size_t)blockIdx.z * Mtot * Ndim;
#pragma unroll
  for (int m = 0; m < 4; ++m)
#pragma unroll
    for (int n = 0; n < 4; ++n)
#pragma unroll
      for (int r = 0; r < 4; ++r) {
        int row = m0 + wr * 64 + m * 16 + l4 * 4 + r;
        int col = n0 + wc * 64 + n * 16 + l15;
        out[(size_t)row * Ndim + col] = acc[m][n][r];
      }
}

// ---------------- chunk prep: one WAVE per chunk, fast transcendentals ----------------
// grid: Bc*Hc*NCc/4 = 512 blocks x 256 threads (4 waves = 4 chunks)
// beta_lin is betap[Mc][128] (padded MFMA output; head h at col h)
__global__ __launch_bounds__(256) void chunk_prep(
    const unsigned short* __restrict__ q_lin, const unsigned short* __restrict__ k_lin,
    const unsigned short* __restrict__ v_lin, const unsigned short* __restrict__ g_raw,
    const float* __restrict__ beta_lin, const float* __restrict__ conv_q,
    const float* __restrict__ conv_k, const float* __restrict__ conv_v,
    const float* __restrict__ A_log, const float* __restrict__ dt_bias,
    unsigned short* __restrict__ qt, unsigned short* __restrict__ u_,
    unsigned short* __restrict__ bv, unsigned short* __restrict__ bw,
    float* __restrict__ wlast) {
  const int wave = threadIdx.x >> 6, lane = threadIdx.x & 63;
  const int cid = blockIdx.x * 4 + wave;  // (b*H+h)*NC + n
  const int n = cid & 63;
  const int h = (cid >> 6) & 15;
  const int b = cid >> 10;
  const int k0 = 2 * lane;
  const int p = h * Kc + k0;
  float cq[2][4], ck[2][4], cv[2][4];
#pragma unroll
  for (int s = 0; s < 2; ++s)
#pragma unroll
    for (int j = 0; j < 4; ++j) {
      cq[s][j] = conv_q[(p + s) * 4 + j];
      ck[s][j] = conv_k[(p + s) * 4 + j];
      cv[s][j] = conv_v[(p + s) * 4 + j];
    }
  const float aneg = -__expf(A_log[h]);
  const float db0 = dt_bias[p], db1 = dt_bias[p + 1];
  float cum0 = 0.f, cum1 = 0.f;
  const int t0 = n * Cc;
  float wq[2][3] = {}, wk[2][3] = {}, wv[2][3] = {};
#pragma unroll
  for (int d = 0; d < 3; ++d) {
    int ts = t0 - 3 + d;
    if (ts >= 0) {
      size_t o = ((size_t)(b * Tc + ts)) * Pc + p;
      ushort2 q2 = *(const ushort2*)(q_lin + o);
      ushort2 k2 = *(const ushort2*)(k_lin + o);
      ushort2 v2 = *(const ushort2*)(v_lin + o);
      wq[0][d] = bf2f(q2.x); wq[1][d] = bf2f(q2.y);
      wk[0][d] = bf2f(k2.x); wk[1][d] = bf2f(k2.y);
      wv[0][d] = bf2f(v2.x); wv[1][d] = bf2f(v2.y);
    }
  }
  for (int c = 0; c < Cc; ++c) {
    const int t = t0 + c;
    size_t off = ((size_t)(b * Tc + t)) * Pc + p;
    ushort2 q2 = *(const ushort2*)(q_lin + off);
    ushort2 k2 = *(const ushort2*)(k_lin + off);
    ushort2 v2 = *(const ushort2*)(v_lin + off);
    ushort2 g2 = *(const ushort2*)(g_raw + off);
    float nq[2] = {bf2f(q2.x), bf2f(q2.y)};
    float nk[2] = {bf2f(k2.x), bf2f(k2.y)};
    float nv[2] = {bf2f(v2.x), bf2f(v2.y)};
    float qv[2], kv[2], vv[2];
#pragma unroll
    for (int s = 0; s < 2; ++s) {
      qv[s] = cq[s][0] * wq[s][0] + cq[s][1] * wq[s][1] + cq[s][2] * wq[s][2] + cq[s][3] * nq[s];
      kv[s] = ck[s][0] * wk[s][0] + ck[s][1] * wk[s][1] + ck[s][2] * wk[s][2] + ck[s][3] * nk[s];
      vv[s] = cv[s][0] * wv[s][0] + cv[s][1] * wv[s][1] + cv[s][2] * wv[s][2] + cv[s][3] * nv[s];
      wq[s][0] = wq[s][1]; wq[s][1] = wq[s][2]; wq[s][2] = nq[s];
      wk[s][0] = wk[s][1]; wk[s][1] = wk[s][2]; wk[s][2] = nk[s];
      wv[s][0] = wv[s][1]; wv[s][1] = wv[s][2]; wv[s][2] = nv[s];
      qv[s] = qv[s] * fsig(qv[s]);  // silu
      kv[s] = kv[s] * fsig(kv[s]);
      vv[s] = vv[s] * fsig(vv[s]);
    }
    float a = qv[0] * qv[0] + qv[1] * qv[1];
    float bb = kv[0] * kv[0] + kv[1] * kv[1];
#pragma unroll
    for (int off2 = 32; off2 > 0; off2 >>= 1) {
      a += __shfl_xor(a, off2, 64);
      bb += __shfl_xor(bb, off2, 64);
    }
    float rq = rsqrtf(a + 1e-12f) * 0.08838834764831845f;  // * K^-0.5
    float rk = rsqrtf(bb + 1e-12f);
    float g0 = bf2f(g2.x) + db0, g1 = bf2f(g2.y) + db1;
    cum0 += aneg * fsoftplus(g0);
    cum1 += aneg * fsoftplus(g1);
    float cc0 = fmaxf(cum0, -15.f), cc1 = fmaxf(cum1, -15.f);
    float Wg0 = __expf(cc0), Wg1 = __expf(cc1);
    float Wi0 = __fdividef(1.f, Wg0), Wi1 = __fdividef(1.f, Wg1);
    float beta = fsig(beta_lin[((size_t)(b * Tc + t)) * 128 + h]);
    size_t idx = ((size_t)cid * Cc + c) * Kc + k0;
    ushort2 o1, o2, o3, o4;
    o1.x = f2bf(qv[0] * rq * Wg0); o1.y = f2bf(qv[1] * rq * Wg1);
    o2.x = f2bf(kv[0] * rk * Wi0); o2.y = f2bf(kv[1] * rk * Wi1);
    o3.x = f2bf(beta * kv[0] * rk * Wg0); o3.y = f2bf(beta * kv[1] * rk * Wg1);
    o4.x = f2bf(beta * vv[0]); o4.y = f2bf(beta * vv[1]);
    *(ushort2*)(qt + idx) = o1;
    *(ushort2*)(u_ + idx) = o2;
    *(ushort2*)(bw + idx) = o3;
    *(ushort2*)(bv + idx) = o4;
    if (c == Cc - 1) {
      wlast[(size_t)cid * Kc + k0] = Wg0;
      wlast[(size_t)cid * Kc + k0 + 1] = Wg1;
    }
  }
}

// ---------------- MFMA chunk solve + in-place u -> u^T transpose ----------------
__global__ __launch_bounds__(256) void chunk_solve_mfma(
    const unsigned short* __restrict__ qt, unsigned short* __restrict__ u_,
    unsigned short* __restrict__ evb,  // in: bv, out: ev
    unsigned short* __restrict__ ewb,  // in: bw, out: ew
    unsigned short* __restrict__ intra_out) {
  const int blk = blockIdx.x;
  const size_t base = (size_t)blk * (Cc * Kc);
  const size_t ibase = (size_t)blk * (Cc * Cc);
  const int tid = threadIdx.x, wave = tid >> 6, lane = tid & 63;
  const int l15 = lane & 15, l4 = lane >> 4;

  __shared__ __align__(16) char lds[65536];
  unsigned short* uS   = (unsigned short*)(lds);            // [64][128] swzA
  unsigned short* qtS  = (unsigned short*)(lds + 16384);    // [64][128] swzA
  unsigned short* bwS  = (unsigned short*)(lds + 32768);    // [64][128] swzA
  unsigned short* NLrm = (unsigned short*)(lds + 49152);    // [64][64] swzB
  unsigned short* NLT  = (unsigned short*)(lds + 57344);    // [64][64] swzB
  unsigned short* Trm  = (unsigned short*)(lds);            // over uS
  unsigned short* TT   = (unsigned short*)(lds + 8192);
  unsigned short* Prm  = (unsigned short*)(lds + 16384);    // over qtS
  unsigned short* PT   = (unsigned short*)(lds + 24576);
  unsigned short* bvT  = (unsigned short*)(lds + 32768);    // [128][64] swzB, over bwS
  unsigned short* bwT  = (unsigned short*)(lds + 49152);    // [128][64] swzB, over NL

#pragma unroll
  for (int i = 0; i < 4; ++i) {
    int cid = tid + i * 256;
    int r = cid >> 4, c8 = (cid & 15) * 8, cb2 = (cid & 15) * 16;
    int4 vu = *(const int4*)(u_ + base + (size_t)r * 128 + c8);
    int4 vb = *(const int4*)(ewb + base + (size_t)r * 128 + c8);
    int4 vq = *(const int4*)(qt + base + (size_t)r * 128 + c8);
    stsv16B(uS, swzA(r, cb2), vu);
    stsv16B(bwS, swzA(r, cb2), vb);
    stsv16B(qtS, swzA(r, cb2), vq);
  }
  __syncthreads();

  const int arow = 16 * wave + l15;
  bf16x8 aBw[4], aQt[4];
#pragma unroll
  for (int ks = 0; ks < 4; ++ks) {
    aBw[ks] = ldsv8(bwS, swzA(arow, 16 * l4 + 64 * ks));
    aQt[ks] = ldsv8(qtS, swzA(arow, 16 * l4 + 64 * ks));
  }
  f32x4 Lc[4], Ic[4];
#pragma unroll
  for (int nt = 0; nt < 4; ++nt) {
    f32x4 a = {}, bq = {};
#pragma unroll
    for (int ks = 0; ks < 4; ++ks) {
      bf16x8 bu = ldsv8(uS, swzA(16 * nt + l15, 16 * l4 + 64 * ks));
      a = __builtin_amdgcn_mfma_f32_16x16x32_bf16(aBw[ks], bu, a, 0, 0, 0);
      bq = __builtin_amdgcn_mfma_f32_16x16x32_bf16(aQt[ks], bu, bq, 0, 0, 0);
    }
    Lc[nt] = a; Ic[nt] = bq;
  }
#pragma unroll
  for (int nt = 0; nt < 4; ++nt)
#pragma unroll
    for (int r = 0; r < 4; ++r) {
      int row = 16 * wave + 4 * l4 + r, col = 16 * nt + l15;
      intra_out[ibase + (size_t)row * 64 + col] = f2bf((col <= row) ? Ic[nt][r] : 0.f);
    }

  // in-place u^T write-back
#pragma unroll
  for (int i = 0; i < 4; ++i) {
    int w2 = tid + i * 256;
    int k = w2 >> 3, cg = w2 & 7;
    unsigned short tmp[8];
#pragma unroll
    for (int j = 0; j < 8; ++j) {
      int c = cg + 8 * j;
      tmp[j] = lds16(uS, swzA(c, 2 * k));
    }
#pragma unroll
    for (int j = 0; j < 8; ++j)
      u_[base + (size_t)k * 64 + cg + 8 * j] = tmp[j];
  }
  __syncthreads();

  f32x4 Tf[4];
#pragma unroll
  for (int nt = 0; nt < 4; ++nt)
#pragma unroll
    for (int r = 0; r < 4; ++r) {
      int row = 16 * wave + 4 * l4 + r, col = 16 * nt + l15;
      float nl = (col < row) ? -Lc[nt][r] : 0.f;
      unsigned short nb = f2bf(nl);
      *reinterpret_cast<unsigned short*>((char*)NLrm + swzB(row, col * 2)) = nb;
      *reinterpret_cast<unsigned short*>((char*)NLT + swzB(col, row * 2)) = nb;
      float t0 = nl + ((row == col) ? 1.f : 0.f);
      Tf[nt][r] = t0;
      unsigned short tb = f2bf(t0);
      *reinterpret_cast<unsigned short*>((char*)Trm + swzB(row, col * 2)) = tb;
      *reinterpret_cast<unsigned short*>((char*)TT + swzB(col, row * 2)) = tb;
    }
  __syncthreads();

  bf16x8 aN[2];
#pragma unroll
  for (int ks = 0; ks < 2; ++ks) aN[ks] = ldsv8(NLrm, swzB(arow, 16 * l4 + 64 * ks));
  f32x4 Pf[4];
#pragma unroll
  for (int nt = 0; nt < 4; ++nt) {
    f32x4 acc = {};
#pragma unroll
    for (int ks = 0; ks < 2; ++ks)
      acc = __builtin_amdgcn_mfma_f32_16x16x32_bf16(aN[ks], ldsv8(NLT, swzB(16 * nt + l15, 16 * l4 + 64 * ks)), acc, 0, 0, 0);
    Pf[nt] = acc;
  }
  int4 rv[4], rw[4];
#pragma unroll
  for (int i = 0; i < 4; ++i) {
    int cid = tid + i * 256;
    int r = cid >> 4, c8 = (cid & 15) * 8;
    rv[i] = *(const int4*)(evb + base + (size_t)r * 128 + c8);
    rw[i] = *(const int4*)(ewb + base + (size_t)r * 128 + c8);
  }
#pragma unroll
  for (int nt = 0; nt < 4; ++nt)
#pragma unroll
    for (int r = 0; r < 4; ++r) {
      int row = 16 * wave + 4 * l4 + r, col = 16 * nt + l15;
      unsigned short pb = f2bf(Pf[nt][r]);
      *reinterpret_cast<unsigned short*>((char*)Prm + swzB(row, col * 2)) = pb;
      *reinterpret_cast<unsigned short*>((char*)PT + swzB(col, row * 2)) = pb;
    }
  __syncthreads();

  for (int it = 0; it < 5; ++it) {
    bf16x8 aP[2];
#pragma unroll
    for (int ks = 0; ks < 2; ++ks) aP[ks] = ldsv8(Prm, swzB(arow, 16 * l4 + 64 * ks));
    f32x4 Tn[4], Pn[4];
#pragma unroll
    for (int nt = 0; nt < 4; ++nt) {
      f32x4 acc = Tf[nt];
#pragma unroll
      for (int ks = 0; ks < 2; ++ks)
        acc = __builtin_amdgcn_mfma_f32_16x16x32_bf16(aP[ks], ldsv8(TT, swzB(16 * nt + l15, 16 * l4 + 64 * ks)), acc, 0, 0, 0);
      Tn[nt] = acc;
    }
    if (it < 4) {
#pragma unroll
      for (int nt = 0; nt < 4; ++nt) {
        f32x4 acc = {};
#pragma unroll
        for (int ks = 0; ks < 2; ++ks)
          acc = __builtin_amdgcn_mfma_f32_16x16x32_bf16(aP[ks], ldsv8(PT, swzB(16 * nt + l15, 16 * l4 + 64 * ks)), acc, 0, 0, 0);
        Pn[nt] = acc;
      }
    }
    __syncthreads();
#pragma unroll
    for (int nt = 0; nt < 4; ++nt)
#pragma unroll
      for (int r = 0; r < 4; ++r) {
        int row = 16 * wave + 4 * l4 + r, col = 16 * nt + l15;
        unsigned short tb = f2bf(Tn[nt][r]);
        *reinterpret_cast<unsigned short*>((char*)Trm + swzB(row, col * 2)) = tb;
        *reinterpret_cast<unsigned short*>((char*)TT + swzB(col, row * 2)) = tb;
        if (it < 4) {
          unsigned short pb = f2bf(Pn[nt][r]);
          *reinterpret_cast<unsigned short*>((char*)Prm + swzB(row, col * 2)) = pb;
          *reinterpret_cast<unsigned short*>((char*)PT + swzB(col, row * 2)) = pb;
        }
      }
#pragma unroll
    for (int nt = 0; nt < 4; ++nt) Tf[nt] = Tn[nt];
    __syncthreads();
  }

#pragma unroll
  for (int i = 0; i < 4; ++i) {
    int cid = tid + i * 256;
    int r = cid >> 4;
    const unsigned short* pv = reinterpret_cast<const unsigned short*>(&rv[i]);
    const unsigned short* pw = reinterpret_cast<const unsigned short*>(&rw[i]);
#pragma unroll
    for (int j = 0; j < 8; ++j) {
      int v = (cid & 15) * 8 + j;
      *reinterpret_cast<unsigned short*>((char*)bvT + swzB(v, r * 2)) = pv[j];
      *reinterpret_cast<unsigned short*>((char*)bwT + swzB(v, r * 2)) = pw[j];
    }
  }
  __syncthreads();

  bf16x8 aT[2];
#pragma unroll
  for (int ks = 0; ks < 2; ++ks) aT[ks] = ldsv8(Trm, swzB(arow, 16 * l4 + 64 * ks));
#pragma unroll
  for (int nt = 0; nt < 8; ++nt) {
    f32x4 e = {}, w2 = {};
#pragma unroll
    for (int ks = 0; ks < 2; ++ks) {
      e = __builtin_amdgcn_mfma_f32_16x16x32_bf16(aT[ks], ldsv8(bvT, swzB(16 * nt + l15, 16 * l4 + 64 * ks)), e, 0, 0, 0);
      w2 = __builtin_amdgcn_mfma_f32_16x16x32_bf16(aT[ks], ldsv8(bwT, swzB(16 * nt + l15, 16 * l4 + 64 * ks)), w2, 0, 0, 0);
    }
#pragma unroll
    for (int r = 0; r < 4; ++r) {
      int row = 16 * wave + 4 * l4 + r, col = 16 * nt + l15;
      evb[base + (size_t)row * 128 + col] = f2bf(e[r]);
      ewb[base + (size_t)row * 128 + col] = f2bf(w2[r]);
    }
  }
}

// ---------------- MFMA scan, v-split x2: grid = B*H*2, 8 waves --------------------
__global__ __launch_bounds__(512) void scan_mfma(
    const unsigned short* __restrict__ qt, const unsigned short* __restrict__ uT,
    const unsigned short* __restrict__ evb, const unsigned short* __restrict__ ewb,
    const unsigned short* __restrict__ intra, const float* __restrict__ wlast,
    unsigned short* __restrict__ attn_o, unsigned short* __restrict__ snapb) {
  const int blk = blockIdx.x;
  const int bh = blk >> 1, vh = blk & 1;
  const int b = bh >> 4, h = bh & 15;
  const int v0 = vh * 64;
  const int tid = threadIdx.x, wave = tid >> 6, lane = tid & 63;
  const int l15 = lane & 15, l4 = lane >> 4;
  __shared__ __align__(16) unsigned short ewS[8192];  // [64 c][128 k] swzA
  __shared__ __align__(16) unsigned short qtS[8192];  // [64 c][128 k] swzA
  __shared__ __align__(16) unsigned short uTS[8192];  // [128 k][64 c] swzB
  __shared__ __align__(16) unsigned short iaS[4096];  // [64 c][64 j]  swzB
  __shared__ __align__(16) unsigned short evS[4096];  // [64 c][64 v]  swzB (slice)
  __shared__ __align__(16) unsigned short sBT[8192];  // [64 v][128 k] swzA (S^T slice)
  __shared__ __align__(16) unsigned short dBT[4096];  // [64 v][64 c]  swzB (delta^T)

  f32x4 S[4] = {};
  {
    int4 z = {0, 0, 0, 0};
    stsv16B(sBT, tid * 32, z);
    stsv16B(sBT, tid * 32 + 16, z);
  }

  const int sr = tid >> 3;           // 0..63
  const int sk0 = (tid & 7) * 16;    // 128-wide col base
  const int sc0 = (tid & 7) * 8;     // 64-wide col base
  const int tk = tid >> 3;           // uT rows tk, tk+64
  const int wloff = 16 * wave + 4 * l4;
  int4 rEw0, rEw1, rQt0, rQt1, rEv, rUT0, rUT1, rIa;
  float4 rWlN, rWlC;

#define STAGE_LOAD(CB, IB, NN)                                                    \
  rEw0 = *(const int4*)(ewb + (CB) + sr * 128 + sk0);                             \
  rEw1 = *(const int4*)(ewb + (CB) + sr * 128 + sk0 + 8);                         \
  rQt0 = *(const int4*)(qt + (CB) + sr * 128 + sk0);                              \
  rQt1 = *(const int4*)(qt + (CB) + sr * 128 + sk0 + 8);                          \
  rEv = *(const int4*)(evb + (CB) + sr * 128 + v0 + sc0);                         \
  rUT0 = *(const int4*)(uT + (CB) + (size_t)tk * 64 + sc0);                       \
  rUT1 = *(const int4*)(uT + (CB) + (size_t)(tk + 64) * 64 + sc0);                \
  rIa = *(const int4*)(intra + (IB) + sr * 64 + sc0);                             \
  rWlN = ld4(wlast + ((size_t)bh * 64 + (NN)) * 128 + wloff);

#define STAGE_WRITE()                                                             \
  stsv16B(ewS, swzA(sr, sk0 * 2), rEw0);                                          \
  stsv16B(ewS, swzA(sr, sk0 * 2 + 16), rEw1);                                     \
  stsv16B(qtS, swzA(sr, sk0 * 2), rQt0);                                          \
  stsv16B(qtS, swzA(sr, sk0 * 2 + 16), rQt1);                                     \
  stsv16B(evS, swzB(sr, sc0 * 2), rEv);                                           \
  stsv16B(iaS, swzB(sr, sc0 * 2), rIa);                                           \
  stsv16B(uTS, swzB(tk, sc0 * 2), rUT0);                                          \
  stsv16B(uTS, swzB(tk + 64, sc0 * 2), rUT1);

  {
    const size_t cb0 = (size_t)bh * 64 * 8192;
    const size_t ib0 = (size_t)bh * 64 * 4096;
    STAGE_LOAD(cb0, ib0, 0);
    STAGE_WRITE();
    rWlC = rWlN;
  }
  __syncthreads();

  const int m = wave & 3, ntb = (wave >> 2) * 2;
  const int arow = 16 * m + l15;
  const int krow = 16 * wave + l15;

  for (int n = 0; n < NCc; ++n) {
    const size_t cb = ((size_t)bh * 64 + n) * 8192;
    const size_t ib = ((size_t)bh * 64 + n) * 4096;
    // ---- Phase A: prefetch n+1; delta = ev - ew@S -> dBT ----
    if (n < 63) { STAGE_LOAD(cb + 8192, ib + 4096, n + 1); }
    bf16x8 aEw[4];
#pragma unroll
    for (int ks = 0; ks < 4; ++ks) aEw[ks] = ldsv8(ewS, swzA(arow, 16 * l4 + 64 * ks));
#pragma unroll
    for (int i = 0; i < 2; ++i) {
      int vl = 16 * (ntb + i) + l15;
      f32x4 p = {};
#pragma unroll
      for (int ks = 0; ks < 4; ++ks)
        p = __builtin_amdgcn_mfma_f32_16x16x32_bf16(aEw[ks], ldsv8(sBT, swzA(vl, 16 * l4 + 64 * ks)), p, 0, 0, 0);
      float d[4];
#pragma unroll
      for (int r = 0; r < 4; ++r) {
        int c = 16 * m + 4 * l4 + r;
        d[r] = bf2f(lds16(evS, swzB(c, 2 * vl))) - p[r];
      }
      uint2 pk;
      pk.x = (unsigned)f2bf(d[0]) | ((unsigned)f2bf(d[1]) << 16);
      pk.y = (unsigned)f2bf(d[2]) | ((unsigned)f2bf(d[3]) << 16);
      stsv8B(dBT, swzB(vl, (16 * m + 4 * l4) * 2), pk);
    }
    __syncthreads();
    // ---- Phase B1: o = qt@S + ia@delta; S = wl*(S + uT@delta) ----
    bf16x8 aQt[4], aIa[2], aU[2];
#pragma unroll
    for (int ks = 0; ks < 4; ++ks) aQt[ks] = ldsv8(qtS, swzA(arow, 16 * l4 + 64 * ks));
#pragma unroll
    for (int ks = 0; ks < 2; ++ks) aIa[ks] = ldsv8(iaS, swzB(arow, 16 * l4 + 64 * ks));
#pragma unroll
    for (int ks = 0; ks < 2; ++ks) aU[ks] = ldsv8(uTS, swzB(krow, 16 * l4 + 64 * ks));
#pragma unroll
    for (int i = 0; i < 2; ++i) {
      int vl = 16 * (ntb + i) + l15;
      f32x4 o = {};
#pragma unroll
      for (int ks = 0; ks < 4; ++ks)
        o = __builtin_amdgcn_mfma_f32_16x16x32_bf16(aQt[ks], ldsv8(sBT, swzA(vl, 16 * l4 + 64 * ks)), o, 0, 0, 0);
#pragma unroll
      for (int ks = 0; ks < 2; ++ks)
        o = __builtin_amdgcn_mfma_f32_16x16x32_bf16(aIa[ks], ldsv8(dBT, swzB(vl, 16 * l4 + 64 * ks)), o, 0, 0, 0);
#pragma unroll
      for (int r = 0; r < 4; ++r) {
        int c = 16 * m + 4 * l4 + r;
        int t = n * 64 + c;
        attn_o[((size_t)(b * Tc + t) * Hc + h) * Kc + v0 + vl] = f2bf(o[r]);
      }
    }
    float wlv[4] = {rWlC.x, rWlC.y, rWlC.z, rWlC.w};
#pragma unroll
    for (int nt4 = 0; nt4 < 4; ++nt4) {
      int vl = 16 * nt4 + l15;
      f32x4 U = {};
#pragma unroll
      for (int ks = 0; ks < 2; ++ks)
        U = __builtin_amdgcn_mfma_f32_16x16x32_bf16(aU[ks], ldsv8(dBT, swzB(vl, 16 * l4 + 64 * ks)), U, 0, 0, 0);
#pragma unroll
      for (int r = 0; r < 4; ++r) S[nt4][r] = wlv[r] * (S[nt4][r] + U[r]);
    }
    __syncthreads();
    // ---- Phase B2: S -> sBT, staging writes, snapshot ----
#pragma unroll
    for (int nt4 = 0; nt4 < 4; ++nt4) {
      int vl = 16 * nt4 + l15;
      uint2 pk;
      pk.x = (unsigned)f2bf(S[nt4][0]) | ((unsigned)f2bf(S[nt4][1]) << 16);
      pk.y = (unsigned)f2bf(S[nt4][2]) | ((unsigned)f2bf(S[nt4][3]) << 16);
      stsv8B(sBT, swzA(vl, (16 * wave + 4 * l4) * 2), pk);
    }
    if (n < 63) { STAGE_WRITE(); rWlC = rWlN; }
    if ((n & 3) == 3) {
      int ns = n >> 2;
      size_t sb = (size_t)((ns * Bc + b) * Hc + h) * 16384;
#pragma unroll
      for (int nt4 = 0; nt4 < 4; ++nt4)
#pragma unroll
        for (int r = 0; r < 4; ++r) {
          int k = 16 * wave + 4 * l4 + r;
          snapb[sb + (size_t)k * 128 + v0 + 16 * nt4 + l15] = f2bf(S[nt4][r]);
        }
    }
    __syncthreads();
  }
#undef STAGE_LOAD
#undef STAGE_WRITE
}

// ---------------- snapshot helpers ----------------
__global__ void sdw_mul_bf16(const float* __restrict__ snap_down, const float* __restrict__ w,
                             unsigned short* __restrict__ sdwb) {
  int i = (blockIdx.x * 256 + threadIdx.x) * 4;
  float4 v = ld4(snap_down + i);
  int k = i & 16383;
  float4 ww = ld4(w + k);
  ushort4 o;
  o.x = f2bf(v.x * ww.x); o.y = f2bf(v.y * ww.y); o.z = f2bf(v.z * ww.z); o.w = f2bf(v.w * ww.w);
  *reinterpret_cast<ushort4*>(sdwb + i) = o;
}

__global__ __launch_bounds__(256) void snap_scale_kernel(const unsigned short* __restrict__ snapb,
                                                         float* __restrict__ scale) {
  int r = blockIdx.x;
  const unsigned short* row = snapb + (size_t)r * 16384;
  float s = 0.f;
  for (int ii = threadIdx.x * 4; ii < 16384; ii += 1024) {
    float4 x = ld4(row + ii);
    s += x.x * x.x + x.y * x.y + x.z * x.z + x.w * x.w;
  }
#pragma unroll
  for (int off = 32; off > 0; off >>= 1) s += __shfl_down(s, off, 64);
  __shared__ float red[4];
  if ((threadIdx.x & 63) == 0) red[threadIdx.x >> 6] = s;
  __syncthreads();
  if (threadIdx.x == 0) {
    float tot = red[0] + red[1] + red[2] + red[3];
    scale[r] = rsqrtf(tot * (1.f / 16384.f) + 1e-6f);
  }
}

__global__ void snap_reduce_scatter(const float* __restrict__ part,
                                    const float* __restrict__ scale,
                                    float* __restrict__ outp) {
  int idx = blockIdx.x * 256 + threadIdx.x;
  int l = idx & 127;
  int hh = (idx >> 7) & 15;
  int ns = (idx >> 11) & 15;
  int bb = idx >> 15;
  int r = (ns * Bc + bb) * Hc + hh;
  float s = 0.f;
#pragma unroll
  for (int z = 0; z < 16; ++z) s += part[(size_t)z * 65536 + r * 128 + l];
  outp[idx] = s * scale[r];
}

// ---------------- final rmsnorm * sigmoid(gate): wave-per-row ----------
__global__ __launch_bounds__(256) void out_norm_gate(unsigned short* __restrict__ attn_io,
                                                     const unsigned short* __restrict__ gate_raw,
                                                     const float* __restrict__ bgb,
                                                     const float* __restrict__ o_norm_w) {
  const int wave = threadIdx.x >> 6, lane = threadIdx.x & 63;
  const int blk = blockIdx.x * 4 + wave;  // (b*T + t)*H + h
  const int h = blk & 15;
  const size_t row = (size_t)(blk >> 4);
  const size_t base = (size_t)blk * Kc;
  ushort2 xv = *reinterpret_cast<const ushort2*>(attn_io + base + 2 * lane);
  float x0 = bf2f(xv.x), x1 = bf2f(xv.y);
  float ss = x0 * x0 + x1 * x1;
#pragma unroll
  for (int off = 32; off > 0; off >>= 1) ss += __shfl_xor(ss, off, 64);
  float inv = rsqrtf(ss * (1.f / 128.f) + 1e-6f);
  const int p0 = h * Kc + 2 * lane;
  ushort2 gv = *reinterpret_cast<const ushort2*>(gate_raw + row * Pc + p0);
  float g0 = bf2f(gv.x) + bgb[p0];
  float g1 = bf2f(gv.y) + bgb[p0 + 1];
  float o0 = x0 * inv * o_norm_w[2 * lane] * fsig(g0);
  float o1 = x1 * inv * o_norm_w[2 * lane + 1] * fsig(g1);
  ushort2 ov; ov.x = f2bf(o0); ov.y = f2bf(o1);
  *reinterpret_cast<ushort2*>(attn_io + base + 2 * lane) = ov;
}

// ---------------- launch ----------------
extern "C" void kernel_launch(void* const* d_in, const int* in_sizes, int n_in,
                              void* d_out, int out_size, void* d_ws, size_t ws_size,
                              hipStream_t stream) {
  (void)in_sizes; (void)n_in;
  const float* x        = (const float*)d_in[0];
  const float* Wq       = (const float*)d_in[1];
  const float* Wk       = (const float*)d_in[2];
  const float* Wv       = (const float*)d_in[3];
  const float* conv_q   = (const float*)d_in[4];
  const float* conv_k   = (const float*)d_in[5];
  const float* conv_v   = (const float*)d_in[6];
  const float* A_log    = (const float*)d_in[7];
  const float* dt_bias  = (const float*)d_in[8];
  const float* Wfa      = (const float*)d_in[9];
  const float* Wfb      = (const float*)d_in[10];
  const float* Wb       = (const float*)d_in[11];
  const float* Wga      = (const float*)d_in[12];
  const float* Wgb      = (const float*)d_in[13];
  const float* bgb      = (const float*)d_in[14];
  const float* o_norm_w = (const float*)d_in[15];
  const float* Wo       = (const float*)d_in[16];
  const float* snap_nw  = (const float*)d_in[17];
  const float* snap_down= (const float*)d_in[18];

  const size_t MP2 = (size_t)Mc * Pc * 2;
  const size_t NEED = 6 * MP2
                    + 2 * (size_t)Mc * Kc * 4
                    + (size_t)Mc * Hc * 4
                    + (size_t)Bc * Hc * NCc * Kc * 4;
  if (ws_size < NEED + 4096) {
    hipMemsetAsync(d_out, 0, (size_t)out_size * 4, stream);
    return;
  }
  char* w = (char*)d_ws;
  auto alloc = [&](size_t bytes) {
    char* r = w;
    w += (bytes + 255) & ~(size_t)255;
    return r;
  };
  unsigned short* q_lin = (unsigned short*)alloc(MP2);  // q,k,v contiguous (QKV-fused out)
  unsigned short* k_lin = (unsigned short*)alloc(MP2);
  unsigned short* v_lin = (unsigned short*)alloc(MP2);
  unsigned short* g_raw = (unsigned short*)alloc(MP2);
  unsigned short* evb   = (unsigned short*)alloc(MP2);
  unsigned short* ewb   = (unsigned short*)alloc(MP2);
  float* fa    = (float*)alloc((size_t)Mc * Kc * 4);    // fab; later betap (8192x128 f32)
  float* ga    = (float*)alloc((size_t)Mc * Kc * 4);
  float* betab = (float*)alloc((size_t)Mc * Hc * 4);    // unused (kept for NEED layout)
  float* wlast = (float*)alloc((size_t)Bc * Hc * NCc * Kc * 4);
  (void)betab;

  unsigned short* qt = (unsigned short*)d_out;
  unsigned short* u_ = (unsigned short*)((char*)d_out + MP2);

  unsigned short* xb    = evb;
  unsigned short* Wqb   = ewb;                 // [Wq;Wk;Wv] contiguous (6144 rows)
  unsigned short* Wkb   = ewb + 4194304;
  unsigned short* Wvb   = ewb + 8388608;
  unsigned short* Wfab  = ewb + 12582912;
  unsigned short* Wgab  = ewb + 12845056;
  unsigned short* Wfbb  = ewb + 13107200;      // ends 13,369,344
  unsigned short* Wbp   = ewb + 13369344;      // padded Wb: 128x2048 bf16, ends 13,631,488
  unsigned short* fab   = (unsigned short*)fa;
  unsigned short* gab   = (unsigned short*)ga;
  float* betap          = fa;                  // 8192x128 f32 = 4MB exact (fa dead after g_raw GEMM)

  unsigned short* intra = q_lin;
  unsigned short* Wob   = q_lin + 8388608;
  unsigned short* Wgbb  = q_lin + 12582912;
  unsigned short* attn  = k_lin;
  unsigned short* gate_raw = g_raw;
  unsigned short* snapb = v_lin;
  unsigned short* sdwb  = v_lin + (size_t)512 * 16384;
  float* partial   = (float*)ewb;
  float* snapscale = (float*)(ewb + 4400000);

  float* y = (float*)d_out;
  float* snaps_out = (float*)d_out + (size_t)Bc * Tc * Dc;

  // 0) casts (+ zero-padded Wb for MFMA beta)
  cast_f32_bf16<<<16384, 256, 0, stream>>>(x, xb, Mc * Dc);
  cast_f32_bf16<<<4096, 256, 0, stream>>>(Wq, Wqb, Pc * Dc);
  cast_f32_bf16<<<4096, 256, 0, stream>>>(Wk, Wkb, Pc * Dc);
  cast_f32_bf16<<<4096, 256, 0, stream>>>(Wv, Wvb, Pc * Dc);
  cast_f32_bf16<<<256, 256, 0, stream>>>(Wfa, Wfab, Kc * Dc);
  cast_f32_bf16<<<256, 256, 0, stream>>>(Wga, Wgab, Kc * Dc);
  cast_f32_bf16<<<256, 256, 0, stream>>>(Wfb, Wfbb, Pc * Kc);
  hipMemsetAsync(Wbp, 0, (size_t)128 * 2048 * 2, stream);
  cast_f32_bf16<<<32, 256, 0, stream>>>(Wb, Wbp, Hc * Dc);  // rows 0..15 valid

  // 1) input GEMMs (bf16 MFMA): fused QKV + low-rank paths
  gemm_nt_mfma_qkv<<<dim3(64, 48), 256, 0, stream>>>(xb, Wqb, q_lin, Dc);
  gemm_nt_mfma<unsigned short><<<dim3(64, 1), 256, 0, stream>>>(xb, Wfab, fab, Kc, Dc);
  gemm_nt_mfma<unsigned short><<<dim3(64, 1), 256, 0, stream>>>(xb, Wgab, gab, Kc, Dc);
  gemm_nt_mfma<unsigned short><<<dim3(64, 16), 256, 0, stream>>>(fab, Wfbb, g_raw, Pc, Kc);
  // beta via padded MFMA (fa/fab dead now; betap overlays fa region)
  gemm_nt_mfma<float><<<dim3(64, 1), 256, 0, stream>>>(xb, Wbp, betap, 128, Dc);

  // 2) chunk prep (wave-per-chunk, fast transcendentals; beta stride 128)
  chunk_prep<<<Bc * Hc * NCc / 4, 256, 0, stream>>>(q_lin, k_lin, v_lin, g_raw, betap, conv_q,
                                                    conv_k, conv_v, A_log, dt_bias, qt, u_, evb,
                                                    ewb, wlast);

  // 3) late casts into q_lin's dead tail
  cast_f32_bf16<<<4096, 256, 0, stream>>>(Wo, Wob, Dc * Pc);
  cast_f32_bf16<<<256, 256, 0, stream>>>(Wgb, Wgbb, Pc * Kc);

  // chunk solve (also transposes u -> uT in place)
  chunk_solve_mfma<<<Bc * Hc * NCc, 256, 0, stream>>>(qt, u_, evb, ewb, intra);

  // 4) gate projection
  gemm_nt_mfma<unsigned short><<<dim3(64, 16), 256, 0, stream>>>(gab, Wgbb, gate_raw, Pc, Kc);

  // 5) MFMA scan, v-split x2 (u_ holds uT)
  scan_mfma<<<Bc * Hc * 2, 512, 0, stream>>>(qt, u_, evb, ewb, intra, wlast, attn, snapb);

  // 6) snapshots
  sdw_mul_bf16<<<2048, 256, 0, stream>>>(snap_down, snap_nw, sdwb);
  snap_scale_kernel<<<512, 256, 0, stream>>>(snapb, snapscale);
  gemm_nt_mfma_sk<<<dim3(4, 1, 16), 256, 0, stream>>>(snapb, sdwb, partial, 128, 16384, 1024, 512);
  snap_reduce_scatter<<<256, 256, 0, stream>>>(partial, snapscale, snaps_out);

  // 7) output norm*gate + final projection
  out_norm_gate<<<Mc * Hc / 4, 256, 0, stream>>>(attn, gate_raw, bgb, o_norm_w);
  gemm_nt_mfma<float><<<dim3(64, 16), 256, 0, stream>>>(attn, Wob, y, Dc, Pc);
}

// Round 11
// 984.389 us; speedup vs baseline: 8.1240x; 1.0341x over previous
//
#include <hip/hip_runtime.h>

// ---------------- problem constants ----------------
constexpr int Bc   = 2;
constexpr int Tc   = 4096;
constexpr int Dc   = 2048;
constexpr int Hc   = 16;
constexpr int Kc   = 128;
constexpr int Pc   = Hc * Kc;     // 2048
constexpr int Cc   = 64;          // chunk size
constexpr int NCc  = Tc / Cc;     // 64 chunks
constexpr int Mc   = Bc * Tc;     // 8192 rows
constexpr int LATc = 128;

// ---------------- helpers ----------------
__device__ __forceinline__ float bf2f(unsigned short u) {
  unsigned int x = ((unsigned int)u) << 16;
  return __builtin_bit_cast(float, x);
}
__device__ __forceinline__ unsigned short f2bf(float f) {
  unsigned int x = __builtin_bit_cast(unsigned int, f);
  x += 0x7fffu + ((x >> 16) & 1u);
  return (unsigned short)(x >> 16);
}
__device__ __forceinline__ float4 ld4(const float* p) {
  return *reinterpret_cast<const float4*>(p);
}
__device__ __forceinline__ float4 ld4(const unsigned short* p) {
  ushort4 u = *reinterpret_cast<const ushort4*>(p);
  return make_float4(bf2f(u.x), bf2f(u.y), bf2f(u.z), bf2f(u.w));
}
__device__ __forceinline__ void st1(float* p, float v) { *p = v; }
__device__ __forceinline__ void st1(unsigned short* p, float v) { *p = f2bf(v); }

// fast transcendentals (native v_exp_f32 / v_log_f32 / v_rcp_f32)
__device__ __forceinline__ float fsig(float x) {
  return __fdividef(1.f, 1.f + __expf(-x));
}
__device__ __forceinline__ float fsoftplus(float g) {
  return (g > 20.f) ? g : __logf(1.f + __expf(g));
}

typedef __attribute__((ext_vector_type(8))) short bf16x8;
typedef __attribute__((ext_vector_type(4))) float f32x4;

// LDS swizzles: rows of stride 256B (swzA) and 128B (swzB); byte ^= ((row&7)<<4)
__device__ __forceinline__ int swzA(int row, int kbyte) { return row * 256 + (kbyte ^ ((row & 7) << 4)); }
__device__ __forceinline__ int swzB(int row, int kbyte) { return row * 128 + (kbyte ^ ((row & 7) << 4)); }
__device__ __forceinline__ bf16x8 ldsv8(const unsigned short* base, int byteoff) {
  return *reinterpret_cast<const bf16x8*>(reinterpret_cast<const char*>(base) + byteoff);
}
__device__ __forceinline__ void stsv16B(unsigned short* base, int byteoff, int4 v) {
  *reinterpret_cast<int4*>(reinterpret_cast<char*>(base) + byteoff) = v;
}
__device__ __forceinline__ void stsv8B(unsigned short* base, int byteoff, uint2 v) {
  *reinterpret_cast<uint2*>(reinterpret_cast<char*>(base) + byteoff) = v;
}
__device__ __forceinline__ unsigned short lds16(const unsigned short* base, int byteoff) {
  return *reinterpret_cast<const unsigned short*>(reinterpret_cast<const char*>(base) + byteoff);
}

// bijective XCD-aware block swizzle (T1); identity unless nwg%8==0 && nwg>=16
__device__ __forceinline__ int xcd_swz(int id, int nwg) {
  if ((nwg & 7) != 0 || nwg < 16) return id;
  return (id & 7) * (nwg >> 3) + (id >> 3);
}

// ---------------- f32 -> bf16 cast ----------------
__global__ void cast_f32_bf16(const float* __restrict__ in, unsigned short* __restrict__ out,
                              int n) {
  int i = (blockIdx.x * 256 + threadIdx.x) * 4;
  if (i < n) {
    float4 v = ld4(in + i);
    ushort4 o;
    o.x = f2bf(v.x); o.y = f2bf(v.y); o.z = f2bf(v.z); o.w = f2bf(v.w);
    *reinterpret_cast<ushort4*>(out + i) = o;
  }
}

// ---------------- bf16 MFMA NT GEMM (128x128 tile, m97 structure) ------
// tile mapping: XCD swizzle (contiguous range per XCD) + GROUP_M=8 rasterization
// (m fastest within an 8 x gridN group) -> per-XCD L2 working set = 4MB A-panel + B stream.
// Requires gridDim.x (M-tiles) % 8 == 0.
__device__ __forceinline__ void gload_lds16(const unsigned short* g, unsigned short* l) {
  __builtin_amdgcn_global_load_lds(
      (const __attribute__((address_space(1))) void*)g,
      (__attribute__((address_space(3))) void*)l, 16, 0, 0);
}

__device__ __forceinline__ void tile_map(int& m0, int& n0) {
  int id = blockIdx.y * gridDim.x + blockIdx.x;
  id = xcd_swz(id, gridDim.x * gridDim.y);
  const int bpg = gridDim.y << 3;     // 8 m-tiles per group
  int grp = id / bpg, rem = id % bpg;
  m0 = ((grp << 3) + (rem & 7)) * 128;
  n0 = (rem >> 3) * 128;
}

template <typename OT>
__global__ __launch_bounds__(256) void gemm_nt_mfma(const unsigned short* __restrict__ A,
                                                    const unsigned short* __restrict__ Bm,
                                                    OT* __restrict__ Out,
                                                    int Ndim, int Kd) {
  __shared__ __align__(16) unsigned short As[128 * 32];
  __shared__ __align__(16) unsigned short Bs[128 * 32];
  int m0, n0;
  tile_map(m0, n0);
  const int tid = threadIdx.x;
  const int wave = tid >> 6;
  const int lane = tid & 63;
  const int wr = wave >> 1, wc = wave & 1;
  const int l15 = lane & 15, l4 = lane >> 4;
  f32x4 acc[4][4] = {};

  for (int k0 = 0; k0 < Kd; k0 += 32) {
#pragma unroll
    for (int i = 0; i < 2; ++i) {
      int e = (wave * 2 + i) * 512 + lane * 8;
      int r = e >> 5, c = e & 31;
      gload_lds16(&A[(size_t)(m0 + r) * Kd + k0 + c], &As[(wave * 2 + i) * 512]);
      gload_lds16(&Bm[(size_t)(n0 + r) * Kd + k0 + c], &Bs[(wave * 2 + i) * 512]);
    }
    __syncthreads();
    bf16x8 af[4], bfr[4];
#pragma unroll
    for (int m = 0; m < 4; ++m)
      af[m] = *reinterpret_cast<const bf16x8*>(&As[(wr * 64 + m * 16 + l15) * 32 + l4 * 8]);
#pragma unroll
    for (int n = 0; n < 4; ++n)
      bfr[n] = *reinterpret_cast<const bf16x8*>(&Bs[(wc * 64 + n * 16 + l15) * 32 + l4 * 8]);
#pragma unroll
    for (int m = 0; m < 4; ++m)
#pragma unroll
      for (int n = 0; n < 4; ++n)
        acc[m][n] = __builtin_amdgcn_mfma_f32_16x16x32_bf16(af[m], bfr[n], acc[m][n], 0, 0, 0);
    __syncthreads();
  }
#pragma unroll
  for (int m = 0; m < 4; ++m)
#pragma unroll
    for (int n = 0; n < 4; ++n)
#pragma unroll
      for (int r = 0; r < 4; ++r) {
        int row = m0 + wr * 64 + m * 16 + l4 * 4 + r;
        int col = n0 + wc * 64 + n * 16 + l15;
        st1(&Out[(size_t)row * Ndim + col], acc[m][n][r]);
      }
}

// ---- fused QKV variant: B = [Wq;Wk;Wv] contiguous (6144 rows); output col>>11 picks
// one of 3 contiguous [Mc][2048] buffers starting at Out. grid (64, 48).
__global__ __launch_bounds__(256) void gemm_nt_mfma_qkv(const unsigned short* __restrict__ A,
                                                        const unsigned short* __restrict__ Bm,
                                                        unsigned short* __restrict__ Out,
                                                        int Kd) {
  __shared__ __align__(16) unsigned short As[128 * 32];
  __shared__ __align__(16) unsigned short Bs[128 * 32];
  int m0, n0;
  tile_map(m0, n0);
  const int tid = threadIdx.x;
  const int wave = tid >> 6;
  const int lane = tid & 63;
  const int wr = wave >> 1, wc = wave & 1;
  const int l15 = lane & 15, l4 = lane >> 4;
  f32x4 acc[4][4] = {};

  for (int k0 = 0; k0 < Kd; k0 += 32) {
#pragma unroll
    for (int i = 0; i < 2; ++i) {
      int e = (wave * 2 + i) * 512 + lane * 8;
      int r = e >> 5, c = e & 31;
      gload_lds16(&A[(size_t)(m0 + r) * Kd + k0 + c], &As[(wave * 2 + i) * 512]);
      gload_lds16(&Bm[(size_t)(n0 + r) * Kd + k0 + c], &Bs[(wave * 2 + i) * 512]);
    }
    __syncthreads();
    bf16x8 af[4], bfr[4];
#pragma unroll
    for (int m = 0; m < 4; ++m)
      af[m] = *reinterpret_cast<const bf16x8*>(&As[(wr * 64 + m * 16 + l15) * 32 + l4 * 8]);
#pragma unroll
    for (int n = 0; n < 4; ++n)
      bfr[n] = *reinterpret_cast<const bf16x8*>(&Bs[(wc * 64 + n * 16 + l15) * 32 + l4 * 8]);
#pragma unroll
    for (int m = 0; m < 4; ++m)
#pragma unroll
      for (int n = 0; n < 4; ++n)
        acc[m][n] = __builtin_amdgcn_mfma_f32_16x16x32_bf16(af[m], bfr[n], acc[m][n], 0, 0, 0);
    __syncthreads();
  }
  // output: buffer index = col>>11, local col = col&2047
  unsigned short* dst = Out + (size_t)(n0 >> 11) * ((size_t)Mc * 2048);
  const int cbase = n0 & 2047;
#pragma unroll
  for (int m = 0; m < 4; ++m)
#pragma unroll
    for (int n = 0; n < 4; ++n)
#pragma unroll
      for (int r = 0; r < 4; ++r) {
        int row = m0 + wr * 64 + m * 16 + l4 * 4 + r;
        int col = cbase + wc * 64 + n * 16 + l15;
        dst[(size_t)row * 2048 + col] = f2bf(acc[m][n][r]);
      }
}

// ---- splitK variant ----
__global__ __launch_bounds__(256) void gemm_nt_mfma_sk(const unsigned short* __restrict__ A,
                                                       const unsigned short* __restrict__ Bm,
                                                       float* __restrict__ Part,
                                                       int Ndim, int Kd, int kslice, int Mtot) {
  __shared__ __align__(16) unsigned short As[128 * 32];
  __shared__ __align__(16) unsigned short Bs[128 * 32];
  const int m0 = blockIdx.x * 128;
  const int n0 = blockIdx.y * 128;
  const int kz = blockIdx.z * kslice;
  const int tid = threadIdx.x;
  const int wave = tid >> 6;
  const int lane = tid & 63;
  const int wr = wave >> 1, wc = wave & 1;
  const int l15 = lane & 15, l4 = lane >> 4;
  f32x4 acc[4][4] = {};

  for (int k0 = kz; k0 < kz + kslice; k0 += 32) {
#pragma unroll
    for (int i = 0; i < 2; ++i) {
      int e = (wave * 2 + i) * 512 + lane * 8;
      int r = e >> 5, c = e & 31;
      gload_lds16(&A[(size_t)(m0 + r) * Kd + k0 + c], &As[(wave * 2 + i) * 512]);
      gload_lds16(&Bm[(size_t)(n0 + r) * Kd + k0 + c], &Bs[(wave * 2 + i) * 512]);
    }
    __syncthreads();
    bf16x8 af[4], bfr[4];
#pragma unroll
    for (int m = 0; m < 4; ++m)
      af[m] = *reinterpret_cast<const bf16x8*>(&As[(wr * 64 + m * 16 + l15) * 32 + l4 * 8]);
#pragma unroll
    for (int n = 0; n < 4; ++n)
      bfr[n] = *reinterpret_cast<const bf16x8*>(&Bs[(wc * 64 + n * 16 + l15) * 32 + l4 * 8]);
#pragma unroll
    for (int m = 0; m < 4; ++m)
#pragma unroll
      for (int n = 0; n < 4; ++n)
        acc[m][n] = __builtin_amdgcn_mfma_f32_16x16x32_bf16(af[m], bfr[n], acc[m][n], 0, 0, 0);
    __syncthreads();
  }
  float* out = Part + (size_t)blockIdx.z * Mtot * Ndim;
#pragma unroll
  for (int m = 0; m < 4; ++m)
#pragma unroll
    for (int n = 0; n < 4; ++n)
#pragma unroll
      for (int r = 0; r < 4; ++r) {
        int row = m0 + wr * 64 + m * 16 + l4 * 4 + r;
        int col = n0 + wc * 64 + n * 16 + l15;
        out[(size_t)row * Ndim + col] = acc[m][n][r];
      }
}

// ---------------- chunk prep: one WAVE per chunk, fast transcendentals ----------------
// grid: Bc*Hc*NCc/4 = 512 blocks x 256 threads (4 waves = 4 chunks)
// beta_lin is betap[Mc][128] (padded MFMA output; head h at col h)
__global__ __launch_bounds__(256) void chunk_prep(
    const unsigned short* __restrict__ q_lin, const unsigned short* __restrict__ k_lin,
    const unsigned short* __restrict__ v_lin, const unsigned short* __restrict__ g_raw,
    const float* __restrict__ beta_lin, const float* __restrict__ conv_q,
    const float* __restrict__ conv_k, const float* __restrict__ conv_v,
    const float* __restrict__ A_log, const float* __restrict__ dt_bias,
    unsigned short* __restrict__ qt, unsigned short* __restrict__ u_,
    unsigned short* __restrict__ bv, unsigned short* __restrict__ bw,
    float* __restrict__ wlast) {
  const int wave = threadIdx.x >> 6, lane = threadIdx.x & 63;
  const int cid = blockIdx.x * 4 + wave;  // (b*H+h)*NC + n
  const int n = cid & 63;
  const int h = (cid >> 6) & 15;
  const int b = cid >> 10;
  const int k0 = 2 * lane;
  const int p = h * Kc + k0;
  float cq[2][4], ck[2][4], cv[2][4];
#pragma unroll
  for (int s = 0; s < 2; ++s)
#pragma unroll
    for (int j = 0; j < 4; ++j) {
      cq[s][j] = conv_q[(p + s) * 4 + j];
      ck[s][j] = conv_k[(p + s) * 4 + j];
      cv[s][j] = conv_v[(p + s) * 4 + j];
    }
  const float aneg = -__expf(A_log[h]);
  const float db0 = dt_bias[p], db1 = dt_bias[p + 1];
  float cum0 = 0.f, cum1 = 0.f;
  const int t0 = n * Cc;
  float wq[2][3] = {}, wk[2][3] = {}, wv[2][3] = {};
#pragma unroll
  for (int d = 0; d < 3; ++d) {
    int ts = t0 - 3 + d;
    if (ts >= 0) {
      size_t o = ((size_t)(b * Tc + ts)) * Pc + p;
      ushort2 q2 = *(const ushort2*)(q_lin + o);
      ushort2 k2 = *(const ushort2*)(k_lin + o);
      ushort2 v2 = *(const ushort2*)(v_lin + o);
      wq[0][d] = bf2f(q2.x); wq[1][d] = bf2f(q2.y);
      wk[0][d] = bf2f(k2.x); wk[1][d] = bf2f(k2.y);
      wv[0][d] = bf2f(v2.x); wv[1][d] = bf2f(v2.y);
    }
  }
  for (int c = 0; c < Cc; ++c) {
    const int t = t0 + c;
    size_t off = ((size_t)(b * Tc + t)) * Pc + p;
    ushort2 q2 = *(const ushort2*)(q_lin + off);
    ushort2 k2 = *(const ushort2*)(k_lin + off);
    ushort2 v2 = *(const ushort2*)(v_lin + off);
    ushort2 g2 = *(const ushort2*)(g_raw + off);
    float nq[2] = {bf2f(q2.x), bf2f(q2.y)};
    float nk[2] = {bf2f(k2.x), bf2f(k2.y)};
    float nv[2] = {bf2f(v2.x), bf2f(v2.y)};
    float qv[2], kv[2], vv[2];
#pragma unroll
    for (int s = 0; s < 2; ++s) {
      qv[s] = cq[s][0] * wq[s][0] + cq[s][1] * wq[s][1] + cq[s][2] * wq[s][2] + cq[s][3] * nq[s];
      kv[s] = ck[s][0] * wk[s][0] + ck[s][1] * wk[s][1] + ck[s][2] * wk[s][2] + ck[s][3] * nk[s];
      vv[s] = cv[s][0] * wv[s][0] + cv[s][1] * wv[s][1] + cv[s][2] * wv[s][2] + cv[s][3] * nv[s];
      wq[s][0] = wq[s][1]; wq[s][1] = wq[s][2]; wq[s][2] = nq[s];
      wk[s][0] = wk[s][1]; wk[s][1] = wk[s][2]; wk[s][2] = nk[s];
      wv[s][0] = wv[s][1]; wv[s][1] = wv[s][2]; wv[s][2] = nv[s];
      qv[s] = qv[s] * fsig(qv[s]);  // silu
      kv[s] = kv[s] * fsig(kv[s]);
      vv[s] = vv[s] * fsig(vv[s]);
    }
    float a = qv[0] * qv[0] + qv[1] * qv[1];
    float bb = kv[0] * kv[0] + kv[1] * kv[1];
#pragma unroll
    for (int off2 = 32; off2 > 0; off2 >>= 1) {
      a += __shfl_xor(a, off2, 64);
      bb += __shfl_xor(bb, off2, 64);
    }
    float rq = rsqrtf(a + 1e-12f) * 0.08838834764831845f;  // * K^-0.5
    float rk = rsqrtf(bb + 1e-12f);
    float g0 = bf2f(g2.x) + db0, g1 = bf2f(g2.y) + db1;
    cum0 += aneg * fsoftplus(g0);
    cum1 += aneg * fsoftplus(g1);
    float cc0 = fmaxf(cum0, -15.f), cc1 = fmaxf(cum1, -15.f);
    float Wg0 = __expf(cc0), Wg1 = __expf(cc1);
    float Wi0 = __fdividef(1.f, Wg0), Wi1 = __fdividef(1.f, Wg1);
    float beta = fsig(beta_lin[((size_t)(b * Tc + t)) * 128 + h]);
    size_t idx = ((size_t)cid * Cc + c) * Kc + k0;
    ushort2 o1, o2, o3, o4;
    o1.x = f2bf(qv[0] * rq * Wg0); o1.y = f2bf(qv[1] * rq * Wg1);
    o2.x = f2bf(kv[0] * rk * Wi0); o2.y = f2bf(kv[1] * rk * Wi1);
    o3.x = f2bf(beta * kv[0] * rk * Wg0); o3.y = f2bf(beta * kv[1] * rk * Wg1);
    o4.x = f2bf(beta * vv[0]); o4.y = f2bf(beta * vv[1]);
    *(ushort2*)(qt + idx) = o1;
    *(ushort2*)(u_ + idx) = o2;
    *(ushort2*)(bw + idx) = o3;
    *(ushort2*)(bv + idx) = o4;
    if (c == Cc - 1) {
      wlast[(size_t)cid * Kc + k0] = Wg0;
      wlast[(size_t)cid * Kc + k0 + 1] = Wg1;
    }
  }
}

// ---------------- MFMA chunk solve + in-place u -> u^T transpose ----------------
__global__ __launch_bounds__(256) void chunk_solve_mfma(
    const unsigned short* __restrict__ qt, unsigned short* __restrict__ u_,
    unsigned short* __restrict__ evb,  // in: bv, out: ev
    unsigned short* __restrict__ ewb,  // in: bw, out: ew
    unsigned short* __restrict__ intra_out) {
  const int blk = blockIdx.x;
  const size_t base = (size_t)blk * (Cc * Kc);
  const size_t ibase = (size_t)blk * (Cc * Cc);
  const int tid = threadIdx.x, wave = tid >> 6, lane = tid & 63;
  const int l15 = lane & 15, l4 = lane >> 4;

  __shared__ __align__(16) char lds[65536];
  unsigned short* uS   = (unsigned short*)(lds);            // [64][128] swzA
  unsigned short* qtS  = (unsigned short*)(lds + 16384);    // [64][128] swzA
  unsigned short* bwS  = (unsigned short*)(lds + 32768);    // [64][128] swzA
  unsigned short* NLrm = (unsigned short*)(lds + 49152);    // [64][64] swzB
  unsigned short* NLT  = (unsigned short*)(lds + 57344);    // [64][64] swzB
  unsigned short* Trm  = (unsigned short*)(lds);            // over uS
  unsigned short* TT   = (unsigned short*)(lds + 8192);
  unsigned short* Prm  = (unsigned short*)(lds + 16384);    // over qtS
  unsigned short* PT   = (unsigned short*)(lds + 24576);
  unsigned short* bvT  = (unsigned short*)(lds + 32768);    // [128][64] swzB, over bwS
  unsigned short* bwT  = (unsigned short*)(lds + 49152);    // [128][64] swzB, over NL

#pragma unroll
  for (int i = 0; i < 4; ++i) {
    int cid = tid + i * 256;
    int r = cid >> 4, c8 = (cid & 15) * 8, cb2 = (cid & 15) * 16;
    int4 vu = *(const int4*)(u_ + base + (size_t)r * 128 + c8);
    int4 vb = *(const int4*)(ewb + base + (size_t)r * 128 + c8);
    int4 vq = *(const int4*)(qt + base + (size_t)r * 128 + c8);
    stsv16B(uS, swzA(r, cb2), vu);
    stsv16B(bwS, swzA(r, cb2), vb);
    stsv16B(qtS, swzA(r, cb2), vq);
  }
  __syncthreads();

  const int arow = 16 * wave + l15;
  bf16x8 aBw[4], aQt[4];
#pragma unroll
  for (int ks = 0; ks < 4; ++ks) {
    aBw[ks] = ldsv8(bwS, swzA(arow, 16 * l4 + 64 * ks));
    aQt[ks] = ldsv8(qtS, swzA(arow, 16 * l4 + 64 * ks));
  }
  f32x4 Lc[4], Ic[4];
#pragma unroll
  for (int nt = 0; nt < 4; ++nt) {
    f32x4 a = {}, bq = {};
#pragma unroll
    for (int ks = 0; ks < 4; ++ks) {
      bf16x8 bu = ldsv8(uS, swzA(16 * nt + l15, 16 * l4 + 64 * ks));
      a = __builtin_amdgcn_mfma_f32_16x16x32_bf16(aBw[ks], bu, a, 0, 0, 0);
      bq = __builtin_amdgcn_mfma_f32_16x16x32_bf16(aQt[ks], bu, bq, 0, 0, 0);
    }
    Lc[nt] = a; Ic[nt] = bq;
  }
#pragma unroll
  for (int nt = 0; nt < 4; ++nt)
#pragma unroll
    for (int r = 0; r < 4; ++r) {
      int row = 16 * wave + 4 * l4 + r, col = 16 * nt + l15;
      intra_out[ibase + (size_t)row * 64 + col] = f2bf((col <= row) ? Ic[nt][r] : 0.f);
    }

  // in-place u^T write-back
#pragma unroll
  for (int i = 0; i < 4; ++i) {
    int w2 = tid + i * 256;
    int k = w2 >> 3, cg = w2 & 7;
    unsigned short tmp[8];
#pragma unroll
    for (int j = 0; j < 8; ++j) {
      int c = cg + 8 * j;
      tmp[j] = lds16(uS, swzA(c, 2 * k));
    }
#pragma unroll
    for (int j = 0; j < 8; ++j)
      u_[base + (size_t)k * 64 + cg + 8 * j] = tmp[j];
  }
  __syncthreads();

  f32x4 Tf[4];
#pragma unroll
  for (int nt = 0; nt < 4; ++nt)
#pragma unroll
    for (int r = 0; r < 4; ++r) {
      int row = 16 * wave + 4 * l4 + r, col = 16 * nt + l15;
      float nl = (col < row) ? -Lc[nt][r] : 0.f;
      unsigned short nb = f2bf(nl);
      *reinterpret_cast<unsigned short*>((char*)NLrm + swzB(row, col * 2)) = nb;
      *reinterpret_cast<unsigned short*>((char*)NLT + swzB(col, row * 2)) = nb;
      float t0 = nl + ((row == col) ? 1.f : 0.f);
      Tf[nt][r] = t0;
      unsigned short tb = f2bf(t0);
      *reinterpret_cast<unsigned short*>((char*)Trm + swzB(row, col * 2)) = tb;
      *reinterpret_cast<unsigned short*>((char*)TT + swzB(col, row * 2)) = tb;
    }
  __syncthreads();

  bf16x8 aN[2];
#pragma unroll
  for (int ks = 0; ks < 2; ++ks) aN[ks] = ldsv8(NLrm, swzB(arow, 16 * l4 + 64 * ks));
  f32x4 Pf[4];
#pragma unroll
  for (int nt = 0; nt < 4; ++nt) {
    f32x4 acc = {};
#pragma unroll
    for (int ks = 0; ks < 2; ++ks)
      acc = __builtin_amdgcn_mfma_f32_16x16x32_bf16(aN[ks], ldsv8(NLT, swzB(16 * nt + l15, 16 * l4 + 64 * ks)), acc, 0, 0, 0);
    Pf[nt] = acc;
  }
  int4 rv[4], rw[4];
#pragma unroll
  for (int i = 0; i < 4; ++i) {
    int cid = tid + i * 256;
    int r = cid >> 4, c8 = (cid & 15) * 8;
    rv[i] = *(const int4*)(evb + base + (size_t)r * 128 + c8);
    rw[i] = *(const int4*)(ewb + base + (size_t)r * 128 + c8);
  }
#pragma unroll
  for (int nt = 0; nt < 4; ++nt)
#pragma unroll
    for (int r = 0; r < 4; ++r) {
      int row = 16 * wave + 4 * l4 + r, col = 16 * nt + l15;
      unsigned short pb = f2bf(Pf[nt][r]);
      *reinterpret_cast<unsigned short*>((char*)Prm + swzB(row, col * 2)) = pb;
      *reinterpret_cast<unsigned short*>((char*)PT + swzB(col, row * 2)) = pb;
    }
  __syncthreads();

  for (int it = 0; it < 5; ++it) {
    bf16x8 aP[2];
#pragma unroll
    for (int ks = 0; ks < 2; ++ks) aP[ks] = ldsv8(Prm, swzB(arow, 16 * l4 + 64 * ks));
    f32x4 Tn[4], Pn[4];
#pragma unroll
    for (int nt = 0; nt < 4; ++nt) {
      f32x4 acc = Tf[nt];
#pragma unroll
      for (int ks = 0; ks < 2; ++ks)
        acc = __builtin_amdgcn_mfma_f32_16x16x32_bf16(aP[ks], ldsv8(TT, swzB(16 * nt + l15, 16 * l4 + 64 * ks)), acc, 0, 0, 0);
      Tn[nt] = acc;
    }
    if (it < 4) {
#pragma unroll
      for (int nt = 0; nt < 4; ++nt) {
        f32x4 acc = {};
#pragma unroll
        for (int ks = 0; ks < 2; ++ks)
          acc = __builtin_amdgcn_mfma_f32_16x16x32_bf16(aP[ks], ldsv8(PT, swzB(16 * nt + l15, 16 * l4 + 64 * ks)), acc, 0, 0, 0);
        Pn[nt] = acc;
      }
    }
    __syncthreads();
#pragma unroll
    for (int nt = 0; nt < 4; ++nt)
#pragma unroll
      for (int r = 0; r < 4; ++r) {
        int row = 16 * wave + 4 * l4 + r, col = 16 * nt + l15;
        unsigned short tb = f2bf(Tn[nt][r]);
        *reinterpret_cast<unsigned short*>((char*)Trm + swzB(row, col * 2)) = tb;
        *reinterpret_cast<unsigned short*>((char*)TT + swzB(col, row * 2)) = tb;
        if (it < 4) {
          unsigned short pb = f2bf(Pn[nt][r]);
          *reinterpret_cast<unsigned short*>((char*)Prm + swzB(row, col * 2)) = pb;
          *reinterpret_cast<unsigned short*>((char*)PT + swzB(col, row * 2)) = pb;
        }
      }
#pragma unroll
    for (int nt = 0; nt < 4; ++nt) Tf[nt] = Tn[nt];
    __syncthreads();
  }

#pragma unroll
  for (int i = 0; i < 4; ++i) {
    int cid = tid + i * 256;
    int r = cid >> 4;
    const unsigned short* pv = reinterpret_cast<const unsigned short*>(&rv[i]);
    const unsigned short* pw = reinterpret_cast<const unsigned short*>(&rw[i]);
#pragma unroll
    for (int j = 0; j < 8; ++j) {
      int v = (cid & 15) * 8 + j;
      *reinterpret_cast<unsigned short*>((char*)bvT + swzB(v, r * 2)) = pv[j];
      *reinterpret_cast<unsigned short*>((char*)bwT + swzB(v, r * 2)) = pw[j];
    }
  }
  __syncthreads();

  bf16x8 aT[2];
#pragma unroll
  for (int ks = 0; ks < 2; ++ks) aT[ks] = ldsv8(Trm, swzB(arow, 16 * l4 + 64 * ks));
#pragma unroll
  for (int nt = 0; nt < 8; ++nt) {
    f32x4 e = {}, w2 = {};
#pragma unroll
    for (int ks = 0; ks < 2; ++ks) {
      e = __builtin_amdgcn_mfma_f32_16x16x32_bf16(aT[ks], ldsv8(bvT, swzB(16 * nt + l15, 16 * l4 + 64 * ks)), e, 0, 0, 0);
      w2 = __builtin_amdgcn_mfma_f32_16x16x32_bf16(aT[ks], ldsv8(bwT, swzB(16 * nt + l15, 16 * l4 + 64 * ks)), w2, 0, 0, 0);
    }
#pragma unroll
    for (int r = 0; r < 4; ++r) {
      int row = 16 * wave + 4 * l4 + r, col = 16 * nt + l15;
      evb[base + (size_t)row * 128 + col] = f2bf(e[r]);
      ewb[base + (size_t)row * 128 + col] = f2bf(w2[r]);
    }
  }
}

// ---------------- MFMA scan, v-split x2: grid = B*H*2, 8 waves --------------------
__global__ __launch_bounds__(512) void scan_mfma(
    const unsigned short* __restrict__ qt, const unsigned short* __restrict__ uT,
    const unsigned short* __restrict__ evb, const unsigned short* __restrict__ ewb,
    const unsigned short* __restrict__ intra, const float* __restrict__ wlast,
    unsigned short* __restrict__ attn_o, unsigned short* __restrict__ snapb) {
  const int blk = blockIdx.x;
  const int bh = blk >> 1, vh = blk & 1;
  const int b = bh >> 4, h = bh & 15;
  const int v0 = vh * 64;
  const int tid = threadIdx.x, wave = tid >> 6, lane = tid & 63;
  const int l15 = lane & 15, l4 = lane >> 4;
  __shared__ __align__(16) unsigned short ewS[8192];  // [64 c][128 k] swzA
  __shared__ __align__(16) unsigned short qtS[8192];  // [64 c][128 k] swzA
  __shared__ __align__(16) unsigned short uTS[8192];  // [128 k][64 c] swzB
  __shared__ __align__(16) unsigned short iaS[4096];  // [64 c][64 j]  swzB
  __shared__ __align__(16) unsigned short evS[4096];  // [64 c][64 v]  swzB (slice)
  __shared__ __align__(16) unsigned short sBT[8192];  // [64 v][128 k] swzA (S^T slice)
  __shared__ __align__(16) unsigned short dBT[4096];  // [64 v][64 c]  swzB (delta^T)

  f32x4 S[4] = {};
  {
    int4 z = {0, 0, 0, 0};
    stsv16B(sBT, tid * 32, z);
    stsv16B(sBT, tid * 32 + 16, z);
  }

  const int sr = tid >> 3;           // 0..63
  const int sk0 = (tid & 7) * 16;    // 128-wide col base
  const int sc0 = (tid & 7) * 8;     // 64-wide col base
  const int tk = tid >> 3;           // uT rows tk, tk+64
  const int wloff = 16 * wave + 4 * l4;
  int4 rEw0, rEw1, rQt0, rQt1, rEv, rUT0, rUT1, rIa;
  float4 rWlN, rWlC;

#define STAGE_LOAD(CB, IB, NN)                                                    \
  rEw0 = *(const int4*)(ewb + (CB) + sr * 128 + sk0);                             \
  rEw1 = *(const int4*)(ewb + (CB) + sr * 128 + sk0 + 8);                         \
  rQt0 = *(const int4*)(qt + (CB) + sr * 128 + sk0);                              \
  rQt1 = *(const int4*)(qt + (CB) + sr * 128 + sk0 + 8);                          \
  rEv = *(const int4*)(evb + (CB) + sr * 128 + v0 + sc0);                         \
  rUT0 = *(const int4*)(uT + (CB) + (size_t)tk * 64 + sc0);                       \
  rUT1 = *(const int4*)(uT + (CB) + (size_t)(tk + 64) * 64 + sc0);                \
  rIa = *(const int4*)(intra + (IB) + sr * 64 + sc0);                             \
  rWlN = ld4(wlast + ((size_t)bh * 64 + (NN)) * 128 + wloff);

#define STAGE_WRITE()                                                             \
  stsv16B(ewS, swzA(sr, sk0 * 2), rEw0);                                          \
  stsv16B(ewS, swzA(sr, sk0 * 2 + 16), rEw1);                                     \
  stsv16B(qtS, swzA(sr, sk0 * 2), rQt0);                                          \
  stsv16B(qtS, swzA(sr, sk0 * 2 + 16), rQt1);                                     \
  stsv16B(evS, swzB(sr, sc0 * 2), rEv);                                           \
  stsv16B(iaS, swzB(sr, sc0 * 2), rIa);                                           \
  stsv16B(uTS, swzB(tk, sc0 * 2), rUT0);                                          \
  stsv16B(uTS, swzB(tk + 64, sc0 * 2), rUT1);

  {
    const size_t cb0 = (size_t)bh * 64 * 8192;
    const size_t ib0 = (size_t)bh * 64 * 4096;
    STAGE_LOAD(cb0, ib0, 0);
    STAGE_WRITE();
    rWlC = rWlN;
  }
  __syncthreads();

  const int m = wave & 3, ntb = (wave >> 2) * 2;
  const int arow = 16 * m + l15;
  const int krow = 16 * wave + l15;

  for (int n = 0; n < NCc; ++n) {
    const size_t cb = ((size_t)bh * 64 + n) * 8192;
    const size_t ib = ((size_t)bh * 64 + n) * 4096;
    // ---- Phase A: prefetch n+1; delta = ev - ew@S -> dBT ----
    if (n < 63) { STAGE_LOAD(cb + 8192, ib + 4096, n + 1); }
    bf16x8 aEw[4];
#pragma unroll
    for (int ks = 0; ks < 4; ++ks) aEw[ks] = ldsv8(ewS, swzA(arow, 16 * l4 + 64 * ks));
#pragma unroll
    for (int i = 0; i < 2; ++i) {
      int vl = 16 * (ntb + i) + l15;
      f32x4 p = {};
#pragma unroll
      for (int ks = 0; ks < 4; ++ks)
        p = __builtin_amdgcn_mfma_f32_16x16x32_bf16(aEw[ks], ldsv8(sBT, swzA(vl, 16 * l4 + 64 * ks)), p, 0, 0, 0);
      float d[4];
#pragma unroll
      for (int r = 0; r < 4; ++r) {
        int c = 16 * m + 4 * l4 + r;
        d[r] = bf2f(lds16(evS, swzB(c, 2 * vl))) - p[r];
      }
      uint2 pk;
      pk.x = (unsigned)f2bf(d[0]) | ((unsigned)f2bf(d[1]) << 16);
      pk.y = (unsigned)f2bf(d[2]) | ((unsigned)f2bf(d[3]) << 16);
      stsv8B(dBT, swzB(vl, (16 * m + 4 * l4) * 2), pk);
    }
    __syncthreads();
    // ---- Phase B1: o = qt@S + ia@delta; S = wl*(S + uT@delta) ----
    bf16x8 aQt[4], aIa[2], aU[2];
#pragma unroll
    for (int ks = 0; ks < 4; ++ks) aQt[ks] = ldsv8(qtS, swzA(arow, 16 * l4 + 64 * ks));
#pragma unroll
    for (int ks = 0; ks < 2; ++ks) aIa[ks] = ldsv8(iaS, swzB(arow, 16 * l4 + 64 * ks));
#pragma unroll
    for (int ks = 0; ks < 2; ++ks) aU[ks] = ldsv8(uTS, swzB(krow, 16 * l4 + 64 * ks));
#pragma unroll
    for (int i = 0; i < 2; ++i) {
      int vl = 16 * (ntb + i) + l15;
      f32x4 o = {};
#pragma unroll
      for (int ks = 0; ks < 4; ++ks)
        o = __builtin_amdgcn_mfma_f32_16x16x32_bf16(aQt[ks], ldsv8(sBT, swzA(vl, 16 * l4 + 64 * ks)), o, 0, 0, 0);
#pragma unroll
      for (int ks = 0; ks < 2; ++ks)
        o = __builtin_amdgcn_mfma_f32_16x16x32_bf16(aIa[ks], ldsv8(dBT, swzB(vl, 16 * l4 + 64 * ks)), o, 0, 0, 0);
#pragma unroll
      for (int r = 0; r < 4; ++r) {
        int c = 16 * m + 4 * l4 + r;
        int t = n * 64 + c;
        attn_o[((size_t)(b * Tc + t) * Hc + h) * Kc + v0 + vl] = f2bf(o[r]);
      }
    }
    float wlv[4] = {rWlC.x, rWlC.y, rWlC.z, rWlC.w};
#pragma unroll
    for (int nt4 = 0; nt4 < 4; ++nt4) {
      int vl = 16 * nt4 + l15;
      f32x4 U = {};
#pragma unroll
      for (int ks = 0; ks < 2; ++ks)
        U = __builtin_amdgcn_mfma_f32_16x16x32_bf16(aU[ks], ldsv8(dBT, swzB(vl, 16 * l4 + 64 * ks)), U, 0, 0, 0);
#pragma unroll
      for (int r = 0; r < 4; ++r) S[nt4][r] = wlv[r] * (S[nt4][r] + U[r]);
    }
    __syncthreads();
    // ---- Phase B2: S -> sBT, staging writes, snapshot ----
#pragma unroll
    for (int nt4 = 0; nt4 < 4; ++nt4) {
      int vl = 16 * nt4 + l15;
      uint2 pk;
      pk.x = (unsigned)f2bf(S[nt4][0]) | ((unsigned)f2bf(S[nt4][1]) << 16);
      pk.y = (unsigned)f2bf(S[nt4][2]) | ((unsigned)f2bf(S[nt4][3]) << 16);
      stsv8B(sBT, swzA(vl, (16 * wave + 4 * l4) * 2), pk);
    }
    if (n < 63) { STAGE_WRITE(); rWlC = rWlN; }
    if ((n & 3) == 3) {
      int ns = n >> 2;
      size_t sb = (size_t)((ns * Bc + b) * Hc + h) * 16384;
#pragma unroll
      for (int nt4 = 0; nt4 < 4; ++nt4)
#pragma unroll
        for (int r = 0; r < 4; ++r) {
          int k = 16 * wave + 4 * l4 + r;
          snapb[sb + (size_t)k * 128 + v0 + 16 * nt4 + l15] = f2bf(S[nt4][r]);
        }
    }
    __syncthreads();
  }
#undef STAGE_LOAD
#undef STAGE_WRITE
}

// ---------------- snapshot helpers ----------------
__global__ void sdw_mul_bf16(const float* __restrict__ snap_down, const float* __restrict__ w,
                             unsigned short* __restrict__ sdwb) {
  int i = (blockIdx.x * 256 + threadIdx.x) * 4;
  float4 v = ld4(snap_down + i);
  int k = i & 16383;
  float4 ww = ld4(w + k);
  ushort4 o;
  o.x = f2bf(v.x * ww.x); o.y = f2bf(v.y * ww.y); o.z = f2bf(v.z * ww.z); o.w = f2bf(v.w * ww.w);
  *reinterpret_cast<ushort4*>(sdwb + i) = o;
}

__global__ __launch_bounds__(256) void snap_scale_kernel(const unsigned short* __restrict__ snapb,
                                                         float* __restrict__ scale) {
  int r = blockIdx.x;
  const unsigned short* row = snapb + (size_t)r * 16384;
  float s = 0.f;
  for (int ii = threadIdx.x * 4; ii < 16384; ii += 1024) {
    float4 x = ld4(row + ii);
    s += x.x * x.x + x.y * x.y + x.z * x.z + x.w * x.w;
  }
#pragma unroll
  for (int off = 32; off > 0; off >>= 1) s += __shfl_down(s, off, 64);
  __shared__ float red[4];
  if ((threadIdx.x & 63) == 0) red[threadIdx.x >> 6] = s;
  __syncthreads();
  if (threadIdx.x == 0) {
    float tot = red[0] + red[1] + red[2] + red[3];
    scale[r] = rsqrtf(tot * (1.f / 16384.f) + 1e-6f);
  }
}

__global__ void snap_reduce_scatter(const float* __restrict__ part,
                                    const float* __restrict__ scale,
                                    float* __restrict__ outp) {
  int idx = blockIdx.x * 256 + threadIdx.x;
  int l = idx & 127;
  int hh = (idx >> 7) & 15;
  int ns = (idx >> 11) & 15;
  int bb = idx >> 15;
  int r = (ns * Bc + bb) * Hc + hh;
  float s = 0.f;
#pragma unroll
  for (int z = 0; z < 16; ++z) s += part[(size_t)z * 65536 + r * 128 + l];
  outp[idx] = s * scale[r];
}

// ---------------- final rmsnorm * sigmoid(gate): wave-per-row ----------
__global__ __launch_bounds__(256) void out_norm_gate(unsigned short* __restrict__ attn_io,
                                                     const unsigned short* __restrict__ gate_raw,
                                                     const float* __restrict__ bgb,
                                                     const float* __restrict__ o_norm_w) {
  const int wave = threadIdx.x >> 6, lane = threadIdx.x & 63;
  const int blk = blockIdx.x * 4 + wave;  // (b*T + t)*H + h
  const int h = blk & 15;
  const size_t row = (size_t)(blk >> 4);
  const size_t base = (size_t)blk * Kc;
  ushort2 xv = *reinterpret_cast<const ushort2*>(attn_io + base + 2 * lane);
  float x0 = bf2f(xv.x), x1 = bf2f(xv.y);
  float ss = x0 * x0 + x1 * x1;
#pragma unroll
  for (int off = 32; off > 0; off >>= 1) ss += __shfl_xor(ss, off, 64);
  float inv = rsqrtf(ss * (1.f / 128.f) + 1e-6f);
  const int p0 = h * Kc + 2 * lane;
  ushort2 gv = *reinterpret_cast<const ushort2*>(gate_raw + row * Pc + p0);
  float g0 = bf2f(gv.x) + bgb[p0];
  float g1 = bf2f(gv.y) + bgb[p0 + 1];
  float o0 = x0 * inv * o_norm_w[2 * lane] * fsig(g0);
  float o1 = x1 * inv * o_norm_w[2 * lane + 1] * fsig(g1);
  ushort2 ov; ov.x = f2bf(o0); ov.y = f2bf(o1);
  *reinterpret_cast<ushort2*>(attn_io + base + 2 * lane) = ov;
}

// ---------------- launch ----------------
extern "C" void kernel_launch(void* const* d_in, const int* in_sizes, int n_in,
                              void* d_out, int out_size, void* d_ws, size_t ws_size,
                              hipStream_t stream) {
  (void)in_sizes; (void)n_in;
  const float* x        = (const float*)d_in[0];
  const float* Wq       = (const float*)d_in[1];
  const float* Wk       = (const float*)d_in[2];
  const float* Wv       = (const float*)d_in[3];
  const float* conv_q   = (const float*)d_in[4];
  const float* conv_k   = (const float*)d_in[5];
  const float* conv_v   = (const float*)d_in[6];
  const float* A_log    = (const float*)d_in[7];
  const float* dt_bias  = (const float*)d_in[8];
  const float* Wfa      = (const float*)d_in[9];
  const float* Wfb      = (const float*)d_in[10];
  const float* Wb       = (const float*)d_in[11];
  const float* Wga      = (const float*)d_in[12];
  const float* Wgb      = (const float*)d_in[13];
  const float* bgb      = (const float*)d_in[14];
  const float* o_norm_w = (const float*)d_in[15];
  const float* Wo       = (const float*)d_in[16];
  const float* snap_nw  = (const float*)d_in[17];
  const float* snap_down= (const float*)d_in[18];

  const size_t MP2 = (size_t)Mc * Pc * 2;
  const size_t NEED = 6 * MP2
                    + 2 * (size_t)Mc * Kc * 4
                    + (size_t)Mc * Hc * 4
                    + (size_t)Bc * Hc * NCc * Kc * 4;
  if (ws_size < NEED + 4096) {
    hipMemsetAsync(d_out, 0, (size_t)out_size * 4, stream);
    return;
  }
  char* w = (char*)d_ws;
  auto alloc = [&](size_t bytes) {
    char* r = w;
    w += (bytes + 255) & ~(size_t)255;
    return r;
  };
  unsigned short* q_lin = (unsigned short*)alloc(MP2);  // q,k,v contiguous (QKV-fused out)
  unsigned short* k_lin = (unsigned short*)alloc(MP2);
  unsigned short* v_lin = (unsigned short*)alloc(MP2);
  unsigned short* g_raw = (unsigned short*)alloc(MP2);
  unsigned short* evb   = (unsigned short*)alloc(MP2);
  unsigned short* ewb   = (unsigned short*)alloc(MP2);
  float* fa    = (float*)alloc((size_t)Mc * Kc * 4);    // fab; later betap (8192x128 f32)
  float* ga    = (float*)alloc((size_t)Mc * Kc * 4);
  float* betab = (float*)alloc((size_t)Mc * Hc * 4);    // unused (kept for NEED layout)
  float* wlast = (float*)alloc((size_t)Bc * Hc * NCc * Kc * 4);
  (void)betab;

  unsigned short* qt = (unsigned short*)d_out;
  unsigned short* u_ = (unsigned short*)((char*)d_out + MP2);

  unsigned short* xb    = evb;
  unsigned short* Wqb   = ewb;                 // [Wq;Wk;Wv] contiguous (6144 rows)
  unsigned short* Wkb   = ewb + 4194304;
  unsigned short* Wvb   = ewb + 8388608;
  unsigned short* Wfab  = ewb + 12582912;
  unsigned short* Wgab  = ewb + 12845056;
  unsigned short* Wfbb  = ewb + 13107200;      // ends 13,369,344
  unsigned short* Wbp   = ewb + 13369344;      // padded Wb: 128x2048 bf16, ends 13,631,488
  unsigned short* fab   = (unsigned short*)fa;
  unsigned short* gab   = (unsigned short*)ga;
  float* betap          = fa;                  // 8192x128 f32 = 4MB exact (fa dead after g_raw GEMM)

  unsigned short* intra = q_lin;
  unsigned short* Wob   = q_lin + 8388608;
  unsigned short* Wgbb  = q_lin + 12582912;
  unsigned short* attn  = k_lin;
  unsigned short* gate_raw = g_raw;
  unsigned short* snapb = v_lin;
  unsigned short* sdwb  = v_lin + (size_t)512 * 16384;
  float* partial   = (float*)ewb;
  float* snapscale = (float*)(ewb + 4400000);

  float* y = (float*)d_out;
  float* snaps_out = (float*)d_out + (size_t)Bc * Tc * Dc;

  // 0) casts (+ zero-padded Wb for MFMA beta)
  cast_f32_bf16<<<16384, 256, 0, stream>>>(x, xb, Mc * Dc);
  cast_f32_bf16<<<4096, 256, 0, stream>>>(Wq, Wqb, Pc * Dc);
  cast_f32_bf16<<<4096, 256, 0, stream>>>(Wk, Wkb, Pc * Dc);
  cast_f32_bf16<<<4096, 256, 0, stream>>>(Wv, Wvb, Pc * Dc);
  cast_f32_bf16<<<256, 256, 0, stream>>>(Wfa, Wfab, Kc * Dc);
  cast_f32_bf16<<<256, 256, 0, stream>>>(Wga, Wgab, Kc * Dc);
  cast_f32_bf16<<<256, 256, 0, stream>>>(Wfb, Wfbb, Pc * Kc);
  hipMemsetAsync(Wbp, 0, (size_t)128 * 2048 * 2, stream);
  cast_f32_bf16<<<32, 256, 0, stream>>>(Wb, Wbp, Hc * Dc);  // rows 0..15 valid

  // 1) input GEMMs (bf16 MFMA): fused QKV + low-rank paths
  gemm_nt_mfma_qkv<<<dim3(64, 48), 256, 0, stream>>>(xb, Wqb, q_lin, Dc);
  gemm_nt_mfma<unsigned short><<<dim3(64, 1), 256, 0, stream>>>(xb, Wfab, fab, Kc, Dc);
  gemm_nt_mfma<unsigned short><<<dim3(64, 1), 256, 0, stream>>>(xb, Wgab, gab, Kc, Dc);
  gemm_nt_mfma<unsigned short><<<dim3(64, 16), 256, 0, stream>>>(fab, Wfbb, g_raw, Pc, Kc);
  // beta via padded MFMA (fa/fab dead now; betap overlays fa region)
  gemm_nt_mfma<float><<<dim3(64, 1), 256, 0, stream>>>(xb, Wbp, betap, 128, Dc);

  // 2) chunk prep (wave-per-chunk, fast transcendentals; beta stride 128)
  chunk_prep<<<Bc * Hc * NCc / 4, 256, 0, stream>>>(q_lin, k_lin, v_lin, g_raw, betap, conv_q,
                                                    conv_k, conv_v, A_log, dt_bias, qt, u_, evb,
                                                    ewb, wlast);

  // 3) late casts into q_lin's dead tail
  cast_f32_bf16<<<4096, 256, 0, stream>>>(Wo, Wob, Dc * Pc);
  cast_f32_bf16<<<256, 256, 0, stream>>>(Wgb, Wgbb, Pc * Kc);

  // chunk solve (also transposes u -> uT in place)
  chunk_solve_mfma<<<Bc * Hc * NCc, 256, 0, stream>>>(qt, u_, evb, ewb, intra);

  // 4) gate projection
  gemm_nt_mfma<unsigned short><<<dim3(64, 16), 256, 0, stream>>>(gab, Wgbb, gate_raw, Pc, Kc);

  // 5) MFMA scan, v-split x2 (u_ holds uT)
  scan_mfma<<<Bc * Hc * 2, 512, 0, stream>>>(qt, u_, evb, ewb, intra, wlast, attn, snapb);

  // 6) snapshots
  sdw_mul_bf16<<<2048, 256, 0, stream>>>(snap_down, snap_nw, sdwb);
  snap_scale_kernel<<<512, 256, 0, stream>>>(snapb, snapscale);
  gemm_nt_mfma_sk<<<dim3(4, 1, 16), 256, 0, stream>>>(snapb, sdwb, partial, 128, 16384, 1024, 512);
  snap_reduce_scatter<<<256, 256, 0, stream>>>(partial, snapscale, snaps_out);

  // 7) output norm*gate + final projection
  out_norm_gate<<<Mc * Hc / 4, 256, 0, stream>>>(attn, gate_raw, bgb, o_norm_w);
  gemm_nt_mfma<float><<<dim3(64, 16), 256, 0, stream>>>(attn, Wob, y, Dc, Pc);
}